// Round 2
// baseline (5957.577 us; speedup 1.0000x reference)
//
#include <hip/hip_runtime.h>

#ifndef M_PI
#define M_PI 3.14159265358979323846
#endif

// ============================================================================
// EnhancedAIDetector — fp32 correctness-first baseline, batch-chunked to
// bound workspace use (round-1 abort diagnosed as d_ws overflow at ~324MB).
//   backbone: direct convs (LDS input tile + LDS weights, reg-cached rows)
//   DCT branch: linearity collapse (DCT of block-mean), bilinear 8->224,
//               wd1 as 1-channel conv with channel-summed weights
//   FFT branch: DFT-as-matmul  Y = W @ X @ W  (W = 224-pt DFT matrix, symmetric)
//   fusion: split-K atomic GEMMs (M=64)
// Whole per-image pipeline runs in batch chunks of CB images; CB chosen
// at launch from ws_size (deterministic across calls -> graph-capture safe).
// ============================================================================

#define BATCH 64

// ============================================================================
// DFT matrix:  W[j,k] = exp(-2*pi*i * j*k / 224)
// ============================================================================
__global__ void make_dft(float* __restrict__ wre, float* __restrict__ wim) {
    int idx = blockIdx.x * 256 + threadIdx.x;
    if (idx >= 224 * 224) return;
    int j = idx / 224, k = idx % 224;
    int m = (j * k) % 224;
    double a = -2.0 * M_PI * (double)m / 224.0;
    wre[idx] = (float)cos(a);
    wim[idx] = (float)sin(a);
}

// wd1 channel-summed weights: wsum[o*9+k] = sum_c wd1[o][c][k]
__global__ void make_wsum(const float* __restrict__ wd1, float* __restrict__ wsum) {
    int idx = threadIdx.x;
    if (idx >= 288) return;
    int o = idx / 9, k = idx % 9;
    wsum[idx] = wd1[o * 27 + k] + wd1[o * 27 + 9 + k] + wd1[o * 27 + 18 + k];
}

// ============================================================================
// DFT stage 1: T = X @ W  (X real [224,224], W complex).  One (b,c) per z.
// ============================================================================
__global__ __launch_bounds__(256)
void dft_stage1(const float* __restrict__ x, const float* __restrict__ wre,
                const float* __restrict__ wim, float* __restrict__ tre,
                float* __restrict__ tim) {
    const int N = 224;
    const int bc = blockIdx.z;
    const float* X = x + (size_t)bc * N * N;
    float* Tre = tre + (size_t)bc * N * N;
    float* Tim = tim + (size_t)bc * N * N;
    const int tile = blockIdx.x;
    const int tr0 = (tile / 7) * 32, tc0 = (tile % 7) * 32;
    const int tid = threadIdx.x;
    const int rl = tid >> 3;          // 0..31
    const int cl = (tid & 7) << 2;    // 0,4,...,28

    __shared__ __align__(16) float sA[32][17];
    __shared__ __align__(16) float sBre[16][32];
    __shared__ __align__(16) float sBim[16][32];

    float ar[4] = {0, 0, 0, 0}, ai[4] = {0, 0, 0, 0};
    for (int k0 = 0; k0 < N; k0 += 16) {
        for (int i = tid; i < 512; i += 256) {
            int r = i >> 4, k = i & 15;
            sA[r][k] = X[(size_t)(tr0 + r) * N + k0 + k];
        }
        for (int i = tid; i < 512; i += 256) {
            int k = i >> 5, c = i & 31;
            sBre[k][c] = wre[(size_t)(k0 + k) * N + tc0 + c];
            sBim[k][c] = wim[(size_t)(k0 + k) * N + tc0 + c];
        }
        __syncthreads();
#pragma unroll
        for (int k = 0; k < 16; k++) {
            float a = sA[rl][k];
            float4 br = *(const float4*)&sBre[k][cl];
            float4 bi = *(const float4*)&sBim[k][cl];
            ar[0] += a * br.x; ar[1] += a * br.y; ar[2] += a * br.z; ar[3] += a * br.w;
            ai[0] += a * bi.x; ai[1] += a * bi.y; ai[2] += a * bi.z; ai[3] += a * bi.w;
        }
        __syncthreads();
    }
    int r = tr0 + rl, c = tc0 + cl;
    float4 vr = {ar[0], ar[1], ar[2], ar[3]};
    float4 vi = {ai[0], ai[1], ai[2], ai[3]};
    *(float4*)&Tre[(size_t)r * N + c] = vr;
    *(float4*)&Tim[(size_t)r * N + c] = vi;
}

// ============================================================================
// DFT stage 2: Y = W @ T (both complex) -> fft_in[b][2c]=re, [2c+1]=im (b local)
// ============================================================================
__global__ __launch_bounds__(256)
void dft_stage2(const float* __restrict__ wre, const float* __restrict__ wim,
                const float* __restrict__ tre, const float* __restrict__ tim,
                float* __restrict__ fft_in) {
    const int N = 224;
    const int bc = blockIdx.z;
    const int b = bc / 3, c = bc % 3;
    const float* Tre = tre + (size_t)bc * N * N;
    const float* Tim = tim + (size_t)bc * N * N;
    const int tile = blockIdx.x;
    const int tm0 = (tile / 7) * 32, tn0 = (tile % 7) * 32;
    const int tid = threadIdx.x;
    const int rl = tid >> 3;
    const int cl = (tid & 7) << 2;

    __shared__ __align__(16) float sWre[32][17];
    __shared__ __align__(16) float sWim[32][17];
    __shared__ __align__(16) float sTre[16][32];
    __shared__ __align__(16) float sTim[16][32];

    float yr[4] = {0, 0, 0, 0}, yi[4] = {0, 0, 0, 0};
    for (int k0 = 0; k0 < N; k0 += 16) {
        for (int i = tid; i < 512; i += 256) {
            int r = i >> 4, k = i & 15;
            sWre[r][k] = wre[(size_t)(tm0 + r) * N + k0 + k];
            sWim[r][k] = wim[(size_t)(tm0 + r) * N + k0 + k];
        }
        for (int i = tid; i < 512; i += 256) {
            int k = i >> 5, cc = i & 31;
            sTre[k][cc] = Tre[(size_t)(k0 + k) * N + tn0 + cc];
            sTim[k][cc] = Tim[(size_t)(k0 + k) * N + tn0 + cc];
        }
        __syncthreads();
#pragma unroll
        for (int k = 0; k < 16; k++) {
            float wr_ = sWre[rl][k], wi_ = sWim[rl][k];
            float4 t4 = *(const float4*)&sTre[k][cl];
            float4 u4 = *(const float4*)&sTim[k][cl];
            yr[0] += wr_ * t4.x - wi_ * u4.x;  yi[0] += wr_ * u4.x + wi_ * t4.x;
            yr[1] += wr_ * t4.y - wi_ * u4.y;  yi[1] += wr_ * u4.y + wi_ * t4.y;
            yr[2] += wr_ * t4.z - wi_ * u4.z;  yi[2] += wr_ * u4.z + wi_ * t4.z;
            yr[3] += wr_ * t4.w - wi_ * u4.w;  yi[3] += wr_ * u4.w + wi_ * t4.w;
        }
        __syncthreads();
    }
    int m = tm0 + rl, n = tn0 + cl;
    float4 vr = {yr[0], yr[1], yr[2], yr[3]};
    float4 vi = {yi[0], yi[1], yi[2], yi[3]};
    *(float4*)&fft_in[((size_t)(b * 6 + 2 * c) * N + m) * N + n] = vr;
    *(float4*)&fft_in[((size_t)(b * 6 + 2 * c + 1) * N + m) * N + n] = vi;
}

// ============================================================================
// Generic 3x3 stride-2 SAME conv (even in => pad lo 0, hi 1), fused bias+ReLU.
// blockIdx.z = local batch index (pointers pre-offset by chunk).
// ============================================================================
template <int CO_BLK, int TH, int TW, int CI_CHUNK>
__global__ __launch_bounds__(CO_BLK * TH)
void conv3x3_s2(const float* __restrict__ in, const float* __restrict__ w,
                const float* __restrict__ bias, float* __restrict__ out,
                int Ci, int Co, int Hin, int Win, int Hout, int Wout) {
    constexpr int IN_H = 2 * TH + 1;
    constexpr int IN_W = 2 * TW + 1;   // 29
    constexpr int IN_WP = 32;          // padded row (16B-aligned)
    constexpr int WSTR = (CI_CHUNK * 9) | 1;
    __shared__ __align__(16) float s_in[CI_CHUNK][IN_H][IN_WP];
    __shared__ float s_w[CO_BLK * WSTR];

    const int tid = threadIdx.x;
    const int tiles_x = Wout / TW;
    const int tile = blockIdx.x;
    const int ty0 = (tile / tiles_x) * TH;
    const int tx0 = (tile % tiles_x) * TW;
    const int cog = blockIdx.y;
    const int b = blockIdx.z;
    const int co = tid % CO_BLK;
    const int ty = tid / CO_BLK;
    const int co_g = cog * CO_BLK + co;

    float acc[TW];
#pragma unroll
    for (int i = 0; i < TW; i++) acc[i] = 0.f;

    const float* in_b = in + (size_t)b * Ci * Hin * Win;
    const int iy0 = 2 * ty0, ix0 = 2 * tx0;

    for (int ci0 = 0; ci0 < Ci; ci0 += CI_CHUNK) {
        for (int idx = tid; idx < CI_CHUNK * IN_H * IN_W; idx += CO_BLK * TH) {
            int ci = idx / (IN_H * IN_W);
            int rem = idx % (IN_H * IN_W);
            int r = rem / IN_W, cc = rem % IN_W;
            int gy = iy0 + r, gx = ix0 + cc;
            float v = 0.f;
            if (gy < Hin && gx < Win)
                v = in_b[(size_t)(ci0 + ci) * Hin * Win + (size_t)gy * Win + gx];
            s_in[ci][r][cc] = v;
        }
        for (int idx = tid; idx < CO_BLK * CI_CHUNK * 9; idx += CO_BLK * TH) {
            int c = idx / (CI_CHUNK * 9);
            int k = idx % (CI_CHUNK * 9);
            s_w[c * WSTR + k] = w[((size_t)(cog * CO_BLK + c) * Ci + ci0) * 9 + k];
        }
        __syncthreads();

#pragma unroll
        for (int ci = 0; ci < CI_CHUNK; ci++) {
            float wr[9];
#pragma unroll
            for (int k = 0; k < 9; k++) wr[k] = s_w[co * WSTR + ci * 9 + k];
#pragma unroll
            for (int ky = 0; ky < 3; ky++) {
                float r[IN_WP];
                const float4* rowp = (const float4*)&s_in[ci][2 * ty + ky][0];
#pragma unroll
                for (int q = 0; q < IN_WP / 4; q++) {
                    float4 v = rowp[q];
                    r[4 * q] = v.x; r[4 * q + 1] = v.y; r[4 * q + 2] = v.z; r[4 * q + 3] = v.w;
                }
#pragma unroll
                for (int kx = 0; kx < 3; kx++) {
                    float wv = wr[ky * 3 + kx];
#pragma unroll
                    for (int x = 0; x < TW; x++) acc[x] += r[2 * x + kx] * wv;
                }
            }
        }
        __syncthreads();
    }
    float bb = bias[co_g];
    float* outp = out + ((size_t)b * Co + co_g) * Hout * Wout + (size_t)(ty0 + ty) * Wout + tx0;
#pragma unroll
    for (int x = 0; x < TW; x++) {
        float v = acc[x] + bb;
        outp[x] = v > 0.f ? v : 0.f;
    }
}

// ============================================================================
// Stem: 7x7 stride-2 SAME (pad lo=2, hi=3), Cin=3, Cout=64, 224 -> 112
// ============================================================================
__global__ __launch_bounds__(256)
void conv7x7_s2(const float* __restrict__ in, const float* __restrict__ w,
                const float* __restrict__ bias, float* __restrict__ out) {
    constexpr int TH = 4, TW = 14;
    constexpr int IN_H = 13, IN_W = 33, IN_WP = 36, WSTR = 149;
    __shared__ __align__(16) float s_in[3][IN_H][IN_WP];
    __shared__ float s_w[64 * WSTR];
    const int tid = threadIdx.x;
    const int tile = blockIdx.x;       // 0..223
    const int tiles_x = 112 / TW;      // 8
    const int ty0 = (tile / tiles_x) * TH;
    const int tx0 = (tile % tiles_x) * TW;
    const int b = blockIdx.z;
    const int co = tid & 63;
    const int ty = tid >> 6;

    const float* in_b = in + (size_t)b * 3 * 224 * 224;
    const int iy0 = 2 * ty0 - 2, ix0 = 2 * tx0 - 2;

    for (int idx = tid; idx < 3 * IN_H * IN_W; idx += 256) {
        int ci = idx / (IN_H * IN_W);
        int rem = idx % (IN_H * IN_W);
        int r = rem / IN_W, cc = rem % IN_W;
        int gy = iy0 + r, gx = ix0 + cc;
        float v = 0.f;
        if (gy >= 0 && gy < 224 && gx >= 0 && gx < 224)
            v = in_b[(size_t)ci * 224 * 224 + (size_t)gy * 224 + gx];
        s_in[ci][r][cc] = v;
    }
    for (int idx = tid; idx < 64 * 147; idx += 256) {
        int c = idx / 147, k = idx % 147;
        s_w[c * WSTR + k] = w[c * 147 + k];
    }
    __syncthreads();

    float acc[TW];
#pragma unroll
    for (int i = 0; i < TW; i++) acc[i] = 0.f;

#pragma unroll
    for (int ci = 0; ci < 3; ci++) {
#pragma unroll
        for (int ky = 0; ky < 7; ky++) {
            float wr[7];
#pragma unroll
            for (int k = 0; k < 7; k++) wr[k] = s_w[co * WSTR + ci * 49 + ky * 7 + k];
            float r[IN_WP];
            const float4* rowp = (const float4*)&s_in[ci][2 * ty + ky][0];
#pragma unroll
            for (int q = 0; q < IN_WP / 4; q++) {
                float4 v = rowp[q];
                r[4 * q] = v.x; r[4 * q + 1] = v.y; r[4 * q + 2] = v.z; r[4 * q + 3] = v.w;
            }
#pragma unroll
            for (int kx = 0; kx < 7; kx++) {
                float wv = wr[kx];
#pragma unroll
                for (int x = 0; x < TW; x++) acc[x] += r[2 * x + kx] * wv;
            }
        }
    }
    float bb = bias[co];
    float* outp = out + ((size_t)b * 64 + co) * 112 * 112 + (size_t)(ty0 + ty) * 112 + tx0;
#pragma unroll
    for (int x = 0; x < TW; x++) {
        float v = acc[x] + bb;
        outp[x] = v > 0.f ? v : 0.f;
    }
}

// ============================================================================
// DCT branch: mean-of-blocks then 8x8 DCT (linearity collapse). One block per b.
// ============================================================================
__device__ __forceinline__ float dct_coef(int u, int i) {
    if (u == 0) return 0.35355339059327373f;  // 0.5/sqrt(2)
    return 0.5f * cosf((float)M_PI * (float)((2 * i + 1) * u) / 16.0f);
}

__global__ __launch_bounds__(256)
void dct_mean(const float* __restrict__ x, float* __restrict__ dct_out) {
    __shared__ float red[256];
    __shared__ float Mb[64];
    const int b = blockIdx.x;
    const int tid = threadIdx.x;
    const int ij = tid & 63;
    const int grp = tid >> 6;
    const int i = ij >> 3, j = ij & 7;
    const float* xb = x + (size_t)b * 3 * 224 * 224;
    float s = 0.f;
    for (int blk = grp; blk < 784; blk += 4) {
        int m = blk / 28, n = blk % 28;
        int p = m * 8 + i, q = n * 8 + j;
        size_t o = (size_t)p * 224 + q;
        s += (0.299f * xb[o] + 0.587f * xb[224 * 224 + o] + 0.114f * xb[2 * 224 * 224 + o]) * 255.f;
    }
    red[tid] = s;
    __syncthreads();
    if (tid < 64)
        Mb[tid] = (red[tid] + red[tid + 64] + red[tid + 128] + red[tid + 192]) * (1.f / 784.f);
    __syncthreads();
    if (tid < 64) {
        int u = tid >> 3, v = tid & 7;
        float acc = 0.f;
#pragma unroll
        for (int i2 = 0; i2 < 8; i2++) {
            float du = dct_coef(u, i2);
#pragma unroll
            for (int j2 = 0; j2 < 8; j2++) acc += du * Mb[i2 * 8 + j2] * dct_coef(v, j2);
        }
        dct_out[b * 64 + tid] = acc;
    }
}

// bilinear 8x8 -> 224x224, half-pixel convention with edge clamp (== jax.image.resize)
__global__ void resize_bilinear(const float* __restrict__ dct, float* __restrict__ out) {
    int idx = blockIdx.x * 256 + threadIdx.x;
    if (idx >= BATCH * 224 * 224) return;
    int b = idx / (224 * 224);
    int rem = idx % (224 * 224);
    int y = rem / 224, xx = rem % 224;
    float sy = fminf(fmaxf((y + 0.5f) * (1.f / 28.f) - 0.5f, 0.f), 7.f);
    float sx = fminf(fmaxf((xx + 0.5f) * (1.f / 28.f) - 0.5f, 0.f), 7.f);
    int y0 = (int)floorf(sy); if (y0 > 6) y0 = 6;
    int x0 = (int)floorf(sx); if (x0 > 6) x0 = 6;
    float ty = sy - y0, tx = sx - x0;
    const float* M = dct + b * 64;
    float v00 = M[y0 * 8 + x0], v01 = M[y0 * 8 + x0 + 1];
    float v10 = M[(y0 + 1) * 8 + x0], v11 = M[(y0 + 1) * 8 + x0 + 1];
    out[idx] = (1.f - ty) * ((1.f - tx) * v00 + tx * v01) + ty * ((1.f - tx) * v10 + tx * v11);
}

// ============================================================================
// Pooling (chunk-aware: n limits threads, pointers pre-offset)
// ============================================================================
__global__ void pool7(const float* __restrict__ h, float* __restrict__ out,
                      int col_base, int n) {
    int idx = blockIdx.x * 256 + threadIdx.x;
    if (idx >= n) return;
    int b = idx / (64 * 49);
    int rem = idx % (64 * 49);
    int c = rem / 49;
    int ij = rem % 49;
    int i = ij / 7, j = ij % 7;
    const float* hp = h + ((size_t)(b * 64 + c)) * 56 * 56 + (size_t)i * 8 * 56 + j * 8;
    float s = 0.f;
#pragma unroll
    for (int r = 0; r < 8; r++)
#pragma unroll
        for (int q = 0; q < 8; q++) s += hp[r * 56 + q];
    out[(size_t)b * 6272 + col_base + c * 49 + ij] = s * (1.f / 64.f);
}

// global avg pool [CB,512,14,14] -> comb[b*1024 + c]; one wave per (b,c)
__global__ void gap_kernel(const float* __restrict__ h, float* __restrict__ comb, int nwaves) {
    int gt = blockIdx.x * blockDim.x + threadIdx.x;
    int wid = gt >> 6;
    int lane = gt & 63;
    if (wid >= nwaves) return;
    int b = wid / 512, c = wid % 512;
    const float* hp = h + (size_t)wid * 196;
    float s = 0.f;
    for (int i = lane; i < 196; i += 64) s += hp[i];
#pragma unroll
    for (int off = 32; off > 0; off >>= 1) s += __shfl_down(s, off);
    if (lane == 0) comb[(size_t)b * 1024 + c] = s * (1.f / 196.f);
}

// ============================================================================
// Fusion GEMMs: C[64,N] += A[64,K-slice] @ B[K-slice,N], split-K via grid.z
// ============================================================================
__global__ __launch_bounds__(256)
void gemm64_atomic(const float* __restrict__ A, const float* __restrict__ Bm,
                   float* __restrict__ C, int N, int K, int KC) {
    __shared__ __align__(16) float sA[16][68];
    __shared__ __align__(16) float sB[16][68];
    const int tid = threadIdx.x;
    const int n0 = blockIdx.x * 64;
    const int kbase = blockIdx.z * KC;
    const int tr = (tid >> 4) << 2;
    const int tc = (tid & 15) << 2;
    float acc[4][4];
#pragma unroll
    for (int r = 0; r < 4; r++)
#pragma unroll
        for (int c = 0; c < 4; c++) acc[r][c] = 0.f;

    for (int k0 = 0; k0 < KC; k0 += 16) {
        for (int i = tid; i < 1024; i += 256) {
            int m = i >> 4, k = i & 15;
            sA[k][m] = A[(size_t)m * K + kbase + k0 + k];
        }
        for (int i = tid; i < 1024; i += 256) {
            int k = i >> 6, n = i & 63;
            sB[k][n] = Bm[(size_t)(kbase + k0 + k) * N + n0 + n];
        }
        __syncthreads();
#pragma unroll
        for (int k = 0; k < 16; k++) {
            float4 a = *(const float4*)&sA[k][tr];
            float4 bv = *(const float4*)&sB[k][tc];
            float av[4] = {a.x, a.y, a.z, a.w};
            float bb[4] = {bv.x, bv.y, bv.z, bv.w};
#pragma unroll
            for (int r = 0; r < 4; r++)
#pragma unroll
                for (int c = 0; c < 4; c++) acc[r][c] += av[r] * bb[c];
        }
        __syncthreads();
    }
#pragma unroll
    for (int r = 0; r < 4; r++)
#pragma unroll
        for (int c = 0; c < 4; c++)
            atomicAdd(&C[(size_t)(tr + r) * N + n0 + tc + c], acc[r][c]);
}

// dst[b*dstStride + dstOff + n] = relu(src[b*N + n] + bias[n])
__global__ void bias_relu_copy(const float* __restrict__ src, const float* __restrict__ bias,
                               float* __restrict__ dst, int N, int dstStride, int dstOff) {
    int idx = blockIdx.x * 256 + threadIdx.x;
    if (idx >= BATCH * N) return;
    int b = idx / N, n = idx % N;
    float v = src[idx] + bias[n];
    dst[(size_t)b * dstStride + dstOff + n] = v > 0.f ? v : 0.f;
}

// logits + temperature calibration
__global__ void logits_kernel(const float* __restrict__ fused, const float* __restrict__ Wc,
                              const float* __restrict__ bcls, const float* __restrict__ temp,
                              float* __restrict__ out) {
    int idx = threadIdx.x;
    if (idx >= 128) return;
    int b = idx >> 1, n = idx & 1;
    float s = bcls[n];
    const float* f = fused + (size_t)b * 512;
    for (int k = 0; k < 512; k++) s += f[k] * Wc[k * 2 + n];
    out[idx] = s;
    out[128 + idx] = s / temp[0];
}

// ============================================================================
extern "C" void kernel_launch(void* const* d_in, const int* in_sizes, int n_in,
                              void* d_out, int out_size, void* d_ws, size_t ws_size,
                              hipStream_t stream) {
    const float* x      = (const float*)d_in[0];
    const float* w_stem = (const float*)d_in[1];
    const float* b_stem = (const float*)d_in[2];
    const float* w1 = (const float*)d_in[3];   const float* b1 = (const float*)d_in[4];
    const float* w2 = (const float*)d_in[5];   const float* b2 = (const float*)d_in[6];
    const float* w3 = (const float*)d_in[7];   const float* b3 = (const float*)d_in[8];
    const float* wd1 = (const float*)d_in[9];  const float* bd1 = (const float*)d_in[10];
    const float* wd2 = (const float*)d_in[11]; const float* bd2 = (const float*)d_in[12];
    const float* wf1 = (const float*)d_in[13]; const float* bf1 = (const float*)d_in[14];
    const float* wf2 = (const float*)d_in[15]; const float* bf2 = (const float*)d_in[16];
    const float* W_freq = (const float*)d_in[17]; const float* b_freq = (const float*)d_in[18];
    const float* W_fu1  = (const float*)d_in[19]; const float* b_fu1  = (const float*)d_in[20];
    const float* W_fu2  = (const float*)d_in[21]; const float* b_fu2  = (const float*)d_in[22];
    const float* W_cls  = (const float*)d_in[23]; const float* b_cls  = (const float*)d_in[24];
    const float* temp   = (const float*)d_in[25];
    float* ws = (float*)d_ws;
    float* out = (float*)d_out;

    const size_t IMG2 = 224 * 224;           // 50176

    // ---- persistent (small) region ----
    size_t oWRE  = 0;
    size_t oWIM  = oWRE + IMG2;
    size_t oWSUM = oWIM + IMG2;
    size_t oDCT  = oWSUM + 288;
    size_t oDIMG = oDCT + (size_t)BATCH * 64;
    size_t oFREQIN  = oDIMG + (size_t)BATCH * IMG2;      // B*6272
    size_t oCOMB    = oFREQIN + (size_t)BATCH * 6272;    // B*1024
    size_t oFREQACC = oCOMB + (size_t)BATCH * 1024;      // B*512  (zeroed)
    size_t oFU1     = oFREQACC + (size_t)BATCH * 512;    // B*1024 (zeroed)
    size_t oFUSED   = oFU1 + (size_t)BATCH * 1024;       // B*512  (zeroed)
    size_t P        = oFUSED + (size_t)BATCH * 512;      // ~3.9M floats

    // ---- chunk regions: pick largest CB in {16,8,4,2,1} that fits ws_size ----
    // per-chunk floats: STEM CB*64*12544 + C1 CB*128*3136 + C2 CB*256*784 + C3 CB*512*196
    //                 = CB * 1,505,280
    int CB = 16;
    while (CB > 1 && (P + (size_t)CB * 1505280) * sizeof(float) > ws_size) CB >>= 1;
    size_t oSTEM = P;                                   // CB*802816
    size_t oC1   = oSTEM + (size_t)CB * 802816;         // CB*401408
    size_t oC2   = oC1 + (size_t)CB * 401408;           // CB*200704
    size_t oC3   = oC2 + (size_t)CB * 200704;           // CB*100352
    // FFT-phase aliases (dead before backbone uses the same bytes):
    size_t oT_re  = oSTEM;                              // CB*150528
    size_t oT_im  = oT_re + (size_t)CB * 150528;        // CB*150528
    size_t oFFTIN = oT_im + (size_t)CB * 150528;        // CB*301056 (<= STEM region)
    size_t oBIG1  = oC1;                                // CB*401408 (exact fit)
    size_t oBIG2  = oC2;                                // CB*200704 (exact fit)

    // ---- batch-independent prep ----
    make_dft<<<196, 256, 0, stream>>>(ws + oWRE, ws + oWIM);
    make_wsum<<<1, 288, 0, stream>>>(wd1, ws + oWSUM);
    dct_mean<<<BATCH, 256, 0, stream>>>(x, ws + oDCT);
    resize_bilinear<<<12544, 256, 0, stream>>>(ws + oDCT, ws + oDIMG);
    hipMemsetAsync(ws + oFREQACC, 0, (size_t)BATCH * (512 + 1024 + 512) * sizeof(float), stream);

    // ---- per-image pipeline in batch chunks ----
    for (int b0 = 0; b0 < BATCH; b0 += CB) {
        const float* xc = x + (size_t)b0 * 3 * IMG2;
        // FFT branch
        dft_stage1<<<dim3(49, 1, 3 * CB), 256, 0, stream>>>(
            xc, ws + oWRE, ws + oWIM, ws + oT_re, ws + oT_im);
        dft_stage2<<<dim3(49, 1, 3 * CB), 256, 0, stream>>>(
            ws + oWRE, ws + oWIM, ws + oT_re, ws + oT_im, ws + oFFTIN);
        conv3x3_s2<32, 8, 14, 6><<<dim3(112, 1, CB), 256, 0, stream>>>(
            ws + oFFTIN, wf1, bf1, ws + oBIG1, 6, 32, 224, 224, 112, 112);
        conv3x3_s2<64, 4, 14, 8><<<dim3(56, 1, CB), 256, 0, stream>>>(
            ws + oBIG1, wf2, bf2, ws + oBIG2, 32, 64, 112, 112, 56, 56);
        pool7<<<(CB * 64 * 49 + 255) / 256, 256, 0, stream>>>(
            ws + oBIG2, ws + oFREQIN + (size_t)b0 * 6272, 3136, CB * 64 * 49);
        // DCT branch
        conv3x3_s2<32, 8, 14, 1><<<dim3(112, 1, CB), 256, 0, stream>>>(
            ws + oDIMG + (size_t)b0 * IMG2, ws + oWSUM, bd1, ws + oBIG1, 1, 32, 224, 224, 112, 112);
        conv3x3_s2<64, 4, 14, 8><<<dim3(56, 1, CB), 256, 0, stream>>>(
            ws + oBIG1, wd2, bd2, ws + oBIG2, 32, 64, 112, 112, 56, 56);
        pool7<<<(CB * 64 * 49 + 255) / 256, 256, 0, stream>>>(
            ws + oBIG2, ws + oFREQIN + (size_t)b0 * 6272, 0, CB * 64 * 49);
        // backbone (overwrites FFT aliases — dead by now)
        conv7x7_s2<<<dim3(224, 1, CB), 256, 0, stream>>>(xc, w_stem, b_stem, ws + oSTEM);
        conv3x3_s2<64, 4, 14, 8><<<dim3(56, 2, CB), 256, 0, stream>>>(
            ws + oSTEM, w1, b1, ws + oC1, 64, 128, 112, 112, 56, 56);
        conv3x3_s2<64, 4, 14, 8><<<dim3(14, 4, CB), 256, 0, stream>>>(
            ws + oC1, w2, b2, ws + oC2, 128, 256, 56, 56, 28, 28);
        conv3x3_s2<64, 2, 14, 8><<<dim3(7, 8, CB), 128, 0, stream>>>(
            ws + oC2, w3, b3, ws + oC3, 256, 512, 28, 28, 14, 14);
        gap_kernel<<<(CB * 512 * 64 + 255) / 256, 256, 0, stream>>>(
            ws + oC3, ws + oCOMB + (size_t)b0 * 1024, CB * 512);
    }

    // ---- fusion ----
    gemm64_atomic<<<dim3(8, 1, 8), 256, 0, stream>>>(ws + oFREQIN, W_freq, ws + oFREQACC,
                                                     512, 6272, 784);
    bias_relu_copy<<<128, 256, 0, stream>>>(ws + oFREQACC, b_freq, ws + oCOMB, 512, 1024, 512);
    gemm64_atomic<<<dim3(16, 1, 4), 256, 0, stream>>>(ws + oCOMB, W_fu1, ws + oFU1,
                                                      1024, 1024, 256);
    bias_relu_copy<<<256, 256, 0, stream>>>(ws + oFU1, b_fu1, ws + oFU1, 1024, 1024, 0);
    gemm64_atomic<<<dim3(8, 1, 4), 256, 0, stream>>>(ws + oFU1, W_fu2, ws + oFUSED,
                                                     512, 1024, 256);
    bias_relu_copy<<<128, 256, 0, stream>>>(ws + oFUSED, b_fu2, ws + oFUSED, 512, 512, 0);
    logits_kernel<<<1, 128, 0, stream>>>(ws + oFUSED, W_cls, b_cls, temp, out);
}

// Round 3
// 3176.948 us; speedup vs baseline: 1.8753x; 1.8753x over previous
//
#include <hip/hip_runtime.h>

#ifndef M_PI
#define M_PI 3.14159265358979323846
#endif

// ============================================================================
// EnhancedAIDetector — round 3: backbone conv1/2/3 -> MFMA implicit GEMM
// (bf16 hi/lo split x3 for fp32-grade accuracy). Stem + branch convs + DFT
// remain fp32 direct. Activations between backbone convs stored as packed
// {bf16 hi, bf16 lo} uint32. Batch-chunked workspace (adaptive CB).
// ============================================================================

#define BATCH 64

typedef __bf16 bf16x8 __attribute__((ext_vector_type(8)));
typedef float f32x4 __attribute__((ext_vector_type(4)));

__device__ __forceinline__ unsigned short f2bf(float f) {
    unsigned u = __float_as_uint(f);
    u += 0x7FFF + ((u >> 16) & 1);      // RNE
    return (unsigned short)(u >> 16);
}
__device__ __forceinline__ unsigned packsplit(float v) {
    unsigned short h = f2bf(v);
    float hf = __uint_as_float(((unsigned)h) << 16);
    unsigned short l = f2bf(v - hf);
    return (((unsigned)h) << 16) | (unsigned)l;
}

union U8frag { bf16x8 v; unsigned d[4]; };

// unpack 8 packed dwords at p (LDS) -> hi fragment + lo fragment
__device__ __forceinline__ void unpack8(const unsigned* p, bf16x8& hi, bf16x8& lo) {
    uint4 a = *(const uint4*)p;
    uint4 b = *(const uint4*)(p + 4);
    U8frag H, L;
    H.d[0] = __builtin_amdgcn_perm(a.y, a.x, 0x07060302u);
    L.d[0] = __builtin_amdgcn_perm(a.y, a.x, 0x05040100u);
    H.d[1] = __builtin_amdgcn_perm(a.w, a.z, 0x07060302u);
    L.d[1] = __builtin_amdgcn_perm(a.w, a.z, 0x05040100u);
    H.d[2] = __builtin_amdgcn_perm(b.y, b.x, 0x07060302u);
    L.d[2] = __builtin_amdgcn_perm(b.y, b.x, 0x05040100u);
    H.d[3] = __builtin_amdgcn_perm(b.w, b.z, 0x07060302u);
    L.d[3] = __builtin_amdgcn_perm(b.w, b.z, 0x05040100u);
    hi = H.v; lo = L.v;
}

// ============================================================================
// Weight prep: fp32 [Co][Ci][3][3] -> packed split [9][Co][Ci]
// ============================================================================
__global__ void prep_w(const float* __restrict__ w, unsigned* __restrict__ dst,
                       int Co, int Ci) {
    int idx = blockIdx.x * 256 + threadIdx.x;
    int tot = Co * Ci * 9;
    if (idx >= tot) return;
    int k9 = idx % 9;
    int rest = idx / 9;
    int ci = rest % Ci, co = rest / Ci;
    dst[((size_t)k9 * Co + co) * Ci + ci] = packsplit(w[idx]);
}

// ============================================================================
// MFMA implicit-GEMM 3x3 stride-2 conv (SAME, even input: pad lo=0, hi=1).
// Block: 256 thr = 4 waves; tile 128co x 64n; K-chunk 32 over ci, outer (ky,kx).
// inP: packed [CB][Ci][Hin][Win]; wP: packed [9][Co][Ci].
// mode 0: out = relu(acc+bias) packed -> outPk. mode 1: raw fp32 acc -> outF{0,1} by z.
// ============================================================================
__global__ __launch_bounds__(256)
void conv3x3s2_mfma(const unsigned* __restrict__ inP, const unsigned* __restrict__ wP,
                    const float* __restrict__ bias,
                    unsigned* __restrict__ outPk, float* __restrict__ outF0,
                    float* __restrict__ outF1,
                    int Ci, int Co, int Hin, int Win, int Hout, int Wout,
                    int NTOT, int ciPer, int mode) {
    __shared__ unsigned sA[128 * 36];
    __shared__ unsigned sB[64 * 36];
    const int tid = threadIdx.x;
    const int wv = tid >> 6, lane = tid & 63;
    const int ciBeg = blockIdx.z * ciPer;
    const int coT0 = blockIdx.y * 128;
    const int HWin = Hin * Win, HWout = Hout * Wout;

    // B-gather identity: LDS row n_local = tid>>2, k-quarter = tid&3
    const int nG = blockIdx.x * 64 + (tid >> 2);
    const int kqB = tid & 3;
    int bb = 0, yy = 0, xx = 0;
    bool nval = nG < NTOT;
    if (nval) {
        bb = nG / HWout;
        int rem = nG - bb * HWout;
        yy = rem / Wout;
        xx = rem - yy * Wout;
    }
    const unsigned baseImg = (unsigned)bb * Ci * HWin;

    // A staging identity: co row = tid>>1, ci half = tid&1
    const int coA = tid >> 1, halfA = tid & 1;

    f32x4 acc[2][4];
#pragma unroll
    for (int s = 0; s < 2; s++)
#pragma unroll
        for (int t = 0; t < 4; t++) acc[s][t] = (f32x4){0.f, 0.f, 0.f, 0.f};

    for (int k9 = 0; k9 < 9; k9++) {
        int ky = k9 / 3, kx = k9 - ky * 3;
        int iy = 2 * yy + ky, ix = 2 * xx + kx;
        bool bval = nval && iy < Hin && ix < Win;
        unsigned off0 = baseImg + (unsigned)iy * Win + (unsigned)ix;
        const unsigned* wbase = wP + ((size_t)k9 * Co + coT0 + coA) * Ci + ciBeg + halfA * 16;

        for (int c0 = 0; c0 < ciPer; c0 += 32) {
            __syncthreads();
            // stage A: 16 dwords per thread (weights, contiguous)
            {
                const uint4* g = (const uint4*)(wbase + c0);
                uint4 v0 = g[0], v1 = g[1], v2 = g[2], v3 = g[3];
                uint4* d = (uint4*)(sA + coA * 36 + halfA * 16);
                d[0] = v0; d[1] = v1; d[2] = v2; d[3] = v3;
            }
            // stage B: 8 gathered dwords per thread
            {
                unsigned u[8];
                const unsigned cbase = off0 + (unsigned)(ciBeg + c0 + kqB * 8) * HWin;
#pragma unroll
                for (int j = 0; j < 8; j++)
                    u[j] = bval ? inP[cbase + (unsigned)j * HWin] : 0u;
                uint4* d = (uint4*)(sB + (tid >> 2) * 36 + kqB * 8);
                uint4 w0; w0.x = u[0]; w0.y = u[1]; w0.z = u[2]; w0.w = u[3];
                uint4 w1; w1.x = u[4]; w1.y = u[5]; w1.z = u[6]; w1.w = u[7];
                d[0] = w0; d[1] = w1;
            }
            __syncthreads();

            bf16x8 ah[2], al[2], bh[4], bl[4];
            const int m = lane & 15, q = lane >> 4;
#pragma unroll
            for (int s = 0; s < 2; s++)
                unpack8(sA + (wv * 32 + s * 16 + m) * 36 + q * 8, ah[s], al[s]);
#pragma unroll
            for (int t = 0; t < 4; t++)
                unpack8(sB + (t * 16 + m) * 36 + q * 8, bh[t], bl[t]);

#pragma unroll
            for (int s = 0; s < 2; s++)
#pragma unroll
                for (int t = 0; t < 4; t++)
                    acc[s][t] = __builtin_amdgcn_mfma_f32_16x16x32_bf16(ah[s], bh[t], acc[s][t], 0, 0, 0);
#pragma unroll
            for (int s = 0; s < 2; s++)
#pragma unroll
                for (int t = 0; t < 4; t++)
                    acc[s][t] = __builtin_amdgcn_mfma_f32_16x16x32_bf16(ah[s], bl[t], acc[s][t], 0, 0, 0);
#pragma unroll
            for (int s = 0; s < 2; s++)
#pragma unroll
                for (int t = 0; t < 4; t++)
                    acc[s][t] = __builtin_amdgcn_mfma_f32_16x16x32_bf16(al[s], bh[t], acc[s][t], 0, 0, 0);
        }
    }

    // epilogue: D[row=co_local][col=n_local], col=lane&15, row=(lane>>4)*4+reg
    const int m = lane & 15, q = lane >> 4;
#pragma unroll
    for (int t = 0; t < 4; t++) {
        int n_g = blockIdx.x * 64 + t * 16 + m;
        if (n_g >= NTOT) continue;
        int b = n_g / HWout;
        int rem = n_g - b * HWout;
        size_t nb = (size_t)b * Co * HWout + rem;
#pragma unroll
        for (int s = 0; s < 2; s++) {
            int co_l = wv * 32 + s * 16 + q * 4;
#pragma unroll
            for (int r = 0; r < 4; r++) {
                int co_g = coT0 + co_l + r;
                float v = acc[s][t][r];
                size_t addr = nb + (size_t)co_g * HWout;
                if (mode == 0) {
                    v += bias[co_g];
                    v = v > 0.f ? v : 0.f;
                    outPk[addr] = packsplit(v);
                } else {
                    (blockIdx.z == 0 ? outF0 : outF1)[addr] = v;
                }
            }
        }
    }
}

// ============================================================================
// DFT matrix:  W[j,k] = exp(-2*pi*i * j*k / 224)
// ============================================================================
__global__ void make_dft(float* __restrict__ wre, float* __restrict__ wim) {
    int idx = blockIdx.x * 256 + threadIdx.x;
    if (idx >= 224 * 224) return;
    int j = idx / 224, k = idx % 224;
    int m = (j * k) % 224;
    double a = -2.0 * M_PI * (double)m / 224.0;
    wre[idx] = (float)cos(a);
    wim[idx] = (float)sin(a);
}

__global__ void make_wsum(const float* __restrict__ wd1, float* __restrict__ wsum) {
    int idx = threadIdx.x;
    if (idx >= 288) return;
    int o = idx / 9, k = idx % 9;
    wsum[idx] = wd1[o * 27 + k] + wd1[o * 27 + 9 + k] + wd1[o * 27 + 18 + k];
}

// ============================================================================
// DFT stage 1: T = X @ W
// ============================================================================
__global__ __launch_bounds__(256)
void dft_stage1(const float* __restrict__ x, const float* __restrict__ wre,
                const float* __restrict__ wim, float* __restrict__ tre,
                float* __restrict__ tim) {
    const int N = 224;
    const int bc = blockIdx.z;
    const float* X = x + (size_t)bc * N * N;
    float* Tre = tre + (size_t)bc * N * N;
    float* Tim = tim + (size_t)bc * N * N;
    const int tile = blockIdx.x;
    const int tr0 = (tile / 7) * 32, tc0 = (tile % 7) * 32;
    const int tid = threadIdx.x;
    const int rl = tid >> 3;
    const int cl = (tid & 7) << 2;

    __shared__ __align__(16) float sA[32][17];
    __shared__ __align__(16) float sBre[16][32];
    __shared__ __align__(16) float sBim[16][32];

    float ar[4] = {0, 0, 0, 0}, ai[4] = {0, 0, 0, 0};
    for (int k0 = 0; k0 < N; k0 += 16) {
        for (int i = tid; i < 512; i += 256) {
            int r = i >> 4, k = i & 15;
            sA[r][k] = X[(size_t)(tr0 + r) * N + k0 + k];
        }
        for (int i = tid; i < 512; i += 256) {
            int k = i >> 5, c = i & 31;
            sBre[k][c] = wre[(size_t)(k0 + k) * N + tc0 + c];
            sBim[k][c] = wim[(size_t)(k0 + k) * N + tc0 + c];
        }
        __syncthreads();
#pragma unroll
        for (int k = 0; k < 16; k++) {
            float a = sA[rl][k];
            float4 br = *(const float4*)&sBre[k][cl];
            float4 bi = *(const float4*)&sBim[k][cl];
            ar[0] += a * br.x; ar[1] += a * br.y; ar[2] += a * br.z; ar[3] += a * br.w;
            ai[0] += a * bi.x; ai[1] += a * bi.y; ai[2] += a * bi.z; ai[3] += a * bi.w;
        }
        __syncthreads();
    }
    int r = tr0 + rl, c = tc0 + cl;
    float4 vr = {ar[0], ar[1], ar[2], ar[3]};
    float4 vi = {ai[0], ai[1], ai[2], ai[3]};
    *(float4*)&Tre[(size_t)r * N + c] = vr;
    *(float4*)&Tim[(size_t)r * N + c] = vi;
}

// ============================================================================
// DFT stage 2: Y = W @ T -> fft_in
// ============================================================================
__global__ __launch_bounds__(256)
void dft_stage2(const float* __restrict__ wre, const float* __restrict__ wim,
                const float* __restrict__ tre, const float* __restrict__ tim,
                float* __restrict__ fft_in) {
    const int N = 224;
    const int bc = blockIdx.z;
    const int b = bc / 3, c = bc % 3;
    const float* Tre = tre + (size_t)bc * N * N;
    const float* Tim = tim + (size_t)bc * N * N;
    const int tile = blockIdx.x;
    const int tm0 = (tile / 7) * 32, tn0 = (tile % 7) * 32;
    const int tid = threadIdx.x;
    const int rl = tid >> 3;
    const int cl = (tid & 7) << 2;

    __shared__ __align__(16) float sWre[32][17];
    __shared__ __align__(16) float sWim[32][17];
    __shared__ __align__(16) float sTre[16][32];
    __shared__ __align__(16) float sTim[16][32];

    float yr[4] = {0, 0, 0, 0}, yi[4] = {0, 0, 0, 0};
    for (int k0 = 0; k0 < N; k0 += 16) {
        for (int i = tid; i < 512; i += 256) {
            int r = i >> 4, k = i & 15;
            sWre[r][k] = wre[(size_t)(tm0 + r) * N + k0 + k];
            sWim[r][k] = wim[(size_t)(tm0 + r) * N + k0 + k];
        }
        for (int i = tid; i < 512; i += 256) {
            int k = i >> 5, cc = i & 31;
            sTre[k][cc] = Tre[(size_t)(k0 + k) * N + tn0 + cc];
            sTim[k][cc] = Tim[(size_t)(k0 + k) * N + tn0 + cc];
        }
        __syncthreads();
#pragma unroll
        for (int k = 0; k < 16; k++) {
            float wr_ = sWre[rl][k], wi_ = sWim[rl][k];
            float4 t4 = *(const float4*)&sTre[k][cl];
            float4 u4 = *(const float4*)&sTim[k][cl];
            yr[0] += wr_ * t4.x - wi_ * u4.x;  yi[0] += wr_ * u4.x + wi_ * t4.x;
            yr[1] += wr_ * t4.y - wi_ * u4.y;  yi[1] += wr_ * u4.y + wi_ * t4.y;
            yr[2] += wr_ * t4.z - wi_ * u4.z;  yi[2] += wr_ * u4.z + wi_ * t4.z;
            yr[3] += wr_ * t4.w - wi_ * u4.w;  yi[3] += wr_ * u4.w + wi_ * t4.w;
        }
        __syncthreads();
    }
    int m = tm0 + rl, n = tn0 + cl;
    float4 vr = {yr[0], yr[1], yr[2], yr[3]};
    float4 vi = {yi[0], yi[1], yi[2], yi[3]};
    *(float4*)&fft_in[((size_t)(b * 6 + 2 * c) * N + m) * N + n] = vr;
    *(float4*)&fft_in[((size_t)(b * 6 + 2 * c + 1) * N + m) * N + n] = vi;
}

// ============================================================================
// fp32 direct 3x3 s2 conv (branch convs only now)
// ============================================================================
template <int CO_BLK, int TH, int TW, int CI_CHUNK>
__global__ __launch_bounds__(CO_BLK * TH)
void conv3x3_s2(const float* __restrict__ in, const float* __restrict__ w,
                const float* __restrict__ bias, float* __restrict__ out,
                int Ci, int Co, int Hin, int Win, int Hout, int Wout) {
    constexpr int IN_H = 2 * TH + 1;
    constexpr int IN_W = 2 * TW + 1;
    constexpr int IN_WP = 32;
    constexpr int WSTR = (CI_CHUNK * 9) | 1;
    __shared__ __align__(16) float s_in[CI_CHUNK][IN_H][IN_WP];
    __shared__ float s_w[CO_BLK * WSTR];

    const int tid = threadIdx.x;
    const int tiles_x = Wout / TW;
    const int tile = blockIdx.x;
    const int ty0 = (tile / tiles_x) * TH;
    const int tx0 = (tile % tiles_x) * TW;
    const int cog = blockIdx.y;
    const int b = blockIdx.z;
    const int co = tid % CO_BLK;
    const int ty = tid / CO_BLK;
    const int co_g = cog * CO_BLK + co;

    float acc[TW];
#pragma unroll
    for (int i = 0; i < TW; i++) acc[i] = 0.f;

    const float* in_b = in + (size_t)b * Ci * Hin * Win;
    const int iy0 = 2 * ty0, ix0 = 2 * tx0;

    for (int ci0 = 0; ci0 < Ci; ci0 += CI_CHUNK) {
        for (int idx = tid; idx < CI_CHUNK * IN_H * IN_W; idx += CO_BLK * TH) {
            int ci = idx / (IN_H * IN_W);
            int rem = idx % (IN_H * IN_W);
            int r = rem / IN_W, cc = rem % IN_W;
            int gy = iy0 + r, gx = ix0 + cc;
            float v = 0.f;
            if (gy < Hin && gx < Win)
                v = in_b[(size_t)(ci0 + ci) * Hin * Win + (size_t)gy * Win + gx];
            s_in[ci][r][cc] = v;
        }
        for (int idx = tid; idx < CO_BLK * CI_CHUNK * 9; idx += CO_BLK * TH) {
            int c = idx / (CI_CHUNK * 9);
            int k = idx % (CI_CHUNK * 9);
            s_w[c * WSTR + k] = w[((size_t)(cog * CO_BLK + c) * Ci + ci0) * 9 + k];
        }
        __syncthreads();

#pragma unroll
        for (int ci = 0; ci < CI_CHUNK; ci++) {
            float wr[9];
#pragma unroll
            for (int k = 0; k < 9; k++) wr[k] = s_w[co * WSTR + ci * 9 + k];
#pragma unroll
            for (int ky = 0; ky < 3; ky++) {
                float r[IN_WP];
                const float4* rowp = (const float4*)&s_in[ci][2 * ty + ky][0];
#pragma unroll
                for (int qq = 0; qq < IN_WP / 4; qq++) {
                    float4 v = rowp[qq];
                    r[4 * qq] = v.x; r[4 * qq + 1] = v.y; r[4 * qq + 2] = v.z; r[4 * qq + 3] = v.w;
                }
#pragma unroll
                for (int kx = 0; kx < 3; kx++) {
                    float wv = wr[ky * 3 + kx];
#pragma unroll
                    for (int xq = 0; xq < TW; xq++) acc[xq] += r[2 * xq + kx] * wv;
                }
            }
        }
        __syncthreads();
    }
    float bb = bias[co_g];
    float* outp = out + ((size_t)b * Co + co_g) * Hout * Wout + (size_t)(ty0 + ty) * Wout + tx0;
#pragma unroll
    for (int xq = 0; xq < TW; xq++) {
        float v = acc[xq] + bb;
        outp[xq] = v > 0.f ? v : 0.f;
    }
}

// ============================================================================
// Stem: 7x7 s2, Cin=3, Cout=64, 224->112; epilogue writes PACKED split bf16.
// ============================================================================
__global__ __launch_bounds__(256)
void conv7x7_s2_pack(const float* __restrict__ in, const float* __restrict__ w,
                     const float* __restrict__ bias, unsigned* __restrict__ out) {
    constexpr int TH = 4, TW = 14;
    constexpr int IN_H = 13, IN_W = 33, IN_WP = 36, WSTR = 149;
    __shared__ __align__(16) float s_in[3][IN_H][IN_WP];
    __shared__ float s_w[64 * WSTR];
    const int tid = threadIdx.x;
    const int tile = blockIdx.x;
    const int tiles_x = 112 / TW;
    const int ty0 = (tile / tiles_x) * TH;
    const int tx0 = (tile % tiles_x) * TW;
    const int b = blockIdx.z;
    const int co = tid & 63;
    const int ty = tid >> 6;

    const float* in_b = in + (size_t)b * 3 * 224 * 224;
    const int iy0 = 2 * ty0 - 2, ix0 = 2 * tx0 - 2;

    for (int idx = tid; idx < 3 * IN_H * IN_W; idx += 256) {
        int ci = idx / (IN_H * IN_W);
        int rem = idx % (IN_H * IN_W);
        int r = rem / IN_W, cc = rem % IN_W;
        int gy = iy0 + r, gx = ix0 + cc;
        float v = 0.f;
        if (gy >= 0 && gy < 224 && gx >= 0 && gx < 224)
            v = in_b[(size_t)ci * 224 * 224 + (size_t)gy * 224 + gx];
        s_in[ci][r][cc] = v;
    }
    for (int idx = tid; idx < 64 * 147; idx += 256) {
        int c = idx / 147, k = idx % 147;
        s_w[c * WSTR + k] = w[c * 147 + k];
    }
    __syncthreads();

    float acc[TW];
#pragma unroll
    for (int i = 0; i < TW; i++) acc[i] = 0.f;

#pragma unroll
    for (int ci = 0; ci < 3; ci++) {
#pragma unroll
        for (int ky = 0; ky < 7; ky++) {
            float wr[7];
#pragma unroll
            for (int k = 0; k < 7; k++) wr[k] = s_w[co * WSTR + ci * 49 + ky * 7 + k];
            float r[IN_WP];
            const float4* rowp = (const float4*)&s_in[ci][2 * ty + ky][0];
#pragma unroll
            for (int qq = 0; qq < IN_WP / 4; qq++) {
                float4 v = rowp[qq];
                r[4 * qq] = v.x; r[4 * qq + 1] = v.y; r[4 * qq + 2] = v.z; r[4 * qq + 3] = v.w;
            }
#pragma unroll
            for (int kx = 0; kx < 7; kx++) {
                float wv = wr[kx];
#pragma unroll
                for (int xq = 0; xq < TW; xq++) acc[xq] += r[2 * xq + kx] * wv;
            }
        }
    }
    float bb = bias[co];
    unsigned* outp = out + ((size_t)b * 64 + co) * 112 * 112 + (size_t)(ty0 + ty) * 112 + tx0;
#pragma unroll
    for (int xq = 0; xq < TW; xq++) {
        float v = acc[xq] + bb;
        v = v > 0.f ? v : 0.f;
        outp[xq] = packsplit(v);
    }
}

// ============================================================================
// DCT branch: linearity collapse + resize
// ============================================================================
__device__ __forceinline__ float dct_coef(int u, int i) {
    if (u == 0) return 0.35355339059327373f;
    return 0.5f * cosf((float)M_PI * (float)((2 * i + 1) * u) / 16.0f);
}

__global__ __launch_bounds__(256)
void dct_mean(const float* __restrict__ x, float* __restrict__ dct_out) {
    __shared__ float red[256];
    __shared__ float Mb[64];
    const int b = blockIdx.x;
    const int tid = threadIdx.x;
    const int ij = tid & 63;
    const int grp = tid >> 6;
    const int i = ij >> 3, j = ij & 7;
    const float* xb = x + (size_t)b * 3 * 224 * 224;
    float s = 0.f;
    for (int blk = grp; blk < 784; blk += 4) {
        int m = blk / 28, n = blk % 28;
        int p = m * 8 + i, q = n * 8 + j;
        size_t o = (size_t)p * 224 + q;
        s += (0.299f * xb[o] + 0.587f * xb[224 * 224 + o] + 0.114f * xb[2 * 224 * 224 + o]) * 255.f;
    }
    red[tid] = s;
    __syncthreads();
    if (tid < 64)
        Mb[tid] = (red[tid] + red[tid + 64] + red[tid + 128] + red[tid + 192]) * (1.f / 784.f);
    __syncthreads();
    if (tid < 64) {
        int u = tid >> 3, v = tid & 7;
        float acc = 0.f;
#pragma unroll
        for (int i2 = 0; i2 < 8; i2++) {
            float du = dct_coef(u, i2);
#pragma unroll
            for (int j2 = 0; j2 < 8; j2++) acc += du * Mb[i2 * 8 + j2] * dct_coef(v, j2);
        }
        dct_out[b * 64 + tid] = acc;
    }
}

__global__ void resize_bilinear(const float* __restrict__ dct, float* __restrict__ out) {
    int idx = blockIdx.x * 256 + threadIdx.x;
    if (idx >= BATCH * 224 * 224) return;
    int b = idx / (224 * 224);
    int rem = idx % (224 * 224);
    int y = rem / 224, xx = rem % 224;
    float sy = fminf(fmaxf((y + 0.5f) * (1.f / 28.f) - 0.5f, 0.f), 7.f);
    float sx = fminf(fmaxf((xx + 0.5f) * (1.f / 28.f) - 0.5f, 0.f), 7.f);
    int y0 = (int)floorf(sy); if (y0 > 6) y0 = 6;
    int x0 = (int)floorf(sx); if (x0 > 6) x0 = 6;
    float ty = sy - y0, tx = sx - x0;
    const float* M = dct + b * 64;
    float v00 = M[y0 * 8 + x0], v01 = M[y0 * 8 + x0 + 1];
    float v10 = M[(y0 + 1) * 8 + x0], v11 = M[(y0 + 1) * 8 + x0 + 1];
    out[idx] = (1.f - ty) * ((1.f - tx) * v00 + tx * v01) + ty * ((1.f - tx) * v10 + tx * v11);
}

// ============================================================================
// Pooling
// ============================================================================
__global__ void pool7(const float* __restrict__ h, float* __restrict__ out,
                      int col_base, int n) {
    int idx = blockIdx.x * 256 + threadIdx.x;
    if (idx >= n) return;
    int b = idx / (64 * 49);
    int rem = idx % (64 * 49);
    int c = rem / 49;
    int ij = rem % 49;
    int i = ij / 7, j = ij % 7;
    const float* hp = h + ((size_t)(b * 64 + c)) * 56 * 56 + (size_t)i * 8 * 56 + j * 8;
    float s = 0.f;
#pragma unroll
    for (int r = 0; r < 8; r++)
#pragma unroll
        for (int q = 0; q < 8; q++) s += hp[r * 56 + q];
    out[(size_t)b * 6272 + col_base + c * 49 + ij] = s * (1.f / 64.f);
}

// GAP over conv3 split halves: relu(a + b + bias) then mean 196
__global__ void gap2_kernel(const float* __restrict__ ha, const float* __restrict__ hb,
                            const float* __restrict__ bias, float* __restrict__ comb,
                            int nwaves) {
    int gt = blockIdx.x * blockDim.x + threadIdx.x;
    int wid = gt >> 6;
    int lane = gt & 63;
    if (wid >= nwaves) return;
    int b = wid / 512, c = wid % 512;
    const float* pa = ha + (size_t)wid * 196;
    const float* pb = hb + (size_t)wid * 196;
    float bbv = bias[c];
    float s = 0.f;
    for (int i = lane; i < 196; i += 64) {
        float v = pa[i] + pb[i] + bbv;
        s += v > 0.f ? v : 0.f;
    }
#pragma unroll
    for (int off = 32; off > 0; off >>= 1) s += __shfl_down(s, off);
    if (lane == 0) comb[(size_t)b * 1024 + c] = s * (1.f / 196.f);
}

// ============================================================================
// Fusion GEMMs (fp32, M=64, split-K atomic)
// ============================================================================
__global__ __launch_bounds__(256)
void gemm64_atomic(const float* __restrict__ A, const float* __restrict__ Bm,
                   float* __restrict__ C, int N, int K, int KC) {
    __shared__ __align__(16) float sA[16][68];
    __shared__ __align__(16) float sB[16][68];
    const int tid = threadIdx.x;
    const int n0 = blockIdx.x * 64;
    const int kbase = blockIdx.z * KC;
    const int tr = (tid >> 4) << 2;
    const int tc = (tid & 15) << 2;
    float acc[4][4];
#pragma unroll
    for (int r = 0; r < 4; r++)
#pragma unroll
        for (int c = 0; c < 4; c++) acc[r][c] = 0.f;

    for (int k0 = 0; k0 < KC; k0 += 16) {
        for (int i = tid; i < 1024; i += 256) {
            int m = i >> 4, k = i & 15;
            sA[k][m] = A[(size_t)m * K + kbase + k0 + k];
        }
        for (int i = tid; i < 1024; i += 256) {
            int k = i >> 6, n = i & 63;
            sB[k][n] = Bm[(size_t)(kbase + k0 + k) * N + n0 + n];
        }
        __syncthreads();
#pragma unroll
        for (int k = 0; k < 16; k++) {
            float4 a = *(const float4*)&sA[k][tr];
            float4 bv = *(const float4*)&sB[k][tc];
            float av[4] = {a.x, a.y, a.z, a.w};
            float bb[4] = {bv.x, bv.y, bv.z, bv.w};
#pragma unroll
            for (int r = 0; r < 4; r++)
#pragma unroll
                for (int c = 0; c < 4; c++) acc[r][c] += av[r] * bb[c];
        }
        __syncthreads();
    }
#pragma unroll
    for (int r = 0; r < 4; r++)
#pragma unroll
        for (int c = 0; c < 4; c++)
            atomicAdd(&C[(size_t)(tr + r) * N + n0 + tc + c], acc[r][c]);
}

__global__ void bias_relu_copy(const float* __restrict__ src, const float* __restrict__ bias,
                               float* __restrict__ dst, int N, int dstStride, int dstOff) {
    int idx = blockIdx.x * 256 + threadIdx.x;
    if (idx >= BATCH * N) return;
    int b = idx / N, n = idx % N;
    float v = src[idx] + bias[n];
    dst[(size_t)b * dstStride + dstOff + n] = v > 0.f ? v : 0.f;
}

__global__ void logits_kernel(const float* __restrict__ fused, const float* __restrict__ Wc,
                              const float* __restrict__ bcls, const float* __restrict__ temp,
                              float* __restrict__ out) {
    int idx = threadIdx.x;
    if (idx >= 128) return;
    int b = idx >> 1, n = idx & 1;
    float s = bcls[n];
    const float* f = fused + (size_t)b * 512;
    for (int k = 0; k < 512; k++) s += f[k] * Wc[k * 2 + n];
    out[idx] = s;
    out[128 + idx] = s / temp[0];
}

// ============================================================================
extern "C" void kernel_launch(void* const* d_in, const int* in_sizes, int n_in,
                              void* d_out, int out_size, void* d_ws, size_t ws_size,
                              hipStream_t stream) {
    const float* x      = (const float*)d_in[0];
    const float* w_stem = (const float*)d_in[1];
    const float* b_stem = (const float*)d_in[2];
    const float* w1 = (const float*)d_in[3];   const float* b1 = (const float*)d_in[4];
    const float* w2 = (const float*)d_in[5];   const float* b2 = (const float*)d_in[6];
    const float* w3 = (const float*)d_in[7];   const float* b3 = (const float*)d_in[8];
    const float* wd1 = (const float*)d_in[9];  const float* bd1 = (const float*)d_in[10];
    const float* wd2 = (const float*)d_in[11]; const float* bd2 = (const float*)d_in[12];
    const float* wf1 = (const float*)d_in[13]; const float* bf1 = (const float*)d_in[14];
    const float* wf2 = (const float*)d_in[15]; const float* bf2 = (const float*)d_in[16];
    const float* W_freq = (const float*)d_in[17]; const float* b_freq = (const float*)d_in[18];
    const float* W_fu1  = (const float*)d_in[19]; const float* b_fu1  = (const float*)d_in[20];
    const float* W_fu2  = (const float*)d_in[21]; const float* b_fu2  = (const float*)d_in[22];
    const float* W_cls  = (const float*)d_in[23]; const float* b_cls  = (const float*)d_in[24];
    const float* temp   = (const float*)d_in[25];
    float* ws = (float*)d_ws;
    float* out = (float*)d_out;

    const size_t IMG2 = 224 * 224;

    // ---- persistent region (dword offsets) ----
    size_t oWRE  = 0;
    size_t oWIM  = oWRE + IMG2;
    size_t oWSUM = oWIM + IMG2;
    size_t oDCT  = oWSUM + 288;
    size_t oDIMG = oDCT + (size_t)BATCH * 64;
    size_t oFREQIN  = oDIMG + (size_t)BATCH * IMG2;
    size_t oCOMB    = oFREQIN + (size_t)BATCH * 6272;
    size_t oFREQACC = oCOMB + (size_t)BATCH * 1024;
    size_t oFU1     = oFREQACC + (size_t)BATCH * 512;
    size_t oFUSED   = oFU1 + (size_t)BATCH * 1024;
    size_t oW1s     = oFUSED + (size_t)BATCH * 512;      // 9*128*64
    size_t oW2s     = oW1s + 73728;                      // 9*256*128
    size_t oW3s     = oW2s + 294912;                     // 9*512*256
    size_t P        = oW3s + 1179648;                    // 5,462,304 dwords

    // ---- chunk region: CB*1,605,632 dwords ----
    int CB = 16;
    while (CB > 1 && (P + (size_t)CB * 1605632) * 4 > ws_size) CB >>= 1;
    size_t base   = P;
    size_t oSTEMP = base;                                // CB*802816 (packed)
    size_t oC1P   = oSTEMP + (size_t)CB * 802816;        // CB*401408 (packed)
    size_t oC2P   = oC1P + (size_t)CB * 401408;          // CB*200704 (packed)
    size_t oC3a   = oC2P + (size_t)CB * 200704;          // CB*100352 fp32
    size_t oC3b   = oC3a + (size_t)CB * 100352;          // CB*100352 fp32
    // FFT-phase aliases (dead before backbone writes):
    size_t oT_re  = base;
    size_t oT_im  = oT_re + (size_t)CB * 150528;
    size_t oFFTIN = oT_im + (size_t)CB * 150528;         // CB*301056
    size_t oBIG1  = base + (size_t)CB * 602112;          // CB*401408
    size_t oBIG2  = base + (size_t)CB * 1003520;         // CB*200704

    unsigned* W1s = (unsigned*)(ws + oW1s);
    unsigned* W2s = (unsigned*)(ws + oW2s);
    unsigned* W3s = (unsigned*)(ws + oW3s);
    unsigned* STEMP = (unsigned*)(ws + oSTEMP);
    unsigned* C1P   = (unsigned*)(ws + oC1P);
    unsigned* C2P   = (unsigned*)(ws + oC2P);

    // ---- batch-independent prep ----
    make_dft<<<196, 256, 0, stream>>>(ws + oWRE, ws + oWIM);
    make_wsum<<<1, 288, 0, stream>>>(wd1, ws + oWSUM);
    prep_w<<<(128 * 64 * 9 + 255) / 256, 256, 0, stream>>>(w1, W1s, 128, 64);
    prep_w<<<(256 * 128 * 9 + 255) / 256, 256, 0, stream>>>(w2, W2s, 256, 128);
    prep_w<<<(512 * 256 * 9 + 255) / 256, 256, 0, stream>>>(w3, W3s, 512, 256);
    dct_mean<<<BATCH, 256, 0, stream>>>(x, ws + oDCT);
    resize_bilinear<<<12544, 256, 0, stream>>>(ws + oDCT, ws + oDIMG);
    hipMemsetAsync(ws + oFREQACC, 0, (size_t)BATCH * (512 + 1024 + 512) * sizeof(float), stream);

    // ---- per-image pipeline in batch chunks ----
    for (int b0 = 0; b0 < BATCH; b0 += CB) {
        const float* xc = x + (size_t)b0 * 3 * IMG2;
        // FFT branch
        dft_stage1<<<dim3(49, 1, 3 * CB), 256, 0, stream>>>(
            xc, ws + oWRE, ws + oWIM, ws + oT_re, ws + oT_im);
        dft_stage2<<<dim3(49, 1, 3 * CB), 256, 0, stream>>>(
            ws + oWRE, ws + oWIM, ws + oT_re, ws + oT_im, ws + oFFTIN);
        conv3x3_s2<32, 8, 14, 6><<<dim3(112, 1, CB), 256, 0, stream>>>(
            ws + oFFTIN, wf1, bf1, ws + oBIG1, 6, 32, 224, 224, 112, 112);
        conv3x3_s2<64, 4, 14, 8><<<dim3(56, 1, CB), 256, 0, stream>>>(
            ws + oBIG1, wf2, bf2, ws + oBIG2, 32, 64, 112, 112, 56, 56);
        pool7<<<(CB * 64 * 49 + 255) / 256, 256, 0, stream>>>(
            ws + oBIG2, ws + oFREQIN + (size_t)b0 * 6272, 3136, CB * 64 * 49);
        // DCT branch
        conv3x3_s2<32, 8, 14, 1><<<dim3(112, 1, CB), 256, 0, stream>>>(
            ws + oDIMG + (size_t)b0 * IMG2, ws + oWSUM, bd1, ws + oBIG1, 1, 32, 224, 224, 112, 112);
        conv3x3_s2<64, 4, 14, 8><<<dim3(56, 1, CB), 256, 0, stream>>>(
            ws + oBIG1, wd2, bd2, ws + oBIG2, 32, 64, 112, 112, 56, 56);
        pool7<<<(CB * 64 * 49 + 255) / 256, 256, 0, stream>>>(
            ws + oBIG2, ws + oFREQIN + (size_t)b0 * 6272, 0, CB * 64 * 49);
        // backbone: stem (fp32, packs) then 3 MFMA convs
        conv7x7_s2_pack<<<dim3(224, 1, CB), 256, 0, stream>>>(xc, w_stem, b_stem, STEMP);
        conv3x3s2_mfma<<<dim3((CB * 3136 + 63) / 64, 1, 1), 256, 0, stream>>>(
            STEMP, W1s, b1, C1P, nullptr, nullptr,
            64, 128, 112, 112, 56, 56, CB * 3136, 64, 0);
        conv3x3s2_mfma<<<dim3((CB * 784 + 63) / 64, 2, 1), 256, 0, stream>>>(
            C1P, W2s, b2, C2P, nullptr, nullptr,
            128, 256, 56, 56, 28, 28, CB * 784, 128, 0);
        conv3x3s2_mfma<<<dim3((CB * 196 + 63) / 64, 4, 2), 256, 0, stream>>>(
            C2P, W3s, b3, nullptr, ws + oC3a, ws + oC3b,
            256, 512, 28, 28, 14, 14, CB * 196, 128, 1);
        gap2_kernel<<<(CB * 512 * 64 + 255) / 256, 256, 0, stream>>>(
            ws + oC3a, ws + oC3b, b3, ws + oCOMB + (size_t)b0 * 1024, CB * 512);
    }

    // ---- fusion ----
    gemm64_atomic<<<dim3(8, 1, 8), 256, 0, stream>>>(ws + oFREQIN, W_freq, ws + oFREQACC,
                                                     512, 6272, 784);
    bias_relu_copy<<<128, 256, 0, stream>>>(ws + oFREQACC, b_freq, ws + oCOMB, 512, 1024, 512);
    gemm64_atomic<<<dim3(16, 1, 4), 256, 0, stream>>>(ws + oCOMB, W_fu1, ws + oFU1,
                                                      1024, 1024, 256);
    bias_relu_copy<<<256, 256, 0, stream>>>(ws + oFU1, b_fu1, ws + oFU1, 1024, 1024, 0);
    gemm64_atomic<<<dim3(8, 1, 4), 256, 0, stream>>>(ws + oFU1, W_fu2, ws + oFUSED,
                                                     512, 1024, 256);
    bias_relu_copy<<<128, 256, 0, stream>>>(ws + oFUSED, b_fu2, ws + oFUSED, 512, 512, 0);
    logits_kernel<<<1, 128, 0, stream>>>(ws + oFUSED, W_cls, b_cls, temp, out);
}

// Round 4
// 2669.182 us; speedup vs baseline: 2.2320x; 1.1902x over previous
//
#include <hip/hip_runtime.h>

#ifndef M_PI
#define M_PI 3.14159265358979323846
#endif

// ============================================================================
// EnhancedAIDetector — round 4:
//  - fusion GEMMs: split-K chunk 64 (8-12x more blocks; they were 2.7% occ)
//  - wf2/wd2 branch convs -> 64-co-tile MFMA implicit GEMM (bf16 hi/lo x3)
//  - wf1/wd1 fp32 convs now emit packed split-bf16 for the MFMA consumer
// ============================================================================

#define BATCH 64

typedef __bf16 bf16x8 __attribute__((ext_vector_type(8)));
typedef float f32x4 __attribute__((ext_vector_type(4)));

__device__ __forceinline__ unsigned short f2bf(float f) {
    unsigned u = __float_as_uint(f);
    u += 0x7FFF + ((u >> 16) & 1);      // RNE
    return (unsigned short)(u >> 16);
}
__device__ __forceinline__ unsigned packsplit(float v) {
    unsigned short h = f2bf(v);
    float hf = __uint_as_float(((unsigned)h) << 16);
    unsigned short l = f2bf(v - hf);
    return (((unsigned)h) << 16) | (unsigned)l;
}

union U8frag { bf16x8 v; unsigned d[4]; };

__device__ __forceinline__ void unpack8(const unsigned* p, bf16x8& hi, bf16x8& lo) {
    uint4 a = *(const uint4*)p;
    uint4 b = *(const uint4*)(p + 4);
    U8frag H, L;
    H.d[0] = __builtin_amdgcn_perm(a.y, a.x, 0x07060302u);
    L.d[0] = __builtin_amdgcn_perm(a.y, a.x, 0x05040100u);
    H.d[1] = __builtin_amdgcn_perm(a.w, a.z, 0x07060302u);
    L.d[1] = __builtin_amdgcn_perm(a.w, a.z, 0x05040100u);
    H.d[2] = __builtin_amdgcn_perm(b.y, b.x, 0x07060302u);
    L.d[2] = __builtin_amdgcn_perm(b.y, b.x, 0x05040100u);
    H.d[3] = __builtin_amdgcn_perm(b.w, b.z, 0x07060302u);
    L.d[3] = __builtin_amdgcn_perm(b.w, b.z, 0x05040100u);
    hi = H.v; lo = L.v;
}

// ============================================================================
// Weight prep: fp32 [Co][Ci][3][3] -> packed split [9][Co][Ci]
// ============================================================================
__global__ void prep_w(const float* __restrict__ w, unsigned* __restrict__ dst,
                       int Co, int Ci) {
    int idx = blockIdx.x * 256 + threadIdx.x;
    int tot = Co * Ci * 9;
    if (idx >= tot) return;
    int k9 = idx % 9;
    int rest = idx / 9;
    int ci = rest % Ci, co = rest / Ci;
    dst[((size_t)k9 * Co + co) * Ci + ci] = packsplit(w[idx]);
}

// ============================================================================
// MFMA implicit-GEMM 3x3 s2 conv, 128co x 64n tile (backbone conv1/2/3).
// ============================================================================
__global__ __launch_bounds__(256)
void conv3x3s2_mfma(const unsigned* __restrict__ inP, const unsigned* __restrict__ wP,
                    const float* __restrict__ bias,
                    unsigned* __restrict__ outPk, float* __restrict__ outF0,
                    float* __restrict__ outF1,
                    int Ci, int Co, int Hin, int Win, int Hout, int Wout,
                    int NTOT, int ciPer, int mode) {
    __shared__ unsigned sA[128 * 36];
    __shared__ unsigned sB[64 * 36];
    const int tid = threadIdx.x;
    const int wv = tid >> 6, lane = tid & 63;
    const int ciBeg = blockIdx.z * ciPer;
    const int coT0 = blockIdx.y * 128;
    const int HWin = Hin * Win, HWout = Hout * Wout;

    const int nG = blockIdx.x * 64 + (tid >> 2);
    const int kqB = tid & 3;
    int bb = 0, yy = 0, xx = 0;
    bool nval = nG < NTOT;
    if (nval) {
        bb = nG / HWout;
        int rem = nG - bb * HWout;
        yy = rem / Wout;
        xx = rem - yy * Wout;
    }
    const unsigned baseImg = (unsigned)bb * Ci * HWin;
    const int coA = tid >> 1, halfA = tid & 1;

    f32x4 acc[2][4];
#pragma unroll
    for (int s = 0; s < 2; s++)
#pragma unroll
        for (int t = 0; t < 4; t++) acc[s][t] = (f32x4){0.f, 0.f, 0.f, 0.f};

    for (int k9 = 0; k9 < 9; k9++) {
        int ky = k9 / 3, kx = k9 - ky * 3;
        int iy = 2 * yy + ky, ix = 2 * xx + kx;
        bool bval = nval && iy < Hin && ix < Win;
        unsigned off0 = baseImg + (unsigned)iy * Win + (unsigned)ix;
        const unsigned* wbase = wP + ((size_t)k9 * Co + coT0 + coA) * Ci + ciBeg + halfA * 16;

        for (int c0 = 0; c0 < ciPer; c0 += 32) {
            __syncthreads();
            {
                const uint4* g = (const uint4*)(wbase + c0);
                uint4 v0 = g[0], v1 = g[1], v2 = g[2], v3 = g[3];
                uint4* d = (uint4*)(sA + coA * 36 + halfA * 16);
                d[0] = v0; d[1] = v1; d[2] = v2; d[3] = v3;
            }
            {
                unsigned u[8];
                const unsigned cbase = off0 + (unsigned)(ciBeg + c0 + kqB * 8) * HWin;
#pragma unroll
                for (int j = 0; j < 8; j++)
                    u[j] = bval ? inP[cbase + (unsigned)j * HWin] : 0u;
                uint4* d = (uint4*)(sB + (tid >> 2) * 36 + kqB * 8);
                uint4 w0; w0.x = u[0]; w0.y = u[1]; w0.z = u[2]; w0.w = u[3];
                uint4 w1; w1.x = u[4]; w1.y = u[5]; w1.z = u[6]; w1.w = u[7];
                d[0] = w0; d[1] = w1;
            }
            __syncthreads();

            bf16x8 ah[2], al[2], bh[4], bl[4];
            const int m = lane & 15, q = lane >> 4;
#pragma unroll
            for (int s = 0; s < 2; s++)
                unpack8(sA + (wv * 32 + s * 16 + m) * 36 + q * 8, ah[s], al[s]);
#pragma unroll
            for (int t = 0; t < 4; t++)
                unpack8(sB + (t * 16 + m) * 36 + q * 8, bh[t], bl[t]);

#pragma unroll
            for (int s = 0; s < 2; s++)
#pragma unroll
                for (int t = 0; t < 4; t++)
                    acc[s][t] = __builtin_amdgcn_mfma_f32_16x16x32_bf16(ah[s], bh[t], acc[s][t], 0, 0, 0);
#pragma unroll
            for (int s = 0; s < 2; s++)
#pragma unroll
                for (int t = 0; t < 4; t++)
                    acc[s][t] = __builtin_amdgcn_mfma_f32_16x16x32_bf16(ah[s], bl[t], acc[s][t], 0, 0, 0);
#pragma unroll
            for (int s = 0; s < 2; s++)
#pragma unroll
                for (int t = 0; t < 4; t++)
                    acc[s][t] = __builtin_amdgcn_mfma_f32_16x16x32_bf16(al[s], bh[t], acc[s][t], 0, 0, 0);
        }
    }

    const int m = lane & 15, q = lane >> 4;
#pragma unroll
    for (int t = 0; t < 4; t++) {
        int n_g = blockIdx.x * 64 + t * 16 + m;
        if (n_g >= NTOT) continue;
        int b = n_g / HWout;
        int rem = n_g - b * HWout;
        size_t nb = (size_t)b * Co * HWout + rem;
#pragma unroll
        for (int s = 0; s < 2; s++) {
            int co_l = wv * 32 + s * 16 + q * 4;
#pragma unroll
            for (int r = 0; r < 4; r++) {
                int co_g = coT0 + co_l + r;
                float v = acc[s][t][r];
                size_t addr = nb + (size_t)co_g * HWout;
                if (mode == 0) {
                    v += bias[co_g];
                    v = v > 0.f ? v : 0.f;
                    outPk[addr] = packsplit(v);
                } else {
                    (blockIdx.z == 0 ? outF0 : outF1)[addr] = v;
                }
            }
        }
    }
}

// ============================================================================
// MFMA implicit-GEMM 3x3 s2 conv, 64co x 64n tile, Ci == 32 (wf2 / wd2).
// Output: fp32 with bias + ReLU, layout [b][64][Hout][Wout].
// ============================================================================
__global__ __launch_bounds__(256)
void conv3x3s2_mfma64(const unsigned* __restrict__ inP, const unsigned* __restrict__ wP,
                      const float* __restrict__ bias, float* __restrict__ outF,
                      int Hin, int Win, int Hout, int Wout, int NTOT) {
    const int Ci = 32;
    __shared__ unsigned sA[64 * 36];
    __shared__ unsigned sB[64 * 36];
    const int tid = threadIdx.x;
    const int wv = tid >> 6, lane = tid & 63;
    const int HWin = Hin * Win, HWout = Hout * Wout;

    const int nG = blockIdx.x * 64 + (tid >> 2);
    const int kq = tid & 3;
    int bb = 0, yy = 0, xx = 0;
    bool nval = nG < NTOT;
    if (nval) {
        bb = nG / HWout;
        int rem = nG - bb * HWout;
        yy = rem / Wout;
        xx = rem - yy * Wout;
    }
    const unsigned baseImg = (unsigned)bb * Ci * HWin;
    const int ch = wv & 1, nh = wv >> 1;

    f32x4 acc[2][2];
#pragma unroll
    for (int s = 0; s < 2; s++)
#pragma unroll
        for (int t = 0; t < 2; t++) acc[s][t] = (f32x4){0.f, 0.f, 0.f, 0.f};

    for (int k9 = 0; k9 < 9; k9++) {
        int ky = k9 / 3, kx = k9 - ky * 3;
        int iy = 2 * yy + ky, ix = 2 * xx + kx;
        bool bval = nval && iy < Hin && ix < Win;
        unsigned off0 = baseImg + (unsigned)iy * Win + (unsigned)ix;
        __syncthreads();
        {   // stage A: 64 co rows x 32 ci dwords
            const unsigned* g = wP + ((size_t)k9 * 64 + (tid >> 2)) * Ci + kq * 8;
            uint4 v0 = *(const uint4*)g;
            uint4 v1 = *(const uint4*)(g + 4);
            uint4* d = (uint4*)(sA + (tid >> 2) * 36 + kq * 8);
            d[0] = v0; d[1] = v1;
        }
        {   // stage B: 64 n rows x 32 ci dwords (gathered)
            unsigned u[8];
            const unsigned cbase = off0 + (unsigned)(kq * 8) * HWin;
#pragma unroll
            for (int j = 0; j < 8; j++)
                u[j] = bval ? inP[cbase + (unsigned)j * HWin] : 0u;
            uint4* d = (uint4*)(sB + (tid >> 2) * 36 + kq * 8);
            uint4 w0; w0.x = u[0]; w0.y = u[1]; w0.z = u[2]; w0.w = u[3];
            uint4 w1; w1.x = u[4]; w1.y = u[5]; w1.z = u[6]; w1.w = u[7];
            d[0] = w0; d[1] = w1;
        }
        __syncthreads();

        bf16x8 ah[2], al[2], bh[2], bl[2];
        const int m = lane & 15, q = lane >> 4;
#pragma unroll
        for (int s = 0; s < 2; s++)
            unpack8(sA + (ch * 32 + s * 16 + m) * 36 + q * 8, ah[s], al[s]);
#pragma unroll
        for (int t = 0; t < 2; t++)
            unpack8(sB + (nh * 32 + t * 16 + m) * 36 + q * 8, bh[t], bl[t]);

#pragma unroll
        for (int s = 0; s < 2; s++)
#pragma unroll
            for (int t = 0; t < 2; t++)
                acc[s][t] = __builtin_amdgcn_mfma_f32_16x16x32_bf16(ah[s], bh[t], acc[s][t], 0, 0, 0);
#pragma unroll
        for (int s = 0; s < 2; s++)
#pragma unroll
            for (int t = 0; t < 2; t++)
                acc[s][t] = __builtin_amdgcn_mfma_f32_16x16x32_bf16(ah[s], bl[t], acc[s][t], 0, 0, 0);
#pragma unroll
        for (int s = 0; s < 2; s++)
#pragma unroll
            for (int t = 0; t < 2; t++)
                acc[s][t] = __builtin_amdgcn_mfma_f32_16x16x32_bf16(al[s], bh[t], acc[s][t], 0, 0, 0);
    }

    const int m = lane & 15, q = lane >> 4;
#pragma unroll
    for (int t = 0; t < 2; t++) {
        int n_g = blockIdx.x * 64 + nh * 32 + t * 16 + m;
        if (n_g >= NTOT) continue;
        int b = n_g / HWout;
        int rem = n_g - b * HWout;
        size_t nb = (size_t)b * 64 * HWout + rem;
#pragma unroll
        for (int s = 0; s < 2; s++) {
            int co0 = ch * 32 + s * 16 + q * 4;
#pragma unroll
            for (int r = 0; r < 4; r++) {
                int co = co0 + r;
                float v = acc[s][t][r] + bias[co];
                outF[nb + (size_t)co * HWout] = v > 0.f ? v : 0.f;
            }
        }
    }
}

// ============================================================================
// DFT matrix:  W[j,k] = exp(-2*pi*i * j*k / 224)
// ============================================================================
__global__ void make_dft(float* __restrict__ wre, float* __restrict__ wim) {
    int idx = blockIdx.x * 256 + threadIdx.x;
    if (idx >= 224 * 224) return;
    int j = idx / 224, k = idx % 224;
    int m = (j * k) % 224;
    double a = -2.0 * M_PI * (double)m / 224.0;
    wre[idx] = (float)cos(a);
    wim[idx] = (float)sin(a);
}

__global__ void make_wsum(const float* __restrict__ wd1, float* __restrict__ wsum) {
    int idx = threadIdx.x;
    if (idx >= 288) return;
    int o = idx / 9, k = idx % 9;
    wsum[idx] = wd1[o * 27 + k] + wd1[o * 27 + 9 + k] + wd1[o * 27 + 18 + k];
}

// ============================================================================
// DFT stage 1: T = X @ W
// ============================================================================
__global__ __launch_bounds__(256)
void dft_stage1(const float* __restrict__ x, const float* __restrict__ wre,
                const float* __restrict__ wim, float* __restrict__ tre,
                float* __restrict__ tim) {
    const int N = 224;
    const int bc = blockIdx.z;
    const float* X = x + (size_t)bc * N * N;
    float* Tre = tre + (size_t)bc * N * N;
    float* Tim = tim + (size_t)bc * N * N;
    const int tile = blockIdx.x;
    const int tr0 = (tile / 7) * 32, tc0 = (tile % 7) * 32;
    const int tid = threadIdx.x;
    const int rl = tid >> 3;
    const int cl = (tid & 7) << 2;

    __shared__ __align__(16) float sA[32][17];
    __shared__ __align__(16) float sBre[16][32];
    __shared__ __align__(16) float sBim[16][32];

    float ar[4] = {0, 0, 0, 0}, ai[4] = {0, 0, 0, 0};
    for (int k0 = 0; k0 < N; k0 += 16) {
        for (int i = tid; i < 512; i += 256) {
            int r = i >> 4, k = i & 15;
            sA[r][k] = X[(size_t)(tr0 + r) * N + k0 + k];
        }
        for (int i = tid; i < 512; i += 256) {
            int k = i >> 5, c = i & 31;
            sBre[k][c] = wre[(size_t)(k0 + k) * N + tc0 + c];
            sBim[k][c] = wim[(size_t)(k0 + k) * N + tc0 + c];
        }
        __syncthreads();
#pragma unroll
        for (int k = 0; k < 16; k++) {
            float a = sA[rl][k];
            float4 br = *(const float4*)&sBre[k][cl];
            float4 bi = *(const float4*)&sBim[k][cl];
            ar[0] += a * br.x; ar[1] += a * br.y; ar[2] += a * br.z; ar[3] += a * br.w;
            ai[0] += a * bi.x; ai[1] += a * bi.y; ai[2] += a * bi.z; ai[3] += a * bi.w;
        }
        __syncthreads();
    }
    int r = tr0 + rl, c = tc0 + cl;
    float4 vr = {ar[0], ar[1], ar[2], ar[3]};
    float4 vi = {ai[0], ai[1], ai[2], ai[3]};
    *(float4*)&Tre[(size_t)r * N + c] = vr;
    *(float4*)&Tim[(size_t)r * N + c] = vi;
}

// ============================================================================
// DFT stage 2: Y = W @ T -> fft_in
// ============================================================================
__global__ __launch_bounds__(256)
void dft_stage2(const float* __restrict__ wre, const float* __restrict__ wim,
                const float* __restrict__ tre, const float* __restrict__ tim,
                float* __restrict__ fft_in) {
    const int N = 224;
    const int bc = blockIdx.z;
    const int b = bc / 3, c = bc % 3;
    const float* Tre = tre + (size_t)bc * N * N;
    const float* Tim = tim + (size_t)bc * N * N;
    const int tile = blockIdx.x;
    const int tm0 = (tile / 7) * 32, tn0 = (tile % 7) * 32;
    const int tid = threadIdx.x;
    const int rl = tid >> 3;
    const int cl = (tid & 7) << 2;

    __shared__ __align__(16) float sWre[32][17];
    __shared__ __align__(16) float sWim[32][17];
    __shared__ __align__(16) float sTre[16][32];
    __shared__ __align__(16) float sTim[16][32];

    float yr[4] = {0, 0, 0, 0}, yi[4] = {0, 0, 0, 0};
    for (int k0 = 0; k0 < N; k0 += 16) {
        for (int i = tid; i < 512; i += 256) {
            int r = i >> 4, k = i & 15;
            sWre[r][k] = wre[(size_t)(tm0 + r) * N + k0 + k];
            sWim[r][k] = wim[(size_t)(tm0 + r) * N + k0 + k];
        }
        for (int i = tid; i < 512; i += 256) {
            int k = i >> 5, cc = i & 31;
            sTre[k][cc] = Tre[(size_t)(k0 + k) * N + tn0 + cc];
            sTim[k][cc] = Tim[(size_t)(k0 + k) * N + tn0 + cc];
        }
        __syncthreads();
#pragma unroll
        for (int k = 0; k < 16; k++) {
            float wr_ = sWre[rl][k], wi_ = sWim[rl][k];
            float4 t4 = *(const float4*)&sTre[k][cl];
            float4 u4 = *(const float4*)&sTim[k][cl];
            yr[0] += wr_ * t4.x - wi_ * u4.x;  yi[0] += wr_ * u4.x + wi_ * t4.x;
            yr[1] += wr_ * t4.y - wi_ * u4.y;  yi[1] += wr_ * u4.y + wi_ * t4.y;
            yr[2] += wr_ * t4.z - wi_ * u4.z;  yi[2] += wr_ * u4.z + wi_ * t4.z;
            yr[3] += wr_ * t4.w - wi_ * u4.w;  yi[3] += wr_ * u4.w + wi_ * t4.w;
        }
        __syncthreads();
    }
    int m = tm0 + rl, n = tn0 + cl;
    float4 vr = {yr[0], yr[1], yr[2], yr[3]};
    float4 vi = {yi[0], yi[1], yi[2], yi[3]};
    *(float4*)&fft_in[((size_t)(b * 6 + 2 * c) * N + m) * N + n] = vr;
    *(float4*)&fft_in[((size_t)(b * 6 + 2 * c + 1) * N + m) * N + n] = vi;
}

// ============================================================================
// fp32 direct 3x3 s2 conv; PACK=true writes split-bf16 packed dwords.
// ============================================================================
template <int CO_BLK, int TH, int TW, int CI_CHUNK, bool PACK>
__global__ __launch_bounds__(CO_BLK * TH)
void conv3x3_s2(const float* __restrict__ in, const float* __restrict__ w,
                const float* __restrict__ bias, float* __restrict__ out,
                int Ci, int Co, int Hin, int Win, int Hout, int Wout) {
    constexpr int IN_H = 2 * TH + 1;
    constexpr int IN_W = 2 * TW + 1;
    constexpr int IN_WP = 32;
    constexpr int WSTR = (CI_CHUNK * 9) | 1;
    __shared__ __align__(16) float s_in[CI_CHUNK][IN_H][IN_WP];
    __shared__ float s_w[CO_BLK * WSTR];

    const int tid = threadIdx.x;
    const int tiles_x = Wout / TW;
    const int tile = blockIdx.x;
    const int ty0 = (tile / tiles_x) * TH;
    const int tx0 = (tile % tiles_x) * TW;
    const int cog = blockIdx.y;
    const int b = blockIdx.z;
    const int co = tid % CO_BLK;
    const int ty = tid / CO_BLK;
    const int co_g = cog * CO_BLK + co;

    float acc[TW];
#pragma unroll
    for (int i = 0; i < TW; i++) acc[i] = 0.f;

    const float* in_b = in + (size_t)b * Ci * Hin * Win;
    const int iy0 = 2 * ty0, ix0 = 2 * tx0;

    for (int ci0 = 0; ci0 < Ci; ci0 += CI_CHUNK) {
        for (int idx = tid; idx < CI_CHUNK * IN_H * IN_W; idx += CO_BLK * TH) {
            int ci = idx / (IN_H * IN_W);
            int rem = idx % (IN_H * IN_W);
            int r = rem / IN_W, cc = rem % IN_W;
            int gy = iy0 + r, gx = ix0 + cc;
            float v = 0.f;
            if (gy < Hin && gx < Win)
                v = in_b[(size_t)(ci0 + ci) * Hin * Win + (size_t)gy * Win + gx];
            s_in[ci][r][cc] = v;
        }
        for (int idx = tid; idx < CO_BLK * CI_CHUNK * 9; idx += CO_BLK * TH) {
            int c = idx / (CI_CHUNK * 9);
            int k = idx % (CI_CHUNK * 9);
            s_w[c * WSTR + k] = w[((size_t)(cog * CO_BLK + c) * Ci + ci0) * 9 + k];
        }
        __syncthreads();

#pragma unroll
        for (int ci = 0; ci < CI_CHUNK; ci++) {
            float wr[9];
#pragma unroll
            for (int k = 0; k < 9; k++) wr[k] = s_w[co * WSTR + ci * 9 + k];
#pragma unroll
            for (int ky = 0; ky < 3; ky++) {
                float r[IN_WP];
                const float4* rowp = (const float4*)&s_in[ci][2 * ty + ky][0];
#pragma unroll
                for (int qq = 0; qq < IN_WP / 4; qq++) {
                    float4 v = rowp[qq];
                    r[4 * qq] = v.x; r[4 * qq + 1] = v.y; r[4 * qq + 2] = v.z; r[4 * qq + 3] = v.w;
                }
#pragma unroll
                for (int kx = 0; kx < 3; kx++) {
                    float wv = wr[ky * 3 + kx];
#pragma unroll
                    for (int xq = 0; xq < TW; xq++) acc[xq] += r[2 * xq + kx] * wv;
                }
            }
        }
        __syncthreads();
    }
    float bb = bias[co_g];
    size_t obase = ((size_t)b * Co + co_g) * Hout * Wout + (size_t)(ty0 + ty) * Wout + tx0;
#pragma unroll
    for (int xq = 0; xq < TW; xq++) {
        float v = acc[xq] + bb;
        v = v > 0.f ? v : 0.f;
        if (PACK)
            ((unsigned*)out)[obase + xq] = packsplit(v);
        else
            out[obase + xq] = v;
    }
}

// ============================================================================
// Stem: 7x7 s2, Cin=3, Cout=64, 224->112; writes PACKED split bf16.
// ============================================================================
__global__ __launch_bounds__(256)
void conv7x7_s2_pack(const float* __restrict__ in, const float* __restrict__ w,
                     const float* __restrict__ bias, unsigned* __restrict__ out) {
    constexpr int TH = 4, TW = 14;
    constexpr int IN_H = 13, IN_W = 33, IN_WP = 36, WSTR = 149;
    __shared__ __align__(16) float s_in[3][IN_H][IN_WP];
    __shared__ float s_w[64 * WSTR];
    const int tid = threadIdx.x;
    const int tile = blockIdx.x;
    const int tiles_x = 112 / TW;
    const int ty0 = (tile / tiles_x) * TH;
    const int tx0 = (tile % tiles_x) * TW;
    const int b = blockIdx.z;
    const int co = tid & 63;
    const int ty = tid >> 6;

    const float* in_b = in + (size_t)b * 3 * 224 * 224;
    const int iy0 = 2 * ty0 - 2, ix0 = 2 * tx0 - 2;

    for (int idx = tid; idx < 3 * IN_H * IN_W; idx += 256) {
        int ci = idx / (IN_H * IN_W);
        int rem = idx % (IN_H * IN_W);
        int r = rem / IN_W, cc = rem % IN_W;
        int gy = iy0 + r, gx = ix0 + cc;
        float v = 0.f;
        if (gy >= 0 && gy < 224 && gx >= 0 && gx < 224)
            v = in_b[(size_t)ci * 224 * 224 + (size_t)gy * 224 + gx];
        s_in[ci][r][cc] = v;
    }
    for (int idx = tid; idx < 64 * 147; idx += 256) {
        int c = idx / 147, k = idx % 147;
        s_w[c * WSTR + k] = w[c * 147 + k];
    }
    __syncthreads();

    float acc[TW];
#pragma unroll
    for (int i = 0; i < TW; i++) acc[i] = 0.f;

#pragma unroll
    for (int ci = 0; ci < 3; ci++) {
#pragma unroll
        for (int ky = 0; ky < 7; ky++) {
            float wr[7];
#pragma unroll
            for (int k = 0; k < 7; k++) wr[k] = s_w[co * WSTR + ci * 49 + ky * 7 + k];
            float r[IN_WP];
            const float4* rowp = (const float4*)&s_in[ci][2 * ty + ky][0];
#pragma unroll
            for (int qq = 0; qq < IN_WP / 4; qq++) {
                float4 v = rowp[qq];
                r[4 * qq] = v.x; r[4 * qq + 1] = v.y; r[4 * qq + 2] = v.z; r[4 * qq + 3] = v.w;
            }
#pragma unroll
            for (int kx = 0; kx < 7; kx++) {
                float wv = wr[kx];
#pragma unroll
                for (int xq = 0; xq < TW; xq++) acc[xq] += r[2 * xq + kx] * wv;
            }
        }
    }
    float bb = bias[co];
    unsigned* outp = out + ((size_t)b * 64 + co) * 112 * 112 + (size_t)(ty0 + ty) * 112 + tx0;
#pragma unroll
    for (int xq = 0; xq < TW; xq++) {
        float v = acc[xq] + bb;
        v = v > 0.f ? v : 0.f;
        outp[xq] = packsplit(v);
    }
}

// ============================================================================
// DCT branch: linearity collapse + resize
// ============================================================================
__device__ __forceinline__ float dct_coef(int u, int i) {
    if (u == 0) return 0.35355339059327373f;
    return 0.5f * cosf((float)M_PI * (float)((2 * i + 1) * u) / 16.0f);
}

__global__ __launch_bounds__(256)
void dct_mean(const float* __restrict__ x, float* __restrict__ dct_out) {
    __shared__ float red[256];
    __shared__ float Mb[64];
    const int b = blockIdx.x;
    const int tid = threadIdx.x;
    const int ij = tid & 63;
    const int grp = tid >> 6;
    const int i = ij >> 3, j = ij & 7;
    const float* xb = x + (size_t)b * 3 * 224 * 224;
    float s = 0.f;
    for (int blk = grp; blk < 784; blk += 4) {
        int m = blk / 28, n = blk % 28;
        int p = m * 8 + i, q = n * 8 + j;
        size_t o = (size_t)p * 224 + q;
        s += (0.299f * xb[o] + 0.587f * xb[224 * 224 + o] + 0.114f * xb[2 * 224 * 224 + o]) * 255.f;
    }
    red[tid] = s;
    __syncthreads();
    if (tid < 64)
        Mb[tid] = (red[tid] + red[tid + 64] + red[tid + 128] + red[tid + 192]) * (1.f / 784.f);
    __syncthreads();
    if (tid < 64) {
        int u = tid >> 3, v = tid & 7;
        float acc = 0.f;
#pragma unroll
        for (int i2 = 0; i2 < 8; i2++) {
            float du = dct_coef(u, i2);
#pragma unroll
            for (int j2 = 0; j2 < 8; j2++) acc += du * Mb[i2 * 8 + j2] * dct_coef(v, j2);
        }
        dct_out[b * 64 + tid] = acc;
    }
}

__global__ void resize_bilinear(const float* __restrict__ dct, float* __restrict__ out) {
    int idx = blockIdx.x * 256 + threadIdx.x;
    if (idx >= BATCH * 224 * 224) return;
    int b = idx / (224 * 224);
    int rem = idx % (224 * 224);
    int y = rem / 224, xx = rem % 224;
    float sy = fminf(fmaxf((y + 0.5f) * (1.f / 28.f) - 0.5f, 0.f), 7.f);
    float sx = fminf(fmaxf((xx + 0.5f) * (1.f / 28.f) - 0.5f, 0.f), 7.f);
    int y0 = (int)floorf(sy); if (y0 > 6) y0 = 6;
    int x0 = (int)floorf(sx); if (x0 > 6) x0 = 6;
    float ty = sy - y0, tx = sx - x0;
    const float* M = dct + b * 64;
    float v00 = M[y0 * 8 + x0], v01 = M[y0 * 8 + x0 + 1];
    float v10 = M[(y0 + 1) * 8 + x0], v11 = M[(y0 + 1) * 8 + x0 + 1];
    out[idx] = (1.f - ty) * ((1.f - tx) * v00 + tx * v01) + ty * ((1.f - tx) * v10 + tx * v11);
}

// ============================================================================
// Pooling
// ============================================================================
__global__ void pool7(const float* __restrict__ h, float* __restrict__ out,
                      int col_base, int n) {
    int idx = blockIdx.x * 256 + threadIdx.x;
    if (idx >= n) return;
    int b = idx / (64 * 49);
    int rem = idx % (64 * 49);
    int c = rem / 49;
    int ij = rem % 49;
    int i = ij / 7, j = ij % 7;
    const float* hp = h + ((size_t)(b * 64 + c)) * 56 * 56 + (size_t)i * 8 * 56 + j * 8;
    float s = 0.f;
#pragma unroll
    for (int r = 0; r < 8; r++)
#pragma unroll
        for (int q = 0; q < 8; q++) s += hp[r * 56 + q];
    out[(size_t)b * 6272 + col_base + c * 49 + ij] = s * (1.f / 64.f);
}

__global__ void gap2_kernel(const float* __restrict__ ha, const float* __restrict__ hb,
                            const float* __restrict__ bias, float* __restrict__ comb,
                            int nwaves) {
    int gt = blockIdx.x * blockDim.x + threadIdx.x;
    int wid = gt >> 6;
    int lane = gt & 63;
    if (wid >= nwaves) return;
    int b = wid / 512, c = wid % 512;
    const float* pa = ha + (size_t)wid * 196;
    const float* pb = hb + (size_t)wid * 196;
    float bbv = bias[c];
    float s = 0.f;
    for (int i = lane; i < 196; i += 64) {
        float v = pa[i] + pb[i] + bbv;
        s += v > 0.f ? v : 0.f;
    }
#pragma unroll
    for (int off = 32; off > 0; off >>= 1) s += __shfl_down(s, off);
    if (lane == 0) comb[(size_t)b * 1024 + c] = s * (1.f / 196.f);
}

// ============================================================================
// Fusion GEMMs (fp32, M=64, split-K atomic)
// ============================================================================
__global__ __launch_bounds__(256)
void gemm64_atomic(const float* __restrict__ A, const float* __restrict__ Bm,
                   float* __restrict__ C, int N, int K, int KC) {
    __shared__ __align__(16) float sA[16][68];
    __shared__ __align__(16) float sB[16][68];
    const int tid = threadIdx.x;
    const int n0 = blockIdx.x * 64;
    const int kbase = blockIdx.z * KC;
    const int tr = (tid >> 4) << 2;
    const int tc = (tid & 15) << 2;
    float acc[4][4];
#pragma unroll
    for (int r = 0; r < 4; r++)
#pragma unroll
        for (int c = 0; c < 4; c++) acc[r][c] = 0.f;

    for (int k0 = 0; k0 < KC; k0 += 16) {
        for (int i = tid; i < 1024; i += 256) {
            int m = i >> 4, k = i & 15;
            sA[k][m] = A[(size_t)m * K + kbase + k0 + k];
        }
        for (int i = tid; i < 1024; i += 256) {
            int k = i >> 6, n = i & 63;
            sB[k][n] = Bm[(size_t)(kbase + k0 + k) * N + n0 + n];
        }
        __syncthreads();
#pragma unroll
        for (int k = 0; k < 16; k++) {
            float4 a = *(const float4*)&sA[k][tr];
            float4 bv = *(const float4*)&sB[k][tc];
            float av[4] = {a.x, a.y, a.z, a.w};
            float bb[4] = {bv.x, bv.y, bv.z, bv.w};
#pragma unroll
            for (int r = 0; r < 4; r++)
#pragma unroll
                for (int c = 0; c < 4; c++) acc[r][c] += av[r] * bb[c];
        }
        __syncthreads();
    }
#pragma unroll
    for (int r = 0; r < 4; r++)
#pragma unroll
        for (int c = 0; c < 4; c++)
            atomicAdd(&C[(size_t)(tr + r) * N + n0 + tc + c], acc[r][c]);
}

__global__ void bias_relu_copy(const float* __restrict__ src, const float* __restrict__ bias,
                               float* __restrict__ dst, int N, int dstStride, int dstOff) {
    int idx = blockIdx.x * 256 + threadIdx.x;
    if (idx >= BATCH * N) return;
    int b = idx / N, n = idx % N;
    float v = src[idx] + bias[n];
    dst[(size_t)b * dstStride + dstOff + n] = v > 0.f ? v : 0.f;
}

__global__ void logits_kernel(const float* __restrict__ fused, const float* __restrict__ Wc,
                              const float* __restrict__ bcls, const float* __restrict__ temp,
                              float* __restrict__ out) {
    int idx = threadIdx.x;
    if (idx >= 128) return;
    int b = idx >> 1, n = idx & 1;
    float s = bcls[n];
    const float* f = fused + (size_t)b * 512;
    for (int k = 0; k < 512; k++) s += f[k] * Wc[k * 2 + n];
    out[idx] = s;
    out[128 + idx] = s / temp[0];
}

// ============================================================================
extern "C" void kernel_launch(void* const* d_in, const int* in_sizes, int n_in,
                              void* d_out, int out_size, void* d_ws, size_t ws_size,
                              hipStream_t stream) {
    const float* x      = (const float*)d_in[0];
    const float* w_stem = (const float*)d_in[1];
    const float* b_stem = (const float*)d_in[2];
    const float* w1 = (const float*)d_in[3];   const float* b1 = (const float*)d_in[4];
    const float* w2 = (const float*)d_in[5];   const float* b2 = (const float*)d_in[6];
    const float* w3 = (const float*)d_in[7];   const float* b3 = (const float*)d_in[8];
    const float* wd1 = (const float*)d_in[9];  const float* bd1 = (const float*)d_in[10];
    const float* wd2 = (const float*)d_in[11]; const float* bd2 = (const float*)d_in[12];
    const float* wf1 = (const float*)d_in[13]; const float* bf1 = (const float*)d_in[14];
    const float* wf2 = (const float*)d_in[15]; const float* bf2 = (const float*)d_in[16];
    const float* W_freq = (const float*)d_in[17]; const float* b_freq = (const float*)d_in[18];
    const float* W_fu1  = (const float*)d_in[19]; const float* b_fu1  = (const float*)d_in[20];
    const float* W_fu2  = (const float*)d_in[21]; const float* b_fu2  = (const float*)d_in[22];
    const float* W_cls  = (const float*)d_in[23]; const float* b_cls  = (const float*)d_in[24];
    const float* temp   = (const float*)d_in[25];
    float* ws = (float*)d_ws;
    float* out = (float*)d_out;

    const size_t IMG2 = 224 * 224;

    // ---- persistent region (dword offsets) ----
    size_t oWRE  = 0;
    size_t oWIM  = oWRE + IMG2;
    size_t oWSUM = oWIM + IMG2;
    size_t oDCT  = oWSUM + 288;
    size_t oDIMG = oDCT + (size_t)BATCH * 64;
    size_t oFREQIN  = oDIMG + (size_t)BATCH * IMG2;
    size_t oCOMB    = oFREQIN + (size_t)BATCH * 6272;
    size_t oFREQACC = oCOMB + (size_t)BATCH * 1024;
    size_t oFU1     = oFREQACC + (size_t)BATCH * 512;
    size_t oFUSED   = oFU1 + (size_t)BATCH * 1024;
    size_t oW1s     = oFUSED + (size_t)BATCH * 512;      // 9*128*64
    size_t oW2s     = oW1s + 73728;                      // 9*256*128
    size_t oW3s     = oW2s + 294912;                     // 9*512*256
    size_t oWF2s    = oW3s + 1179648;                    // 9*64*32
    size_t oWD2s    = oWF2s + 18432;                     // 9*64*32
    size_t P        = oWD2s + 18432;

    // ---- chunk region: CB*1,605,632 dwords ----
    int CB = 16;
    while (CB > 1 && (P + (size_t)CB * 1605632) * 4 > ws_size) CB >>= 1;
    size_t base   = P;
    size_t oSTEMP = base;                                // CB*802816 (packed)
    size_t oC1P   = oSTEMP + (size_t)CB * 802816;        // CB*401408 (packed)
    size_t oC2P   = oC1P + (size_t)CB * 401408;          // CB*200704 (packed)
    size_t oC3a   = oC2P + (size_t)CB * 200704;          // CB*100352 fp32
    size_t oC3b   = oC3a + (size_t)CB * 100352;          // CB*100352 fp32
    // FFT-phase aliases (dead before backbone writes):
    size_t oT_re  = base;
    size_t oT_im  = oT_re + (size_t)CB * 150528;
    size_t oFFTIN = oT_im + (size_t)CB * 150528;         // CB*301056
    size_t oBIG1  = base + (size_t)CB * 602112;          // CB*401408 (packed now)
    size_t oBIG2  = base + (size_t)CB * 1003520;         // CB*200704 fp32

    unsigned* W1s = (unsigned*)(ws + oW1s);
    unsigned* W2s = (unsigned*)(ws + oW2s);
    unsigned* W3s = (unsigned*)(ws + oW3s);
    unsigned* WF2s = (unsigned*)(ws + oWF2s);
    unsigned* WD2s = (unsigned*)(ws + oWD2s);
    unsigned* STEMP = (unsigned*)(ws + oSTEMP);
    unsigned* C1P   = (unsigned*)(ws + oC1P);
    unsigned* C2P   = (unsigned*)(ws + oC2P);
    unsigned* BIG1P = (unsigned*)(ws + oBIG1);

    // ---- batch-independent prep ----
    make_dft<<<196, 256, 0, stream>>>(ws + oWRE, ws + oWIM);
    make_wsum<<<1, 288, 0, stream>>>(wd1, ws + oWSUM);
    prep_w<<<(128 * 64 * 9 + 255) / 256, 256, 0, stream>>>(w1, W1s, 128, 64);
    prep_w<<<(256 * 128 * 9 + 255) / 256, 256, 0, stream>>>(w2, W2s, 256, 128);
    prep_w<<<(512 * 256 * 9 + 255) / 256, 256, 0, stream>>>(w3, W3s, 512, 256);
    prep_w<<<(64 * 32 * 9 + 255) / 256, 256, 0, stream>>>(wf2, WF2s, 64, 32);
    prep_w<<<(64 * 32 * 9 + 255) / 256, 256, 0, stream>>>(wd2, WD2s, 64, 32);
    dct_mean<<<BATCH, 256, 0, stream>>>(x, ws + oDCT);
    resize_bilinear<<<12544, 256, 0, stream>>>(ws + oDCT, ws + oDIMG);
    hipMemsetAsync(ws + oFREQACC, 0, (size_t)BATCH * (512 + 1024 + 512) * sizeof(float), stream);

    // ---- per-image pipeline in batch chunks ----
    for (int b0 = 0; b0 < BATCH; b0 += CB) {
        const float* xc = x + (size_t)b0 * 3 * IMG2;
        // FFT branch
        dft_stage1<<<dim3(49, 1, 3 * CB), 256, 0, stream>>>(
            xc, ws + oWRE, ws + oWIM, ws + oT_re, ws + oT_im);
        dft_stage2<<<dim3(49, 1, 3 * CB), 256, 0, stream>>>(
            ws + oWRE, ws + oWIM, ws + oT_re, ws + oT_im, ws + oFFTIN);
        conv3x3_s2<32, 8, 14, 6, true><<<dim3(112, 1, CB), 256, 0, stream>>>(
            ws + oFFTIN, wf1, bf1, ws + oBIG1, 6, 32, 224, 224, 112, 112);
        conv3x3s2_mfma64<<<dim3(CB * 3136 / 64, 1, 1), 256, 0, stream>>>(
            BIG1P, WF2s, bf2, ws + oBIG2, 112, 112, 56, 56, CB * 3136);
        pool7<<<(CB * 64 * 49 + 255) / 256, 256, 0, stream>>>(
            ws + oBIG2, ws + oFREQIN + (size_t)b0 * 6272, 3136, CB * 64 * 49);
        // DCT branch
        conv3x3_s2<32, 8, 14, 1, true><<<dim3(112, 1, CB), 256, 0, stream>>>(
            ws + oDIMG + (size_t)b0 * IMG2, ws + oWSUM, bd1, ws + oBIG1, 1, 32, 224, 224, 112, 112);
        conv3x3s2_mfma64<<<dim3(CB * 3136 / 64, 1, 1), 256, 0, stream>>>(
            BIG1P, WD2s, bd2, ws + oBIG2, 112, 112, 56, 56, CB * 3136);
        pool7<<<(CB * 64 * 49 + 255) / 256, 256, 0, stream>>>(
            ws + oBIG2, ws + oFREQIN + (size_t)b0 * 6272, 0, CB * 64 * 49);
        // backbone
        conv7x7_s2_pack<<<dim3(224, 1, CB), 256, 0, stream>>>(xc, w_stem, b_stem, STEMP);
        conv3x3s2_mfma<<<dim3((CB * 3136 + 63) / 64, 1, 1), 256, 0, stream>>>(
            STEMP, W1s, b1, C1P, nullptr, nullptr,
            64, 128, 112, 112, 56, 56, CB * 3136, 64, 0);
        conv3x3s2_mfma<<<dim3((CB * 784 + 63) / 64, 2, 1), 256, 0, stream>>>(
            C1P, W2s, b2, C2P, nullptr, nullptr,
            128, 256, 56, 56, 28, 28, CB * 784, 128, 0);
        conv3x3s2_mfma<<<dim3((CB * 196 + 63) / 64, 4, 2), 256, 0, stream>>>(
            C2P, W3s, b3, nullptr, ws + oC3a, ws + oC3b,
            256, 512, 28, 28, 14, 14, CB * 196, 128, 1);
        gap2_kernel<<<(CB * 512 * 64 + 255) / 256, 256, 0, stream>>>(
            ws + oC3a, ws + oC3b, b3, ws + oCOMB + (size_t)b0 * 1024, CB * 512);
    }

    // ---- fusion (KC=64: 8-12x more split-K blocks than round 3) ----
    gemm64_atomic<<<dim3(8, 1, 98), 256, 0, stream>>>(ws + oFREQIN, W_freq, ws + oFREQACC,
                                                      512, 6272, 64);
    bias_relu_copy<<<128, 256, 0, stream>>>(ws + oFREQACC, b_freq, ws + oCOMB, 512, 1024, 512);
    gemm64_atomic<<<dim3(16, 1, 16), 256, 0, stream>>>(ws + oCOMB, W_fu1, ws + oFU1,
                                                       1024, 1024, 64);
    bias_relu_copy<<<256, 256, 0, stream>>>(ws + oFU1, b_fu1, ws + oFU1, 1024, 1024, 0);
    gemm64_atomic<<<dim3(8, 1, 16), 256, 0, stream>>>(ws + oFU1, W_fu2, ws + oFUSED,
                                                      512, 1024, 64);
    bias_relu_copy<<<128, 256, 0, stream>>>(ws + oFUSED, b_fu2, ws + oFUSED, 512, 512, 0);
    logits_kernel<<<1, 128, 0, stream>>>(ws + oFUSED, W_cls, b_cls, temp, out);
}

// Round 5
// 2192.067 us; speedup vs baseline: 2.7178x; 1.2177x over previous
//
#include <hip/hip_runtime.h>

#ifndef M_PI
#define M_PI 3.14159265358979323846
#endif

// ============================================================================
// EnhancedAIDetector — round 5:
//  - dct_mean (was 127us @ 2.3% occ, 64 blocks) -> 2-stage parallel reduction
//  - DFT stages -> MFMA bf16 hi/lo split x3 GEMMs (both stages framed as
//    A=W(symmetric) row-major, B=source rows, k contiguous; exact 224 tiling)
// ============================================================================

#define BATCH 64

typedef __bf16 bf16x8 __attribute__((ext_vector_type(8)));
typedef float f32x4 __attribute__((ext_vector_type(4)));

__device__ __forceinline__ unsigned short f2bf(float f) {
    unsigned u = __float_as_uint(f);
    u += 0x7FFF + ((u >> 16) & 1);      // RNE
    return (unsigned short)(u >> 16);
}
__device__ __forceinline__ unsigned packsplit(float v) {
    unsigned short h = f2bf(v);
    float hf = __uint_as_float(((unsigned)h) << 16);
    unsigned short l = f2bf(v - hf);
    return (((unsigned)h) << 16) | (unsigned)l;
}

union U8frag { bf16x8 v; unsigned d[4]; };

// unpack 8 packed dwords at p (LDS or global) -> hi fragment + lo fragment
__device__ __forceinline__ void unpack8(const unsigned* p, bf16x8& hi, bf16x8& lo) {
    uint4 a = *(const uint4*)p;
    uint4 b = *(const uint4*)(p + 4);
    U8frag H, L;
    H.d[0] = __builtin_amdgcn_perm(a.y, a.x, 0x07060302u);
    L.d[0] = __builtin_amdgcn_perm(a.y, a.x, 0x05040100u);
    H.d[1] = __builtin_amdgcn_perm(a.w, a.z, 0x07060302u);
    L.d[1] = __builtin_amdgcn_perm(a.w, a.z, 0x05040100u);
    H.d[2] = __builtin_amdgcn_perm(b.y, b.x, 0x07060302u);
    L.d[2] = __builtin_amdgcn_perm(b.y, b.x, 0x05040100u);
    H.d[3] = __builtin_amdgcn_perm(b.w, b.z, 0x07060302u);
    L.d[3] = __builtin_amdgcn_perm(b.w, b.z, 0x05040100u);
    hi = H.v; lo = L.v;
}

__device__ __forceinline__ bf16x8 bfneg(bf16x8 v) {
    U8frag a; a.v = v;
    a.d[0] ^= 0x80008000u; a.d[1] ^= 0x80008000u;
    a.d[2] ^= 0x80008000u; a.d[3] ^= 0x80008000u;
    return a.v;
}

// ============================================================================
// Weight prep: fp32 [Co][Ci][3][3] -> packed split [9][Co][Ci]
// ============================================================================
__global__ void prep_w(const float* __restrict__ w, unsigned* __restrict__ dst,
                       int Co, int Ci) {
    int idx = blockIdx.x * 256 + threadIdx.x;
    int tot = Co * Ci * 9;
    if (idx >= tot) return;
    int k9 = idx % 9;
    int rest = idx / 9;
    int ci = rest % Ci, co = rest / Ci;
    dst[((size_t)k9 * Co + co) * Ci + ci] = packsplit(w[idx]);
}

// generic fp32 -> packed split copy
__global__ void pack_f32(const float* __restrict__ src, unsigned* __restrict__ dst, int n) {
    int i = blockIdx.x * 256 + threadIdx.x;
    if (i < n) dst[i] = packsplit(src[i]);
}

// ============================================================================
// MFMA implicit-GEMM 3x3 s2 conv, 128co x 64n tile (backbone conv1/2/3).
// ============================================================================
__global__ __launch_bounds__(256)
void conv3x3s2_mfma(const unsigned* __restrict__ inP, const unsigned* __restrict__ wP,
                    const float* __restrict__ bias,
                    unsigned* __restrict__ outPk, float* __restrict__ outF0,
                    float* __restrict__ outF1,
                    int Ci, int Co, int Hin, int Win, int Hout, int Wout,
                    int NTOT, int ciPer, int mode) {
    __shared__ unsigned sA[128 * 36];
    __shared__ unsigned sB[64 * 36];
    const int tid = threadIdx.x;
    const int wv = tid >> 6, lane = tid & 63;
    const int ciBeg = blockIdx.z * ciPer;
    const int coT0 = blockIdx.y * 128;
    const int HWin = Hin * Win, HWout = Hout * Wout;

    const int nG = blockIdx.x * 64 + (tid >> 2);
    const int kqB = tid & 3;
    int bb = 0, yy = 0, xx = 0;
    bool nval = nG < NTOT;
    if (nval) {
        bb = nG / HWout;
        int rem = nG - bb * HWout;
        yy = rem / Wout;
        xx = rem - yy * Wout;
    }
    const unsigned baseImg = (unsigned)bb * Ci * HWin;
    const int coA = tid >> 1, halfA = tid & 1;

    f32x4 acc[2][4];
#pragma unroll
    for (int s = 0; s < 2; s++)
#pragma unroll
        for (int t = 0; t < 4; t++) acc[s][t] = (f32x4){0.f, 0.f, 0.f, 0.f};

    for (int k9 = 0; k9 < 9; k9++) {
        int ky = k9 / 3, kx = k9 - ky * 3;
        int iy = 2 * yy + ky, ix = 2 * xx + kx;
        bool bval = nval && iy < Hin && ix < Win;
        unsigned off0 = baseImg + (unsigned)iy * Win + (unsigned)ix;
        const unsigned* wbase = wP + ((size_t)k9 * Co + coT0 + coA) * Ci + ciBeg + halfA * 16;

        for (int c0 = 0; c0 < ciPer; c0 += 32) {
            __syncthreads();
            {
                const uint4* g = (const uint4*)(wbase + c0);
                uint4 v0 = g[0], v1 = g[1], v2 = g[2], v3 = g[3];
                uint4* d = (uint4*)(sA + coA * 36 + halfA * 16);
                d[0] = v0; d[1] = v1; d[2] = v2; d[3] = v3;
            }
            {
                unsigned u[8];
                const unsigned cbase = off0 + (unsigned)(ciBeg + c0 + kqB * 8) * HWin;
#pragma unroll
                for (int j = 0; j < 8; j++)
                    u[j] = bval ? inP[cbase + (unsigned)j * HWin] : 0u;
                uint4* d = (uint4*)(sB + (tid >> 2) * 36 + kqB * 8);
                uint4 w0; w0.x = u[0]; w0.y = u[1]; w0.z = u[2]; w0.w = u[3];
                uint4 w1; w1.x = u[4]; w1.y = u[5]; w1.z = u[6]; w1.w = u[7];
                d[0] = w0; d[1] = w1;
            }
            __syncthreads();

            bf16x8 ah[2], al[2], bh[4], bl[4];
            const int m = lane & 15, q = lane >> 4;
#pragma unroll
            for (int s = 0; s < 2; s++)
                unpack8(sA + (wv * 32 + s * 16 + m) * 36 + q * 8, ah[s], al[s]);
#pragma unroll
            for (int t = 0; t < 4; t++)
                unpack8(sB + (t * 16 + m) * 36 + q * 8, bh[t], bl[t]);

#pragma unroll
            for (int s = 0; s < 2; s++)
#pragma unroll
                for (int t = 0; t < 4; t++)
                    acc[s][t] = __builtin_amdgcn_mfma_f32_16x16x32_bf16(ah[s], bh[t], acc[s][t], 0, 0, 0);
#pragma unroll
            for (int s = 0; s < 2; s++)
#pragma unroll
                for (int t = 0; t < 4; t++)
                    acc[s][t] = __builtin_amdgcn_mfma_f32_16x16x32_bf16(ah[s], bl[t], acc[s][t], 0, 0, 0);
#pragma unroll
            for (int s = 0; s < 2; s++)
#pragma unroll
                for (int t = 0; t < 4; t++)
                    acc[s][t] = __builtin_amdgcn_mfma_f32_16x16x32_bf16(al[s], bh[t], acc[s][t], 0, 0, 0);
        }
    }

    const int m = lane & 15, q = lane >> 4;
#pragma unroll
    for (int t = 0; t < 4; t++) {
        int n_g = blockIdx.x * 64 + t * 16 + m;
        if (n_g >= NTOT) continue;
        int b = n_g / HWout;
        int rem = n_g - b * HWout;
        size_t nb = (size_t)b * Co * HWout + rem;
#pragma unroll
        for (int s = 0; s < 2; s++) {
            int co_l = wv * 32 + s * 16 + q * 4;
#pragma unroll
            for (int r = 0; r < 4; r++) {
                int co_g = coT0 + co_l + r;
                float v = acc[s][t][r];
                size_t addr = nb + (size_t)co_g * HWout;
                if (mode == 0) {
                    v += bias[co_g];
                    v = v > 0.f ? v : 0.f;
                    outPk[addr] = packsplit(v);
                } else {
                    (blockIdx.z == 0 ? outF0 : outF1)[addr] = v;
                }
            }
        }
    }
}

// ============================================================================
// MFMA implicit-GEMM 3x3 s2 conv, 64co x 64n tile, Ci == 32 (wf2 / wd2).
// ============================================================================
__global__ __launch_bounds__(256)
void conv3x3s2_mfma64(const unsigned* __restrict__ inP, const unsigned* __restrict__ wP,
                      const float* __restrict__ bias, float* __restrict__ outF,
                      int Hin, int Win, int Hout, int Wout, int NTOT) {
    const int Ci = 32;
    __shared__ unsigned sA[64 * 36];
    __shared__ unsigned sB[64 * 36];
    const int tid = threadIdx.x;
    const int wv = tid >> 6, lane = tid & 63;
    const int HWin = Hin * Win, HWout = Hout * Wout;

    const int nG = blockIdx.x * 64 + (tid >> 2);
    const int kq = tid & 3;
    int bb = 0, yy = 0, xx = 0;
    bool nval = nG < NTOT;
    if (nval) {
        bb = nG / HWout;
        int rem = nG - bb * HWout;
        yy = rem / Wout;
        xx = rem - yy * Wout;
    }
    const unsigned baseImg = (unsigned)bb * Ci * HWin;
    const int ch = wv & 1, nh = wv >> 1;

    f32x4 acc[2][2];
#pragma unroll
    for (int s = 0; s < 2; s++)
#pragma unroll
        for (int t = 0; t < 2; t++) acc[s][t] = (f32x4){0.f, 0.f, 0.f, 0.f};

    for (int k9 = 0; k9 < 9; k9++) {
        int ky = k9 / 3, kx = k9 - ky * 3;
        int iy = 2 * yy + ky, ix = 2 * xx + kx;
        bool bval = nval && iy < Hin && ix < Win;
        unsigned off0 = baseImg + (unsigned)iy * Win + (unsigned)ix;
        __syncthreads();
        {
            const unsigned* g = wP + ((size_t)k9 * 64 + (tid >> 2)) * Ci + kq * 8;
            uint4 v0 = *(const uint4*)g;
            uint4 v1 = *(const uint4*)(g + 4);
            uint4* d = (uint4*)(sA + (tid >> 2) * 36 + kq * 8);
            d[0] = v0; d[1] = v1;
        }
        {
            unsigned u[8];
            const unsigned cbase = off0 + (unsigned)(kq * 8) * HWin;
#pragma unroll
            for (int j = 0; j < 8; j++)
                u[j] = bval ? inP[cbase + (unsigned)j * HWin] : 0u;
            uint4* d = (uint4*)(sB + (tid >> 2) * 36 + kq * 8);
            uint4 w0; w0.x = u[0]; w0.y = u[1]; w0.z = u[2]; w0.w = u[3];
            uint4 w1; w1.x = u[4]; w1.y = u[5]; w1.z = u[6]; w1.w = u[7];
            d[0] = w0; d[1] = w1;
        }
        __syncthreads();

        bf16x8 ah[2], al[2], bh[2], bl[2];
        const int m = lane & 15, q = lane >> 4;
#pragma unroll
        for (int s = 0; s < 2; s++)
            unpack8(sA + (ch * 32 + s * 16 + m) * 36 + q * 8, ah[s], al[s]);
#pragma unroll
        for (int t = 0; t < 2; t++)
            unpack8(sB + (nh * 32 + t * 16 + m) * 36 + q * 8, bh[t], bl[t]);

#pragma unroll
        for (int s = 0; s < 2; s++)
#pragma unroll
            for (int t = 0; t < 2; t++)
                acc[s][t] = __builtin_amdgcn_mfma_f32_16x16x32_bf16(ah[s], bh[t], acc[s][t], 0, 0, 0);
#pragma unroll
        for (int s = 0; s < 2; s++)
#pragma unroll
            for (int t = 0; t < 2; t++)
                acc[s][t] = __builtin_amdgcn_mfma_f32_16x16x32_bf16(ah[s], bl[t], acc[s][t], 0, 0, 0);
#pragma unroll
        for (int s = 0; s < 2; s++)
#pragma unroll
            for (int t = 0; t < 2; t++)
                acc[s][t] = __builtin_amdgcn_mfma_f32_16x16x32_bf16(al[s], bh[t], acc[s][t], 0, 0, 0);
    }

    const int m = lane & 15, q = lane >> 4;
#pragma unroll
    for (int t = 0; t < 2; t++) {
        int n_g = blockIdx.x * 64 + nh * 32 + t * 16 + m;
        if (n_g >= NTOT) continue;
        int b = n_g / HWout;
        int rem = n_g - b * HWout;
        size_t nb = (size_t)b * 64 * HWout + rem;
#pragma unroll
        for (int s = 0; s < 2; s++) {
            int co0 = ch * 32 + s * 16 + q * 4;
#pragma unroll
            for (int r = 0; r < 4; r++) {
                int co = co0 + r;
                float v = acc[s][t][r] + bias[co];
                outF[nb + (size_t)co * HWout] = v > 0.f ? v : 0.f;
            }
        }
    }
}

// ============================================================================
// DFT matrix (packed split bf16):  W[j,k] = exp(-2*pi*i * j*k / 224)
// ============================================================================
__global__ void make_dft(unsigned* __restrict__ wre, unsigned* __restrict__ wim) {
    int idx = blockIdx.x * 256 + threadIdx.x;
    if (idx >= 224 * 224) return;
    int j = idx / 224, k = idx % 224;
    int m = (j * k) % 224;
    double a = -2.0 * M_PI * (double)m / 224.0;
    wre[idx] = packsplit((float)cos(a));
    wim[idx] = packsplit((float)sin(a));
}

__global__ void make_wsum(const float* __restrict__ wd1, float* __restrict__ wsum) {
    int idx = threadIdx.x;
    if (idx >= 288) return;
    int o = idx / 9, k = idx % 9;
    wsum[idx] = wd1[o * 27 + k] + wd1[o * 27 + 9 + k] + wd1[o * 27 + 18 + k];
}

// ============================================================================
// DFT stage 1 (MFMA): Tt = W @ X^T.  Tt[m][n] = sum_k W[m,k] X[n,k].
// A = W rows (complex packed), B = X rows (real packed).  Exact 32x32 tiles.
// grid (7, 7, 3*CB), block 64 (one wave).
// ============================================================================
__global__ __launch_bounds__(64)
void dft_mfma_s1(const unsigned* __restrict__ wre, const unsigned* __restrict__ wim,
                 const unsigned* __restrict__ xpk,
                 unsigned* __restrict__ ttre, unsigned* __restrict__ ttim) {
    const int z = blockIdx.z;
    const int m0 = blockIdx.x * 32, n0 = blockIdx.y * 32;
    const int lane = threadIdx.x;
    const int ml = lane & 15, q = lane >> 4;
    const unsigned* xb = xpk + (size_t)z * 50176;

    f32x4 cre[2][2], cim[2][2];
#pragma unroll
    for (int s = 0; s < 2; s++)
#pragma unroll
        for (int t = 0; t < 2; t++) { cre[s][t] = (f32x4){0,0,0,0}; cim[s][t] = (f32x4){0,0,0,0}; }

    for (int k0 = 0; k0 < 224; k0 += 32) {
        bf16x8 arh[2], arl[2], aih[2], ail[2], bh[2], bl[2];
#pragma unroll
        for (int s = 0; s < 2; s++) {
            int row = m0 + s * 16 + ml;
            unpack8(wre + row * 224 + k0 + q * 8, arh[s], arl[s]);
            unpack8(wim + row * 224 + k0 + q * 8, aih[s], ail[s]);
        }
#pragma unroll
        for (int t = 0; t < 2; t++)
            unpack8(xb + (n0 + t * 16 + ml) * 224 + k0 + q * 8, bh[t], bl[t]);

#pragma unroll
        for (int s = 0; s < 2; s++)
#pragma unroll
            for (int t = 0; t < 2; t++) {
                cre[s][t] = __builtin_amdgcn_mfma_f32_16x16x32_bf16(arh[s], bh[t], cre[s][t], 0, 0, 0);
                cre[s][t] = __builtin_amdgcn_mfma_f32_16x16x32_bf16(arh[s], bl[t], cre[s][t], 0, 0, 0);
                cre[s][t] = __builtin_amdgcn_mfma_f32_16x16x32_bf16(arl[s], bh[t], cre[s][t], 0, 0, 0);
                cim[s][t] = __builtin_amdgcn_mfma_f32_16x16x32_bf16(aih[s], bh[t], cim[s][t], 0, 0, 0);
                cim[s][t] = __builtin_amdgcn_mfma_f32_16x16x32_bf16(aih[s], bl[t], cim[s][t], 0, 0, 0);
                cim[s][t] = __builtin_amdgcn_mfma_f32_16x16x32_bf16(ail[s], bh[t], cim[s][t], 0, 0, 0);
            }
    }

    unsigned* tre = ttre + (size_t)z * 50176;
    unsigned* tim = ttim + (size_t)z * 50176;
#pragma unroll
    for (int s = 0; s < 2; s++)
#pragma unroll
        for (int t = 0; t < 2; t++)
#pragma unroll
            for (int r = 0; r < 4; r++) {
                int m = m0 + s * 16 + q * 4 + r;
                int n = n0 + t * 16 + ml;
                tre[m * 224 + n] = packsplit(cre[s][t][r]);
                tim[m * 224 + n] = packsplit(cim[s][t][r]);
            }
}

// ============================================================================
// DFT stage 2 (MFMA): Y[m][n] = sum_k W[m,k] T[k,n], T[k,n] = Tt[n][k].
// Yre = Wre*Tre - Wim*Tim ; Yim = Wre*Tim + Wim*Tre.  Output fp32 fft_in.
// grid (7, 7, 3*CB), block 64.
// ============================================================================
__global__ __launch_bounds__(64)
void dft_mfma_s2(const unsigned* __restrict__ wre, const unsigned* __restrict__ wim,
                 const unsigned* __restrict__ ttre, const unsigned* __restrict__ ttim,
                 float* __restrict__ fft_in) {
    const int z = blockIdx.z;
    const int m0 = blockIdx.x * 32, n0 = blockIdx.y * 32;
    const int lane = threadIdx.x;
    const int ml = lane & 15, q = lane >> 4;
    const unsigned* tre = ttre + (size_t)z * 50176;
    const unsigned* tim = ttim + (size_t)z * 50176;

    f32x4 cre[2][2], cim[2][2];
#pragma unroll
    for (int s = 0; s < 2; s++)
#pragma unroll
        for (int t = 0; t < 2; t++) { cre[s][t] = (f32x4){0,0,0,0}; cim[s][t] = (f32x4){0,0,0,0}; }

    for (int k0 = 0; k0 < 224; k0 += 32) {
        bf16x8 arh[2], arl[2], aih[2], ail[2];
        bf16x8 brh[2], brl[2], bih[2], bil[2];
#pragma unroll
        for (int s = 0; s < 2; s++) {
            int row = m0 + s * 16 + ml;
            unpack8(wre + row * 224 + k0 + q * 8, arh[s], arl[s]);
            unpack8(wim + row * 224 + k0 + q * 8, aih[s], ail[s]);
        }
#pragma unroll
        for (int t = 0; t < 2; t++) {
            int row = n0 + t * 16 + ml;
            unpack8(tre + row * 224 + k0 + q * 8, brh[t], brl[t]);
            unpack8(tim + row * 224 + k0 + q * 8, bih[t], bil[t]);
        }

#pragma unroll
        for (int t = 0; t < 2; t++) {
            bf16x8 nih = bfneg(bih[t]);
            bf16x8 nil = bfneg(bil[t]);
#pragma unroll
            for (int s = 0; s < 2; s++) {
                cre[s][t] = __builtin_amdgcn_mfma_f32_16x16x32_bf16(arh[s], brh[t], cre[s][t], 0, 0, 0);
                cre[s][t] = __builtin_amdgcn_mfma_f32_16x16x32_bf16(arh[s], brl[t], cre[s][t], 0, 0, 0);
                cre[s][t] = __builtin_amdgcn_mfma_f32_16x16x32_bf16(arl[s], brh[t], cre[s][t], 0, 0, 0);
                cre[s][t] = __builtin_amdgcn_mfma_f32_16x16x32_bf16(aih[s], nih, cre[s][t], 0, 0, 0);
                cre[s][t] = __builtin_amdgcn_mfma_f32_16x16x32_bf16(aih[s], nil, cre[s][t], 0, 0, 0);
                cre[s][t] = __builtin_amdgcn_mfma_f32_16x16x32_bf16(ail[s], nih, cre[s][t], 0, 0, 0);
                cim[s][t] = __builtin_amdgcn_mfma_f32_16x16x32_bf16(arh[s], bih[t], cim[s][t], 0, 0, 0);
                cim[s][t] = __builtin_amdgcn_mfma_f32_16x16x32_bf16(arh[s], bil[t], cim[s][t], 0, 0, 0);
                cim[s][t] = __builtin_amdgcn_mfma_f32_16x16x32_bf16(arl[s], bih[t], cim[s][t], 0, 0, 0);
                cim[s][t] = __builtin_amdgcn_mfma_f32_16x16x32_bf16(aih[s], brh[t], cim[s][t], 0, 0, 0);
                cim[s][t] = __builtin_amdgcn_mfma_f32_16x16x32_bf16(aih[s], brl[t], cim[s][t], 0, 0, 0);
                cim[s][t] = __builtin_amdgcn_mfma_f32_16x16x32_bf16(ail[s], brh[t], cim[s][t], 0, 0, 0);
            }
        }
    }

    const int b_loc = z / 3, c = z % 3;
    float* yre = fft_in + (size_t)(b_loc * 6 + 2 * c) * 50176;
    float* yim = yre + 50176;
#pragma unroll
    for (int s = 0; s < 2; s++)
#pragma unroll
        for (int t = 0; t < 2; t++)
#pragma unroll
            for (int r = 0; r < 4; r++) {
                int m = m0 + s * 16 + q * 4 + r;
                int n = n0 + t * 16 + ml;
                yre[m * 224 + n] = cre[s][t][r];
                yim[m * 224 + n] = cim[s][t][r];
            }
}

// ============================================================================
// fp32 direct 3x3 s2 conv; PACK=true writes split-bf16 packed dwords.
// ============================================================================
template <int CO_BLK, int TH, int TW, int CI_CHUNK, bool PACK>
__global__ __launch_bounds__(CO_BLK * TH)
void conv3x3_s2(const float* __restrict__ in, const float* __restrict__ w,
                const float* __restrict__ bias, float* __restrict__ out,
                int Ci, int Co, int Hin, int Win, int Hout, int Wout) {
    constexpr int IN_H = 2 * TH + 1;
    constexpr int IN_W = 2 * TW + 1;
    constexpr int IN_WP = 32;
    constexpr int WSTR = (CI_CHUNK * 9) | 1;
    __shared__ __align__(16) float s_in[CI_CHUNK][IN_H][IN_WP];
    __shared__ float s_w[CO_BLK * WSTR];

    const int tid = threadIdx.x;
    const int tiles_x = Wout / TW;
    const int tile = blockIdx.x;
    const int ty0 = (tile / tiles_x) * TH;
    const int tx0 = (tile % tiles_x) * TW;
    const int cog = blockIdx.y;
    const int b = blockIdx.z;
    const int co = tid % CO_BLK;
    const int ty = tid / CO_BLK;
    const int co_g = cog * CO_BLK + co;

    float acc[TW];
#pragma unroll
    for (int i = 0; i < TW; i++) acc[i] = 0.f;

    const float* in_b = in + (size_t)b * Ci * Hin * Win;
    const int iy0 = 2 * ty0, ix0 = 2 * tx0;

    for (int ci0 = 0; ci0 < Ci; ci0 += CI_CHUNK) {
        for (int idx = tid; idx < CI_CHUNK * IN_H * IN_W; idx += CO_BLK * TH) {
            int ci = idx / (IN_H * IN_W);
            int rem = idx % (IN_H * IN_W);
            int r = rem / IN_W, cc = rem % IN_W;
            int gy = iy0 + r, gx = ix0 + cc;
            float v = 0.f;
            if (gy < Hin && gx < Win)
                v = in_b[(size_t)(ci0 + ci) * Hin * Win + (size_t)gy * Win + gx];
            s_in[ci][r][cc] = v;
        }
        for (int idx = tid; idx < CO_BLK * CI_CHUNK * 9; idx += CO_BLK * TH) {
            int c = idx / (CI_CHUNK * 9);
            int k = idx % (CI_CHUNK * 9);
            s_w[c * WSTR + k] = w[((size_t)(cog * CO_BLK + c) * Ci + ci0) * 9 + k];
        }
        __syncthreads();

#pragma unroll
        for (int ci = 0; ci < CI_CHUNK; ci++) {
            float wr[9];
#pragma unroll
            for (int k = 0; k < 9; k++) wr[k] = s_w[co * WSTR + ci * 9 + k];
#pragma unroll
            for (int ky = 0; ky < 3; ky++) {
                float r[IN_WP];
                const float4* rowp = (const float4*)&s_in[ci][2 * ty + ky][0];
#pragma unroll
                for (int qq = 0; qq < IN_WP / 4; qq++) {
                    float4 v = rowp[qq];
                    r[4 * qq] = v.x; r[4 * qq + 1] = v.y; r[4 * qq + 2] = v.z; r[4 * qq + 3] = v.w;
                }
#pragma unroll
                for (int kx = 0; kx < 3; kx++) {
                    float wv = wr[ky * 3 + kx];
#pragma unroll
                    for (int xq = 0; xq < TW; xq++) acc[xq] += r[2 * xq + kx] * wv;
                }
            }
        }
        __syncthreads();
    }
    float bb = bias[co_g];
    size_t obase = ((size_t)b * Co + co_g) * Hout * Wout + (size_t)(ty0 + ty) * Wout + tx0;
#pragma unroll
    for (int xq = 0; xq < TW; xq++) {
        float v = acc[xq] + bb;
        v = v > 0.f ? v : 0.f;
        if (PACK)
            ((unsigned*)out)[obase + xq] = packsplit(v);
        else
            out[obase + xq] = v;
    }
}

// ============================================================================
// Stem: 7x7 s2, Cin=3, Cout=64, 224->112; writes PACKED split bf16.
// ============================================================================
__global__ __launch_bounds__(256)
void conv7x7_s2_pack(const float* __restrict__ in, const float* __restrict__ w,
                     const float* __restrict__ bias, unsigned* __restrict__ out) {
    constexpr int TH = 4, TW = 14;
    constexpr int IN_H = 13, IN_W = 33, IN_WP = 36, WSTR = 149;
    __shared__ __align__(16) float s_in[3][IN_H][IN_WP];
    __shared__ float s_w[64 * WSTR];
    const int tid = threadIdx.x;
    const int tile = blockIdx.x;
    const int tiles_x = 112 / TW;
    const int ty0 = (tile / tiles_x) * TH;
    const int tx0 = (tile % tiles_x) * TW;
    const int b = blockIdx.z;
    const int co = tid & 63;
    const int ty = tid >> 6;

    const float* in_b = in + (size_t)b * 3 * 224 * 224;
    const int iy0 = 2 * ty0 - 2, ix0 = 2 * tx0 - 2;

    for (int idx = tid; idx < 3 * IN_H * IN_W; idx += 256) {
        int ci = idx / (IN_H * IN_W);
        int rem = idx % (IN_H * IN_W);
        int r = rem / IN_W, cc = rem % IN_W;
        int gy = iy0 + r, gx = ix0 + cc;
        float v = 0.f;
        if (gy >= 0 && gy < 224 && gx >= 0 && gx < 224)
            v = in_b[(size_t)ci * 224 * 224 + (size_t)gy * 224 + gx];
        s_in[ci][r][cc] = v;
    }
    for (int idx = tid; idx < 64 * 147; idx += 256) {
        int c = idx / 147, k = idx % 147;
        s_w[c * WSTR + k] = w[c * 147 + k];
    }
    __syncthreads();

    float acc[TW];
#pragma unroll
    for (int i = 0; i < TW; i++) acc[i] = 0.f;

#pragma unroll
    for (int ci = 0; ci < 3; ci++) {
#pragma unroll
        for (int ky = 0; ky < 7; ky++) {
            float wr[7];
#pragma unroll
            for (int k = 0; k < 7; k++) wr[k] = s_w[co * WSTR + ci * 49 + ky * 7 + k];
            float r[IN_WP];
            const float4* rowp = (const float4*)&s_in[ci][2 * ty + ky][0];
#pragma unroll
            for (int qq = 0; qq < IN_WP / 4; qq++) {
                float4 v = rowp[qq];
                r[4 * qq] = v.x; r[4 * qq + 1] = v.y; r[4 * qq + 2] = v.z; r[4 * qq + 3] = v.w;
            }
#pragma unroll
            for (int kx = 0; kx < 7; kx++) {
                float wv = wr[kx];
#pragma unroll
                for (int xq = 0; xq < TW; xq++) acc[xq] += r[2 * xq + kx] * wv;
            }
        }
    }
    float bb = bias[co];
    unsigned* outp = out + ((size_t)b * 64 + co) * 112 * 112 + (size_t)(ty0 + ty) * 112 + tx0;
#pragma unroll
    for (int xq = 0; xq < TW; xq++) {
        float v = acc[xq] + bb;
        v = v > 0.f ? v : 0.f;
        outp[xq] = packsplit(v);
    }
}

// ============================================================================
// DCT branch: parallel block-mean (2-stage) then 8x8 DCT; bilinear resize.
// ============================================================================
__device__ __forceinline__ float dct_coef(int u, int i) {
    if (u == 0) return 0.35355339059327373f;
    return 0.5f * cosf((float)M_PI * (float)((2 * i + 1) * u) / 16.0f);
}

// stage 1: grid (64, 12): partial sums of gray over 8x8 block positions
__global__ __launch_bounds__(256)
void dct_partial(const float* __restrict__ x, float* __restrict__ accum) {
    __shared__ float red[256];
    const int b = blockIdx.x, g = blockIdx.y;
    const int tid = threadIdx.x;
    const int ij = tid & 63;
    const int grp = tid >> 6;
    const int i = ij >> 3, j = ij & 7;
    const float* xb = x + (size_t)b * 3 * 50176;
    float s = 0.f;
    for (int blk = g * 4 + grp; blk < 784; blk += 48) {
        int m = blk / 28, n = blk % 28;
        size_t o = (size_t)(m * 8 + i) * 224 + n * 8 + j;
        s += 0.299f * xb[o] + 0.587f * xb[50176 + o] + 0.114f * xb[2 * 50176 + o];
    }
    red[tid] = s;
    __syncthreads();
    if (tid < 64)
        atomicAdd(&accum[b * 64 + tid],
                  red[tid] + red[tid + 64] + red[tid + 128] + red[tid + 192]);
}

// stage 2: grid 64, block 64: mean + 8x8 DCT
__global__ __launch_bounds__(64)
void dct_final(const float* __restrict__ accum, float* __restrict__ dct_out) {
    __shared__ float Mb[64];
    const int b = blockIdx.x, tid = threadIdx.x;
    Mb[tid] = accum[b * 64 + tid] * (255.f / 784.f);
    __syncthreads();
    int u = tid >> 3, v = tid & 7;
    float acc = 0.f;
#pragma unroll
    for (int i2 = 0; i2 < 8; i2++) {
        float du = dct_coef(u, i2);
#pragma unroll
        for (int j2 = 0; j2 < 8; j2++) acc += du * Mb[i2 * 8 + j2] * dct_coef(v, j2);
    }
    dct_out[b * 64 + tid] = acc;
}

__global__ void resize_bilinear(const float* __restrict__ dct, float* __restrict__ out) {
    int idx = blockIdx.x * 256 + threadIdx.x;
    if (idx >= BATCH * 224 * 224) return;
    int b = idx / (224 * 224);
    int rem = idx % (224 * 224);
    int y = rem / 224, xx = rem % 224;
    float sy = fminf(fmaxf((y + 0.5f) * (1.f / 28.f) - 0.5f, 0.f), 7.f);
    float sx = fminf(fmaxf((xx + 0.5f) * (1.f / 28.f) - 0.5f, 0.f), 7.f);
    int y0 = (int)floorf(sy); if (y0 > 6) y0 = 6;
    int x0 = (int)floorf(sx); if (x0 > 6) x0 = 6;
    float ty = sy - y0, tx = sx - x0;
    const float* M = dct + b * 64;
    float v00 = M[y0 * 8 + x0], v01 = M[y0 * 8 + x0 + 1];
    float v10 = M[(y0 + 1) * 8 + x0], v11 = M[(y0 + 1) * 8 + x0 + 1];
    out[idx] = (1.f - ty) * ((1.f - tx) * v00 + tx * v01) + ty * ((1.f - tx) * v10 + tx * v11);
}

// ============================================================================
// Pooling
// ============================================================================
__global__ void pool7(const float* __restrict__ h, float* __restrict__ out,
                      int col_base, int n) {
    int idx = blockIdx.x * 256 + threadIdx.x;
    if (idx >= n) return;
    int b = idx / (64 * 49);
    int rem = idx % (64 * 49);
    int c = rem / 49;
    int ij = rem % 49;
    int i = ij / 7, j = ij % 7;
    const float* hp = h + ((size_t)(b * 64 + c)) * 56 * 56 + (size_t)i * 8 * 56 + j * 8;
    float s = 0.f;
#pragma unroll
    for (int r = 0; r < 8; r++)
#pragma unroll
        for (int q = 0; q < 8; q++) s += hp[r * 56 + q];
    out[(size_t)b * 6272 + col_base + c * 49 + ij] = s * (1.f / 64.f);
}

__global__ void gap2_kernel(const float* __restrict__ ha, const float* __restrict__ hb,
                            const float* __restrict__ bias, float* __restrict__ comb,
                            int nwaves) {
    int gt = blockIdx.x * blockDim.x + threadIdx.x;
    int wid = gt >> 6;
    int lane = gt & 63;
    if (wid >= nwaves) return;
    int b = wid / 512, c = wid % 512;
    const float* pa = ha + (size_t)wid * 196;
    const float* pb = hb + (size_t)wid * 196;
    float bbv = bias[c];
    float s = 0.f;
    for (int i = lane; i < 196; i += 64) {
        float v = pa[i] + pb[i] + bbv;
        s += v > 0.f ? v : 0.f;
    }
#pragma unroll
    for (int off = 32; off > 0; off >>= 1) s += __shfl_down(s, off);
    if (lane == 0) comb[(size_t)b * 1024 + c] = s * (1.f / 196.f);
}

// ============================================================================
// Fusion GEMMs (fp32, M=64, split-K atomic)
// ============================================================================
__global__ __launch_bounds__(256)
void gemm64_atomic(const float* __restrict__ A, const float* __restrict__ Bm,
                   float* __restrict__ C, int N, int K, int KC) {
    __shared__ __align__(16) float sA[16][68];
    __shared__ __align__(16) float sB[16][68];
    const int tid = threadIdx.x;
    const int n0 = blockIdx.x * 64;
    const int kbase = blockIdx.z * KC;
    const int tr = (tid >> 4) << 2;
    const int tc = (tid & 15) << 2;
    float acc[4][4];
#pragma unroll
    for (int r = 0; r < 4; r++)
#pragma unroll
        for (int c = 0; c < 4; c++) acc[r][c] = 0.f;

    for (int k0 = 0; k0 < KC; k0 += 16) {
        for (int i = tid; i < 1024; i += 256) {
            int m = i >> 4, k = i & 15;
            sA[k][m] = A[(size_t)m * K + kbase + k0 + k];
        }
        for (int i = tid; i < 1024; i += 256) {
            int k = i >> 6, n = i & 63;
            sB[k][n] = Bm[(size_t)(kbase + k0 + k) * N + n0 + n];
        }
        __syncthreads();
#pragma unroll
        for (int k = 0; k < 16; k++) {
            float4 a = *(const float4*)&sA[k][tr];
            float4 bv = *(const float4*)&sB[k][tc];
            float av[4] = {a.x, a.y, a.z, a.w};
            float bb[4] = {bv.x, bv.y, bv.z, bv.w};
#pragma unroll
            for (int r = 0; r < 4; r++)
#pragma unroll
                for (int c = 0; c < 4; c++) acc[r][c] += av[r] * bb[c];
        }
        __syncthreads();
    }
#pragma unroll
    for (int r = 0; r < 4; r++)
#pragma unroll
        for (int c = 0; c < 4; c++)
            atomicAdd(&C[(size_t)(tr + r) * N + n0 + tc + c], acc[r][c]);
}

__global__ void bias_relu_copy(const float* __restrict__ src, const float* __restrict__ bias,
                               float* __restrict__ dst, int N, int dstStride, int dstOff) {
    int idx = blockIdx.x * 256 + threadIdx.x;
    if (idx >= BATCH * N) return;
    int b = idx / N, n = idx % N;
    float v = src[idx] + bias[n];
    dst[(size_t)b * dstStride + dstOff + n] = v > 0.f ? v : 0.f;
}

__global__ void logits_kernel(const float* __restrict__ fused, const float* __restrict__ Wc,
                              const float* __restrict__ bcls, const float* __restrict__ temp,
                              float* __restrict__ out) {
    int idx = threadIdx.x;
    if (idx >= 128) return;
    int b = idx >> 1, n = idx & 1;
    float s = bcls[n];
    const float* f = fused + (size_t)b * 512;
    for (int k = 0; k < 512; k++) s += f[k] * Wc[k * 2 + n];
    out[idx] = s;
    out[128 + idx] = s / temp[0];
}

// ============================================================================
extern "C" void kernel_launch(void* const* d_in, const int* in_sizes, int n_in,
                              void* d_out, int out_size, void* d_ws, size_t ws_size,
                              hipStream_t stream) {
    const float* x      = (const float*)d_in[0];
    const float* w_stem = (const float*)d_in[1];
    const float* b_stem = (const float*)d_in[2];
    const float* w1 = (const float*)d_in[3];   const float* b1 = (const float*)d_in[4];
    const float* w2 = (const float*)d_in[5];   const float* b2 = (const float*)d_in[6];
    const float* w3 = (const float*)d_in[7];   const float* b3 = (const float*)d_in[8];
    const float* wd1 = (const float*)d_in[9];  const float* bd1 = (const float*)d_in[10];
    const float* wd2 = (const float*)d_in[11]; const float* bd2 = (const float*)d_in[12];
    const float* wf1 = (const float*)d_in[13]; const float* bf1 = (const float*)d_in[14];
    const float* wf2 = (const float*)d_in[15]; const float* bf2 = (const float*)d_in[16];
    const float* W_freq = (const float*)d_in[17]; const float* b_freq = (const float*)d_in[18];
    const float* W_fu1  = (const float*)d_in[19]; const float* b_fu1  = (const float*)d_in[20];
    const float* W_fu2  = (const float*)d_in[21]; const float* b_fu2  = (const float*)d_in[22];
    const float* W_cls  = (const float*)d_in[23]; const float* b_cls  = (const float*)d_in[24];
    const float* temp   = (const float*)d_in[25];
    float* ws = (float*)d_ws;
    float* out = (float*)d_out;

    const size_t IMG2 = 224 * 224;

    // ---- persistent region (dword offsets) ----
    size_t oWRE  = 0;                                    // packed W re (224*224)
    size_t oWIM  = oWRE + IMG2;                          // packed W im
    size_t oWSUM = oWIM + IMG2;
    size_t oDCT  = oWSUM + 288;
    size_t oDIMG = oDCT + (size_t)BATCH * 64;
    size_t oFREQIN  = oDIMG + (size_t)BATCH * IMG2;
    size_t oCOMB    = oFREQIN + (size_t)BATCH * 6272;
    size_t oFREQACC = oCOMB + (size_t)BATCH * 1024;      // zeroed region start
    size_t oFU1     = oFREQACC + (size_t)BATCH * 512;
    size_t oFUSED   = oFU1 + (size_t)BATCH * 1024;
    size_t oDCTACC  = oFUSED + (size_t)BATCH * 512;      // B*64, zeroed
    size_t oW1s     = oDCTACC + (size_t)BATCH * 64;
    size_t oW2s     = oW1s + 73728;
    size_t oW3s     = oW2s + 294912;
    size_t oWF2s    = oW3s + 1179648;
    size_t oWD2s    = oWF2s + 18432;
    size_t P        = oWD2s + 18432;

    // ---- chunk region: CB*1,605,632 dwords ----
    int CB = 16;
    while (CB > 1 && (P + (size_t)CB * 1605632) * 4 > ws_size) CB >>= 1;
    size_t base   = P;
    size_t oSTEMP = base;                                // CB*802816 (packed)
    size_t oC1P   = oSTEMP + (size_t)CB * 802816;        // CB*401408 (packed)
    size_t oC2P   = oC1P + (size_t)CB * 401408;          // CB*200704 (packed)
    size_t oC3a   = oC2P + (size_t)CB * 200704;          // CB*100352 fp32
    size_t oC3b   = oC3a + (size_t)CB * 100352;          // CB*100352 fp32
    // FFT-phase aliases (within stem region; dead before backbone writes):
    size_t oXPK   = base;                                // CB*150528 packed X
    size_t oTTRE  = oXPK + (size_t)CB * 150528;          // CB*150528 packed Tt re
    size_t oTTIM  = oTTRE + (size_t)CB * 150528;         // CB*150528 packed Tt im
    size_t oFFTIN = oTTIM + (size_t)CB * 150528;         // CB*301056 fp32 (ends CB*752640 < CB*802816)
    size_t oBIG1  = oC1P;                                // CB*401408 (packed, wf1/wd1 out)
    size_t oBIG2  = oC2P;                                // CB*200704 fp32 (mfma64 out)

    unsigned* WREp = (unsigned*)(ws + oWRE);
    unsigned* WIMp = (unsigned*)(ws + oWIM);
    unsigned* W1s = (unsigned*)(ws + oW1s);
    unsigned* W2s = (unsigned*)(ws + oW2s);
    unsigned* W3s = (unsigned*)(ws + oW3s);
    unsigned* WF2s = (unsigned*)(ws + oWF2s);
    unsigned* WD2s = (unsigned*)(ws + oWD2s);
    unsigned* STEMP = (unsigned*)(ws + oSTEMP);
    unsigned* C1P   = (unsigned*)(ws + oC1P);
    unsigned* C2P   = (unsigned*)(ws + oC2P);
    unsigned* XPK   = (unsigned*)(ws + oXPK);
    unsigned* TTRE  = (unsigned*)(ws + oTTRE);
    unsigned* TTIM  = (unsigned*)(ws + oTTIM);
    unsigned* BIG1P = (unsigned*)(ws + oBIG1);

    // ---- batch-independent prep ----
    hipMemsetAsync(ws + oFREQACC, 0,
                   (size_t)BATCH * (512 + 1024 + 512 + 64) * sizeof(float), stream);
    make_dft<<<196, 256, 0, stream>>>(WREp, WIMp);
    make_wsum<<<1, 288, 0, stream>>>(wd1, ws + oWSUM);
    prep_w<<<(128 * 64 * 9 + 255) / 256, 256, 0, stream>>>(w1, W1s, 128, 64);
    prep_w<<<(256 * 128 * 9 + 255) / 256, 256, 0, stream>>>(w2, W2s, 256, 128);
    prep_w<<<(512 * 256 * 9 + 255) / 256, 256, 0, stream>>>(w3, W3s, 512, 256);
    prep_w<<<(64 * 32 * 9 + 255) / 256, 256, 0, stream>>>(wf2, WF2s, 64, 32);
    prep_w<<<(64 * 32 * 9 + 255) / 256, 256, 0, stream>>>(wd2, WD2s, 64, 32);
    dct_partial<<<dim3(BATCH, 12), 256, 0, stream>>>(x, ws + oDCTACC);
    dct_final<<<BATCH, 64, 0, stream>>>(ws + oDCTACC, ws + oDCT);
    resize_bilinear<<<12544, 256, 0, stream>>>(ws + oDCT, ws + oDIMG);

    // ---- per-image pipeline in batch chunks ----
    for (int b0 = 0; b0 < BATCH; b0 += CB) {
        const float* xc = x + (size_t)b0 * 3 * IMG2;
        // FFT branch: pack X, MFMA DFT stage1'/stage2', then convs
        pack_f32<<<(CB * 3 * (int)IMG2 + 255) / 256, 256, 0, stream>>>(
            xc, XPK, CB * 3 * (int)IMG2);
        dft_mfma_s1<<<dim3(7, 7, 3 * CB), 64, 0, stream>>>(WREp, WIMp, XPK, TTRE, TTIM);
        dft_mfma_s2<<<dim3(7, 7, 3 * CB), 64, 0, stream>>>(WREp, WIMp, TTRE, TTIM, ws + oFFTIN);
        conv3x3_s2<32, 8, 14, 6, true><<<dim3(112, 1, CB), 256, 0, stream>>>(
            ws + oFFTIN, wf1, bf1, ws + oBIG1, 6, 32, 224, 224, 112, 112);
        conv3x3s2_mfma64<<<dim3(CB * 3136 / 64, 1, 1), 256, 0, stream>>>(
            BIG1P, WF2s, bf2, ws + oBIG2, 112, 112, 56, 56, CB * 3136);
        pool7<<<(CB * 64 * 49 + 255) / 256, 256, 0, stream>>>(
            ws + oBIG2, ws + oFREQIN + (size_t)b0 * 6272, 3136, CB * 64 * 49);
        // DCT branch
        conv3x3_s2<32, 8, 14, 1, true><<<dim3(112, 1, CB), 256, 0, stream>>>(
            ws + oDIMG + (size_t)b0 * IMG2, ws + oWSUM, bd1, ws + oBIG1, 1, 32, 224, 224, 112, 112);
        conv3x3s2_mfma64<<<dim3(CB * 3136 / 64, 1, 1), 256, 0, stream>>>(
            BIG1P, WD2s, bd2, ws + oBIG2, 112, 112, 56, 56, CB * 3136);
        pool7<<<(CB * 64 * 49 + 255) / 256, 256, 0, stream>>>(
            ws + oBIG2, ws + oFREQIN + (size_t)b0 * 6272, 0, CB * 64 * 49);
        // backbone
        conv7x7_s2_pack<<<dim3(224, 1, CB), 256, 0, stream>>>(xc, w_stem, b_stem, STEMP);
        conv3x3s2_mfma<<<dim3((CB * 3136 + 63) / 64, 1, 1), 256, 0, stream>>>(
            STEMP, W1s, b1, C1P, nullptr, nullptr,
            64, 128, 112, 112, 56, 56, CB * 3136, 64, 0);
        conv3x3s2_mfma<<<dim3((CB * 784 + 63) / 64, 2, 1), 256, 0, stream>>>(
            C1P, W2s, b2, C2P, nullptr, nullptr,
            128, 256, 56, 56, 28, 28, CB * 784, 128, 0);
        conv3x3s2_mfma<<<dim3((CB * 196 + 63) / 64, 4, 2), 256, 0, stream>>>(
            C2P, W3s, b3, nullptr, ws + oC3a, ws + oC3b,
            256, 512, 28, 28, 14, 14, CB * 196, 128, 1);
        gap2_kernel<<<(CB * 512 * 64 + 255) / 256, 256, 0, stream>>>(
            ws + oC3a, ws + oC3b, b3, ws + oCOMB + (size_t)b0 * 1024, CB * 512);
    }

    // ---- fusion ----
    gemm64_atomic<<<dim3(8, 1, 98), 256, 0, stream>>>(ws + oFREQIN, W_freq, ws + oFREQACC,
                                                      512, 6272, 64);
    bias_relu_copy<<<128, 256, 0, stream>>>(ws + oFREQACC, b_freq, ws + oCOMB, 512, 1024, 512);
    gemm64_atomic<<<dim3(16, 1, 16), 256, 0, stream>>>(ws + oCOMB, W_fu1, ws + oFU1,
                                                       1024, 1024, 64);
    bias_relu_copy<<<256, 256, 0, stream>>>(ws + oFU1, b_fu1, ws + oFU1, 1024, 1024, 0);
    gemm64_atomic<<<dim3(8, 1, 16), 256, 0, stream>>>(ws + oFU1, W_fu2, ws + oFUSED,
                                                      512, 1024, 64);
    bias_relu_copy<<<128, 256, 0, stream>>>(ws + oFUSED, b_fu2, ws + oFUSED, 512, 512, 0);
    logits_kernel<<<1, 128, 0, stream>>>(ws + oFUSED, W_cls, b_cls, temp, out);
}

// Round 6
// 2077.055 us; speedup vs baseline: 2.8683x; 1.0554x over previous
//
#include <hip/hip_runtime.h>

#ifndef M_PI
#define M_PI 3.14159265358979323846
#endif

// ============================================================================
// EnhancedAIDetector — round 6:
//  - stem 7x7 conv (was 407us fp32 VALU @ 37TF) -> MFMA implicit GEMM,
//    K = ky*32 + kx*4 + ci (224 = 7 exact chunks, pure bit-op decode,
//    zero-padded weight slots), input reused from packed XPK.
//  - chunk workspace re-laid: XPK live through stem; C3a/b alias dead XPK.
// ============================================================================

#define BATCH 64

typedef __bf16 bf16x8 __attribute__((ext_vector_type(8)));
typedef float f32x4 __attribute__((ext_vector_type(4)));

__device__ __forceinline__ unsigned short f2bf(float f) {
    unsigned u = __float_as_uint(f);
    u += 0x7FFF + ((u >> 16) & 1);      // RNE
    return (unsigned short)(u >> 16);
}
__device__ __forceinline__ unsigned packsplit(float v) {
    unsigned short h = f2bf(v);
    float hf = __uint_as_float(((unsigned)h) << 16);
    unsigned short l = f2bf(v - hf);
    return (((unsigned)h) << 16) | (unsigned)l;
}

union U8frag { bf16x8 v; unsigned d[4]; };

// unpack 8 packed dwords at p (LDS or global) -> hi fragment + lo fragment
__device__ __forceinline__ void unpack8(const unsigned* p, bf16x8& hi, bf16x8& lo) {
    uint4 a = *(const uint4*)p;
    uint4 b = *(const uint4*)(p + 4);
    U8frag H, L;
    H.d[0] = __builtin_amdgcn_perm(a.y, a.x, 0x07060302u);
    L.d[0] = __builtin_amdgcn_perm(a.y, a.x, 0x05040100u);
    H.d[1] = __builtin_amdgcn_perm(a.w, a.z, 0x07060302u);
    L.d[1] = __builtin_amdgcn_perm(a.w, a.z, 0x05040100u);
    H.d[2] = __builtin_amdgcn_perm(b.y, b.x, 0x07060302u);
    L.d[2] = __builtin_amdgcn_perm(b.y, b.x, 0x05040100u);
    H.d[3] = __builtin_amdgcn_perm(b.w, b.z, 0x07060302u);
    L.d[3] = __builtin_amdgcn_perm(b.w, b.z, 0x05040100u);
    hi = H.v; lo = L.v;
}

__device__ __forceinline__ bf16x8 bfneg(bf16x8 v) {
    U8frag a; a.v = v;
    a.d[0] ^= 0x80008000u; a.d[1] ^= 0x80008000u;
    a.d[2] ^= 0x80008000u; a.d[3] ^= 0x80008000u;
    return a.v;
}

// ============================================================================
// Weight prep: fp32 [Co][Ci][3][3] -> packed split [9][Co][Ci]
// ============================================================================
__global__ void prep_w(const float* __restrict__ w, unsigned* __restrict__ dst,
                       int Co, int Ci) {
    int idx = blockIdx.x * 256 + threadIdx.x;
    int tot = Co * Ci * 9;
    if (idx >= tot) return;
    int k9 = idx % 9;
    int rest = idx / 9;
    int ci = rest % Ci, co = rest / Ci;
    dst[((size_t)k9 * Co + co) * Ci + ci] = packsplit(w[idx]);
}

// stem weight prep: fp32 [64][3][7][7] -> packed [64][224], k = ky*32+kx*4+ci
__global__ void prep_wstem(const float* __restrict__ w, unsigned* __restrict__ dst) {
    int idx = blockIdx.x * 256 + threadIdx.x;
    if (idx >= 64 * 224) return;
    int co = idx / 224, k = idx % 224;
    int ci = k & 3, kx = (k >> 2) & 7, ky = k >> 5;
    float v = 0.f;
    if (ci < 3 && kx < 7)
        v = w[((co * 3 + ci) * 7 + ky) * 7 + kx];
    dst[idx] = packsplit(v);
}

// generic fp32 -> packed split copy
__global__ void pack_f32(const float* __restrict__ src, unsigned* __restrict__ dst, int n) {
    int i = blockIdx.x * 256 + threadIdx.x;
    if (i < n) dst[i] = packsplit(src[i]);
}

// ============================================================================
// MFMA implicit-GEMM 3x3 s2 conv, 128co x 64n tile (backbone conv1/2/3).
// ============================================================================
__global__ __launch_bounds__(256)
void conv3x3s2_mfma(const unsigned* __restrict__ inP, const unsigned* __restrict__ wP,
                    const float* __restrict__ bias,
                    unsigned* __restrict__ outPk, float* __restrict__ outF0,
                    float* __restrict__ outF1,
                    int Ci, int Co, int Hin, int Win, int Hout, int Wout,
                    int NTOT, int ciPer, int mode) {
    __shared__ unsigned sA[128 * 36];
    __shared__ unsigned sB[64 * 36];
    const int tid = threadIdx.x;
    const int wv = tid >> 6, lane = tid & 63;
    const int ciBeg = blockIdx.z * ciPer;
    const int coT0 = blockIdx.y * 128;
    const int HWin = Hin * Win, HWout = Hout * Wout;

    const int nG = blockIdx.x * 64 + (tid >> 2);
    const int kqB = tid & 3;
    int bb = 0, yy = 0, xx = 0;
    bool nval = nG < NTOT;
    if (nval) {
        bb = nG / HWout;
        int rem = nG - bb * HWout;
        yy = rem / Wout;
        xx = rem - yy * Wout;
    }
    const unsigned baseImg = (unsigned)bb * Ci * HWin;
    const int coA = tid >> 1, halfA = tid & 1;

    f32x4 acc[2][4];
#pragma unroll
    for (int s = 0; s < 2; s++)
#pragma unroll
        for (int t = 0; t < 4; t++) acc[s][t] = (f32x4){0.f, 0.f, 0.f, 0.f};

    for (int k9 = 0; k9 < 9; k9++) {
        int ky = k9 / 3, kx = k9 - ky * 3;
        int iy = 2 * yy + ky, ix = 2 * xx + kx;
        bool bval = nval && iy < Hin && ix < Win;
        unsigned off0 = baseImg + (unsigned)iy * Win + (unsigned)ix;
        const unsigned* wbase = wP + ((size_t)k9 * Co + coT0 + coA) * Ci + ciBeg + halfA * 16;

        for (int c0 = 0; c0 < ciPer; c0 += 32) {
            __syncthreads();
            {
                const uint4* g = (const uint4*)(wbase + c0);
                uint4 v0 = g[0], v1 = g[1], v2 = g[2], v3 = g[3];
                uint4* d = (uint4*)(sA + coA * 36 + halfA * 16);
                d[0] = v0; d[1] = v1; d[2] = v2; d[3] = v3;
            }
            {
                unsigned u[8];
                const unsigned cbase = off0 + (unsigned)(ciBeg + c0 + kqB * 8) * HWin;
#pragma unroll
                for (int j = 0; j < 8; j++)
                    u[j] = bval ? inP[cbase + (unsigned)j * HWin] : 0u;
                uint4* d = (uint4*)(sB + (tid >> 2) * 36 + kqB * 8);
                uint4 w0; w0.x = u[0]; w0.y = u[1]; w0.z = u[2]; w0.w = u[3];
                uint4 w1; w1.x = u[4]; w1.y = u[5]; w1.z = u[6]; w1.w = u[7];
                d[0] = w0; d[1] = w1;
            }
            __syncthreads();

            bf16x8 ah[2], al[2], bh[4], bl[4];
            const int m = lane & 15, q = lane >> 4;
#pragma unroll
            for (int s = 0; s < 2; s++)
                unpack8(sA + (wv * 32 + s * 16 + m) * 36 + q * 8, ah[s], al[s]);
#pragma unroll
            for (int t = 0; t < 4; t++)
                unpack8(sB + (t * 16 + m) * 36 + q * 8, bh[t], bl[t]);

#pragma unroll
            for (int s = 0; s < 2; s++)
#pragma unroll
                for (int t = 0; t < 4; t++)
                    acc[s][t] = __builtin_amdgcn_mfma_f32_16x16x32_bf16(ah[s], bh[t], acc[s][t], 0, 0, 0);
#pragma unroll
            for (int s = 0; s < 2; s++)
#pragma unroll
                for (int t = 0; t < 4; t++)
                    acc[s][t] = __builtin_amdgcn_mfma_f32_16x16x32_bf16(ah[s], bl[t], acc[s][t], 0, 0, 0);
#pragma unroll
            for (int s = 0; s < 2; s++)
#pragma unroll
                for (int t = 0; t < 4; t++)
                    acc[s][t] = __builtin_amdgcn_mfma_f32_16x16x32_bf16(al[s], bh[t], acc[s][t], 0, 0, 0);
        }
    }

    const int m = lane & 15, q = lane >> 4;
#pragma unroll
    for (int t = 0; t < 4; t++) {
        int n_g = blockIdx.x * 64 + t * 16 + m;
        if (n_g >= NTOT) continue;
        int b = n_g / HWout;
        int rem = n_g - b * HWout;
        size_t nb = (size_t)b * Co * HWout + rem;
#pragma unroll
        for (int s = 0; s < 2; s++) {
            int co_l = wv * 32 + s * 16 + q * 4;
#pragma unroll
            for (int r = 0; r < 4; r++) {
                int co_g = coT0 + co_l + r;
                float v = acc[s][t][r];
                size_t addr = nb + (size_t)co_g * HWout;
                if (mode == 0) {
                    v += bias[co_g];
                    v = v > 0.f ? v : 0.f;
                    outPk[addr] = packsplit(v);
                } else {
                    (blockIdx.z == 0 ? outF0 : outF1)[addr] = v;
                }
            }
        }
    }
}

// ============================================================================
// MFMA implicit-GEMM 3x3 s2 conv, 64co x 64n tile, Ci == 32 (wf2 / wd2).
// ============================================================================
__global__ __launch_bounds__(256)
void conv3x3s2_mfma64(const unsigned* __restrict__ inP, const unsigned* __restrict__ wP,
                      const float* __restrict__ bias, float* __restrict__ outF,
                      int Hin, int Win, int Hout, int Wout, int NTOT) {
    const int Ci = 32;
    __shared__ unsigned sA[64 * 36];
    __shared__ unsigned sB[64 * 36];
    const int tid = threadIdx.x;
    const int wv = tid >> 6, lane = tid & 63;
    const int HWin = Hin * Win, HWout = Hout * Wout;

    const int nG = blockIdx.x * 64 + (tid >> 2);
    const int kq = tid & 3;
    int bb = 0, yy = 0, xx = 0;
    bool nval = nG < NTOT;
    if (nval) {
        bb = nG / HWout;
        int rem = nG - bb * HWout;
        yy = rem / Wout;
        xx = rem - yy * Wout;
    }
    const unsigned baseImg = (unsigned)bb * Ci * HWin;
    const int ch = wv & 1, nh = wv >> 1;

    f32x4 acc[2][2];
#pragma unroll
    for (int s = 0; s < 2; s++)
#pragma unroll
        for (int t = 0; t < 2; t++) acc[s][t] = (f32x4){0.f, 0.f, 0.f, 0.f};

    for (int k9 = 0; k9 < 9; k9++) {
        int ky = k9 / 3, kx = k9 - ky * 3;
        int iy = 2 * yy + ky, ix = 2 * xx + kx;
        bool bval = nval && iy < Hin && ix < Win;
        unsigned off0 = baseImg + (unsigned)iy * Win + (unsigned)ix;
        __syncthreads();
        {
            const unsigned* g = wP + ((size_t)k9 * 64 + (tid >> 2)) * Ci + kq * 8;
            uint4 v0 = *(const uint4*)g;
            uint4 v1 = *(const uint4*)(g + 4);
            uint4* d = (uint4*)(sA + (tid >> 2) * 36 + kq * 8);
            d[0] = v0; d[1] = v1;
        }
        {
            unsigned u[8];
            const unsigned cbase = off0 + (unsigned)(kq * 8) * HWin;
#pragma unroll
            for (int j = 0; j < 8; j++)
                u[j] = bval ? inP[cbase + (unsigned)j * HWin] : 0u;
            uint4* d = (uint4*)(sB + (tid >> 2) * 36 + kq * 8);
            uint4 w0; w0.x = u[0]; w0.y = u[1]; w0.z = u[2]; w0.w = u[3];
            uint4 w1; w1.x = u[4]; w1.y = u[5]; w1.z = u[6]; w1.w = u[7];
            d[0] = w0; d[1] = w1;
        }
        __syncthreads();

        bf16x8 ah[2], al[2], bh[2], bl[2];
        const int m = lane & 15, q = lane >> 4;
#pragma unroll
        for (int s = 0; s < 2; s++)
            unpack8(sA + (ch * 32 + s * 16 + m) * 36 + q * 8, ah[s], al[s]);
#pragma unroll
        for (int t = 0; t < 2; t++)
            unpack8(sB + (nh * 32 + t * 16 + m) * 36 + q * 8, bh[t], bl[t]);

#pragma unroll
        for (int s = 0; s < 2; s++)
#pragma unroll
            for (int t = 0; t < 2; t++)
                acc[s][t] = __builtin_amdgcn_mfma_f32_16x16x32_bf16(ah[s], bh[t], acc[s][t], 0, 0, 0);
#pragma unroll
        for (int s = 0; s < 2; s++)
#pragma unroll
            for (int t = 0; t < 2; t++)
                acc[s][t] = __builtin_amdgcn_mfma_f32_16x16x32_bf16(ah[s], bl[t], acc[s][t], 0, 0, 0);
#pragma unroll
        for (int s = 0; s < 2; s++)
#pragma unroll
            for (int t = 0; t < 2; t++)
                acc[s][t] = __builtin_amdgcn_mfma_f32_16x16x32_bf16(al[s], bh[t], acc[s][t], 0, 0, 0);
    }

    const int m = lane & 15, q = lane >> 4;
#pragma unroll
    for (int t = 0; t < 2; t++) {
        int n_g = blockIdx.x * 64 + nh * 32 + t * 16 + m;
        if (n_g >= NTOT) continue;
        int b = n_g / HWout;
        int rem = n_g - b * HWout;
        size_t nb = (size_t)b * 64 * HWout + rem;
#pragma unroll
        for (int s = 0; s < 2; s++) {
            int co0 = ch * 32 + s * 16 + q * 4;
#pragma unroll
            for (int r = 0; r < 4; r++) {
                int co = co0 + r;
                float v = acc[s][t][r] + bias[co];
                outF[nb + (size_t)co * HWout] = v > 0.f ? v : 0.f;
            }
        }
    }
}

// ============================================================================
// Stem 7x7 s2 conv as MFMA implicit GEMM.  K = ky*32 + kx*4 + ci (224 total,
// 7 exact chunks of 32; ci==3 / kx==7 slots carry zero weights).
// inP: packed x [CB][3][224*224]; wP: packed [64][224]; out: packed stem act.
// Tile 64co x 64n, 256 threads.  grid.x = NTOT/64 (exact).
// ============================================================================
__global__ __launch_bounds__(256)
void conv7x7s2_mfma(const unsigned* __restrict__ inP, const unsigned* __restrict__ wP,
                    const float* __restrict__ bias, unsigned* __restrict__ outPk,
                    int NTOT) {
    __shared__ unsigned sA[64 * 36];
    __shared__ unsigned sB[64 * 36];
    const int tid = threadIdx.x;
    const int wv = tid >> 6, lane = tid & 63;
    const int HWout = 112 * 112;

    const int nG = blockIdx.x * 64 + (tid >> 2);
    const int kq = tid & 3;
    bool nval = nG < NTOT;
    int bb = 0, yy = 0, xx = 0;
    if (nval) {
        bb = nG / HWout;
        int rem = nG - bb * HWout;
        yy = rem / 112;
        xx = rem - yy * 112;
    }
    const int iy0 = 2 * yy - 2, ix0 = 2 * xx - 2;
    const unsigned baseImg = (unsigned)bb * 3 * 50176;
    const int ch = wv & 1, nh = wv >> 1;

    f32x4 acc[2][2];
#pragma unroll
    for (int s = 0; s < 2; s++)
#pragma unroll
        for (int t = 0; t < 2; t++) acc[s][t] = (f32x4){0.f, 0.f, 0.f, 0.f};

#pragma unroll
    for (int kyc = 0; kyc < 7; kyc++) {          // chunk index == ky
        const int c0 = kyc * 32;
        const int iy = iy0 + kyc;
        const bool iyv = nval && iy >= 0 && iy < 224;
        __syncthreads();
        {   // stage A: co row = tid>>2, 8 dwords at kq*8
            const unsigned* g = wP + (tid >> 2) * 224 + c0 + kq * 8;
            uint4 v0 = *(const uint4*)g;
            uint4 v1 = *(const uint4*)(g + 4);
            uint4* d = (uint4*)(sA + (tid >> 2) * 36 + kq * 8);
            d[0] = v0; d[1] = v1;
        }
        {   // stage B gather: j in 0..7 -> ci=j&3, kx=kq*2+(j>>2)
            unsigned u[8];
            const unsigned rowbase = baseImg + (unsigned)(iy * 224);
#pragma unroll
            for (int j = 0; j < 8; j++) {
                int ci = j & 3;
                int kx = kq * 2 + (j >> 2);
                int ix = ix0 + kx;
                bool v = iyv && ci < 3 && kx < 7 && ix >= 0 && ix < 224;
                u[j] = v ? inP[rowbase + (unsigned)(ci * 50176 + ix)] : 0u;
            }
            uint4* d = (uint4*)(sB + (tid >> 2) * 36 + kq * 8);
            uint4 w0; w0.x = u[0]; w0.y = u[1]; w0.z = u[2]; w0.w = u[3];
            uint4 w1; w1.x = u[4]; w1.y = u[5]; w1.z = u[6]; w1.w = u[7];
            d[0] = w0; d[1] = w1;
        }
        __syncthreads();

        bf16x8 ah[2], al[2], bh[2], bl[2];
        const int m = lane & 15, q = lane >> 4;
#pragma unroll
        for (int s = 0; s < 2; s++)
            unpack8(sA + (ch * 32 + s * 16 + m) * 36 + q * 8, ah[s], al[s]);
#pragma unroll
        for (int t = 0; t < 2; t++)
            unpack8(sB + (nh * 32 + t * 16 + m) * 36 + q * 8, bh[t], bl[t]);

#pragma unroll
        for (int s = 0; s < 2; s++)
#pragma unroll
            for (int t = 0; t < 2; t++)
                acc[s][t] = __builtin_amdgcn_mfma_f32_16x16x32_bf16(ah[s], bh[t], acc[s][t], 0, 0, 0);
#pragma unroll
        for (int s = 0; s < 2; s++)
#pragma unroll
            for (int t = 0; t < 2; t++)
                acc[s][t] = __builtin_amdgcn_mfma_f32_16x16x32_bf16(ah[s], bl[t], acc[s][t], 0, 0, 0);
#pragma unroll
        for (int s = 0; s < 2; s++)
#pragma unroll
            for (int t = 0; t < 2; t++)
                acc[s][t] = __builtin_amdgcn_mfma_f32_16x16x32_bf16(al[s], bh[t], acc[s][t], 0, 0, 0);
    }

    const int m = lane & 15, q = lane >> 4;
#pragma unroll
    for (int t = 0; t < 2; t++) {
        int n_g = blockIdx.x * 64 + nh * 32 + t * 16 + m;
        if (n_g >= NTOT) continue;
        int b = n_g / HWout;
        int rem = n_g - b * HWout;
        size_t nb = (size_t)b * 64 * HWout + rem;
#pragma unroll
        for (int s = 0; s < 2; s++) {
            int co0 = ch * 32 + s * 16 + q * 4;
#pragma unroll
            for (int r = 0; r < 4; r++) {
                int co = co0 + r;
                float v = acc[s][t][r] + bias[co];
                v = v > 0.f ? v : 0.f;
                outPk[nb + (size_t)co * HWout] = packsplit(v);
            }
        }
    }
}

// ============================================================================
// DFT matrix (packed split bf16):  W[j,k] = exp(-2*pi*i * j*k / 224)
// ============================================================================
__global__ void make_dft(unsigned* __restrict__ wre, unsigned* __restrict__ wim) {
    int idx = blockIdx.x * 256 + threadIdx.x;
    if (idx >= 224 * 224) return;
    int j = idx / 224, k = idx % 224;
    int m = (j * k) % 224;
    double a = -2.0 * M_PI * (double)m / 224.0;
    wre[idx] = packsplit((float)cos(a));
    wim[idx] = packsplit((float)sin(a));
}

__global__ void make_wsum(const float* __restrict__ wd1, float* __restrict__ wsum) {
    int idx = threadIdx.x;
    if (idx >= 288) return;
    int o = idx / 9, k = idx % 9;
    wsum[idx] = wd1[o * 27 + k] + wd1[o * 27 + 9 + k] + wd1[o * 27 + 18 + k];
}

// ============================================================================
// DFT stage 1 (MFMA): Tt = W @ X^T
// ============================================================================
__global__ __launch_bounds__(64)
void dft_mfma_s1(const unsigned* __restrict__ wre, const unsigned* __restrict__ wim,
                 const unsigned* __restrict__ xpk,
                 unsigned* __restrict__ ttre, unsigned* __restrict__ ttim) {
    const int z = blockIdx.z;
    const int m0 = blockIdx.x * 32, n0 = blockIdx.y * 32;
    const int lane = threadIdx.x;
    const int ml = lane & 15, q = lane >> 4;
    const unsigned* xb = xpk + (size_t)z * 50176;

    f32x4 cre[2][2], cim[2][2];
#pragma unroll
    for (int s = 0; s < 2; s++)
#pragma unroll
        for (int t = 0; t < 2; t++) { cre[s][t] = (f32x4){0,0,0,0}; cim[s][t] = (f32x4){0,0,0,0}; }

    for (int k0 = 0; k0 < 224; k0 += 32) {
        bf16x8 arh[2], arl[2], aih[2], ail[2], bh[2], bl[2];
#pragma unroll
        for (int s = 0; s < 2; s++) {
            int row = m0 + s * 16 + ml;
            unpack8(wre + row * 224 + k0 + q * 8, arh[s], arl[s]);
            unpack8(wim + row * 224 + k0 + q * 8, aih[s], ail[s]);
        }
#pragma unroll
        for (int t = 0; t < 2; t++)
            unpack8(xb + (n0 + t * 16 + ml) * 224 + k0 + q * 8, bh[t], bl[t]);

#pragma unroll
        for (int s = 0; s < 2; s++)
#pragma unroll
            for (int t = 0; t < 2; t++) {
                cre[s][t] = __builtin_amdgcn_mfma_f32_16x16x32_bf16(arh[s], bh[t], cre[s][t], 0, 0, 0);
                cre[s][t] = __builtin_amdgcn_mfma_f32_16x16x32_bf16(arh[s], bl[t], cre[s][t], 0, 0, 0);
                cre[s][t] = __builtin_amdgcn_mfma_f32_16x16x32_bf16(arl[s], bh[t], cre[s][t], 0, 0, 0);
                cim[s][t] = __builtin_amdgcn_mfma_f32_16x16x32_bf16(aih[s], bh[t], cim[s][t], 0, 0, 0);
                cim[s][t] = __builtin_amdgcn_mfma_f32_16x16x32_bf16(aih[s], bl[t], cim[s][t], 0, 0, 0);
                cim[s][t] = __builtin_amdgcn_mfma_f32_16x16x32_bf16(ail[s], bh[t], cim[s][t], 0, 0, 0);
            }
    }

    unsigned* tre = ttre + (size_t)z * 50176;
    unsigned* tim = ttim + (size_t)z * 50176;
#pragma unroll
    for (int s = 0; s < 2; s++)
#pragma unroll
        for (int t = 0; t < 2; t++)
#pragma unroll
            for (int r = 0; r < 4; r++) {
                int m = m0 + s * 16 + q * 4 + r;
                int n = n0 + t * 16 + ml;
                tre[m * 224 + n] = packsplit(cre[s][t][r]);
                tim[m * 224 + n] = packsplit(cim[s][t][r]);
            }
}

// ============================================================================
// DFT stage 2 (MFMA): Y = W @ T, complex; output fp32 fft_in
// ============================================================================
__global__ __launch_bounds__(64)
void dft_mfma_s2(const unsigned* __restrict__ wre, const unsigned* __restrict__ wim,
                 const unsigned* __restrict__ ttre, const unsigned* __restrict__ ttim,
                 float* __restrict__ fft_in) {
    const int z = blockIdx.z;
    const int m0 = blockIdx.x * 32, n0 = blockIdx.y * 32;
    const int lane = threadIdx.x;
    const int ml = lane & 15, q = lane >> 4;
    const unsigned* tre = ttre + (size_t)z * 50176;
    const unsigned* tim = ttim + (size_t)z * 50176;

    f32x4 cre[2][2], cim[2][2];
#pragma unroll
    for (int s = 0; s < 2; s++)
#pragma unroll
        for (int t = 0; t < 2; t++) { cre[s][t] = (f32x4){0,0,0,0}; cim[s][t] = (f32x4){0,0,0,0}; }

    for (int k0 = 0; k0 < 224; k0 += 32) {
        bf16x8 arh[2], arl[2], aih[2], ail[2];
        bf16x8 brh[2], brl[2], bih[2], bil[2];
#pragma unroll
        for (int s = 0; s < 2; s++) {
            int row = m0 + s * 16 + ml;
            unpack8(wre + row * 224 + k0 + q * 8, arh[s], arl[s]);
            unpack8(wim + row * 224 + k0 + q * 8, aih[s], ail[s]);
        }
#pragma unroll
        for (int t = 0; t < 2; t++) {
            int row = n0 + t * 16 + ml;
            unpack8(tre + row * 224 + k0 + q * 8, brh[t], brl[t]);
            unpack8(tim + row * 224 + k0 + q * 8, bih[t], bil[t]);
        }

#pragma unroll
        for (int t = 0; t < 2; t++) {
            bf16x8 nih = bfneg(bih[t]);
            bf16x8 nil = bfneg(bil[t]);
#pragma unroll
            for (int s = 0; s < 2; s++) {
                cre[s][t] = __builtin_amdgcn_mfma_f32_16x16x32_bf16(arh[s], brh[t], cre[s][t], 0, 0, 0);
                cre[s][t] = __builtin_amdgcn_mfma_f32_16x16x32_bf16(arh[s], brl[t], cre[s][t], 0, 0, 0);
                cre[s][t] = __builtin_amdgcn_mfma_f32_16x16x32_bf16(arl[s], brh[t], cre[s][t], 0, 0, 0);
                cre[s][t] = __builtin_amdgcn_mfma_f32_16x16x32_bf16(aih[s], nih, cre[s][t], 0, 0, 0);
                cre[s][t] = __builtin_amdgcn_mfma_f32_16x16x32_bf16(aih[s], nil, cre[s][t], 0, 0, 0);
                cre[s][t] = __builtin_amdgcn_mfma_f32_16x16x32_bf16(ail[s], nih, cre[s][t], 0, 0, 0);
                cim[s][t] = __builtin_amdgcn_mfma_f32_16x16x32_bf16(arh[s], bih[t], cim[s][t], 0, 0, 0);
                cim[s][t] = __builtin_amdgcn_mfma_f32_16x16x32_bf16(arh[s], bil[t], cim[s][t], 0, 0, 0);
                cim[s][t] = __builtin_amdgcn_mfma_f32_16x16x32_bf16(arl[s], bih[t], cim[s][t], 0, 0, 0);
                cim[s][t] = __builtin_amdgcn_mfma_f32_16x16x32_bf16(aih[s], brh[t], cim[s][t], 0, 0, 0);
                cim[s][t] = __builtin_amdgcn_mfma_f32_16x16x32_bf16(aih[s], brl[t], cim[s][t], 0, 0, 0);
                cim[s][t] = __builtin_amdgcn_mfma_f32_16x16x32_bf16(ail[s], brh[t], cim[s][t], 0, 0, 0);
            }
        }
    }

    const int b_loc = z / 3, c = z % 3;
    float* yre = fft_in + (size_t)(b_loc * 6 + 2 * c) * 50176;
    float* yim = yre + 50176;
#pragma unroll
    for (int s = 0; s < 2; s++)
#pragma unroll
        for (int t = 0; t < 2; t++)
#pragma unroll
            for (int r = 0; r < 4; r++) {
                int m = m0 + s * 16 + q * 4 + r;
                int n = n0 + t * 16 + ml;
                yre[m * 224 + n] = cre[s][t][r];
                yim[m * 224 + n] = cim[s][t][r];
            }
}

// ============================================================================
// fp32 direct 3x3 s2 conv; PACK=true writes split-bf16 packed dwords.
// ============================================================================
template <int CO_BLK, int TH, int TW, int CI_CHUNK, bool PACK>
__global__ __launch_bounds__(CO_BLK * TH)
void conv3x3_s2(const float* __restrict__ in, const float* __restrict__ w,
                const float* __restrict__ bias, float* __restrict__ out,
                int Ci, int Co, int Hin, int Win, int Hout, int Wout) {
    constexpr int IN_H = 2 * TH + 1;
    constexpr int IN_W = 2 * TW + 1;
    constexpr int IN_WP = 32;
    constexpr int WSTR = (CI_CHUNK * 9) | 1;
    __shared__ __align__(16) float s_in[CI_CHUNK][IN_H][IN_WP];
    __shared__ float s_w[CO_BLK * WSTR];

    const int tid = threadIdx.x;
    const int tiles_x = Wout / TW;
    const int tile = blockIdx.x;
    const int ty0 = (tile / tiles_x) * TH;
    const int tx0 = (tile % tiles_x) * TW;
    const int cog = blockIdx.y;
    const int b = blockIdx.z;
    const int co = tid % CO_BLK;
    const int ty = tid / CO_BLK;
    const int co_g = cog * CO_BLK + co;

    float acc[TW];
#pragma unroll
    for (int i = 0; i < TW; i++) acc[i] = 0.f;

    const float* in_b = in + (size_t)b * Ci * Hin * Win;
    const int iy0 = 2 * ty0, ix0 = 2 * tx0;

    for (int ci0 = 0; ci0 < Ci; ci0 += CI_CHUNK) {
        for (int idx = tid; idx < CI_CHUNK * IN_H * IN_W; idx += CO_BLK * TH) {
            int ci = idx / (IN_H * IN_W);
            int rem = idx % (IN_H * IN_W);
            int r = rem / IN_W, cc = rem % IN_W;
            int gy = iy0 + r, gx = ix0 + cc;
            float v = 0.f;
            if (gy < Hin && gx < Win)
                v = in_b[(size_t)(ci0 + ci) * Hin * Win + (size_t)gy * Win + gx];
            s_in[ci][r][cc] = v;
        }
        for (int idx = tid; idx < CO_BLK * CI_CHUNK * 9; idx += CO_BLK * TH) {
            int c = idx / (CI_CHUNK * 9);
            int k = idx % (CI_CHUNK * 9);
            s_w[c * WSTR + k] = w[((size_t)(cog * CO_BLK + c) * Ci + ci0) * 9 + k];
        }
        __syncthreads();

#pragma unroll
        for (int ci = 0; ci < CI_CHUNK; ci++) {
            float wr[9];
#pragma unroll
            for (int k = 0; k < 9; k++) wr[k] = s_w[co * WSTR + ci * 9 + k];
#pragma unroll
            for (int ky = 0; ky < 3; ky++) {
                float r[IN_WP];
                const float4* rowp = (const float4*)&s_in[ci][2 * ty + ky][0];
#pragma unroll
                for (int qq = 0; qq < IN_WP / 4; qq++) {
                    float4 v = rowp[qq];
                    r[4 * qq] = v.x; r[4 * qq + 1] = v.y; r[4 * qq + 2] = v.z; r[4 * qq + 3] = v.w;
                }
#pragma unroll
                for (int kx = 0; kx < 3; kx++) {
                    float wv = wr[ky * 3 + kx];
#pragma unroll
                    for (int xq = 0; xq < TW; xq++) acc[xq] += r[2 * xq + kx] * wv;
                }
            }
        }
        __syncthreads();
    }
    float bb = bias[co_g];
    size_t obase = ((size_t)b * Co + co_g) * Hout * Wout + (size_t)(ty0 + ty) * Wout + tx0;
#pragma unroll
    for (int xq = 0; xq < TW; xq++) {
        float v = acc[xq] + bb;
        v = v > 0.f ? v : 0.f;
        if (PACK)
            ((unsigned*)out)[obase + xq] = packsplit(v);
        else
            out[obase + xq] = v;
    }
}

// ============================================================================
// DCT branch: parallel block-mean (2-stage) then 8x8 DCT; bilinear resize.
// ============================================================================
__device__ __forceinline__ float dct_coef(int u, int i) {
    if (u == 0) return 0.35355339059327373f;
    return 0.5f * cosf((float)M_PI * (float)((2 * i + 1) * u) / 16.0f);
}

__global__ __launch_bounds__(256)
void dct_partial(const float* __restrict__ x, float* __restrict__ accum) {
    __shared__ float red[256];
    const int b = blockIdx.x, g = blockIdx.y;
    const int tid = threadIdx.x;
    const int ij = tid & 63;
    const int grp = tid >> 6;
    const int i = ij >> 3, j = ij & 7;
    const float* xb = x + (size_t)b * 3 * 50176;
    float s = 0.f;
    for (int blk = g * 4 + grp; blk < 784; blk += 48) {
        int m = blk / 28, n = blk % 28;
        size_t o = (size_t)(m * 8 + i) * 224 + n * 8 + j;
        s += 0.299f * xb[o] + 0.587f * xb[50176 + o] + 0.114f * xb[2 * 50176 + o];
    }
    red[tid] = s;
    __syncthreads();
    if (tid < 64)
        atomicAdd(&accum[b * 64 + tid],
                  red[tid] + red[tid + 64] + red[tid + 128] + red[tid + 192]);
}

__global__ __launch_bounds__(64)
void dct_final(const float* __restrict__ accum, float* __restrict__ dct_out) {
    __shared__ float Mb[64];
    const int b = blockIdx.x, tid = threadIdx.x;
    Mb[tid] = accum[b * 64 + tid] * (255.f / 784.f);
    __syncthreads();
    int u = tid >> 3, v = tid & 7;
    float acc = 0.f;
#pragma unroll
    for (int i2 = 0; i2 < 8; i2++) {
        float du = dct_coef(u, i2);
#pragma unroll
        for (int j2 = 0; j2 < 8; j2++) acc += du * Mb[i2 * 8 + j2] * dct_coef(v, j2);
    }
    dct_out[b * 64 + tid] = acc;
}

__global__ void resize_bilinear(const float* __restrict__ dct, float* __restrict__ out) {
    int idx = blockIdx.x * 256 + threadIdx.x;
    if (idx >= BATCH * 224 * 224) return;
    int b = idx / (224 * 224);
    int rem = idx % (224 * 224);
    int y = rem / 224, xx = rem % 224;
    float sy = fminf(fmaxf((y + 0.5f) * (1.f / 28.f) - 0.5f, 0.f), 7.f);
    float sx = fminf(fmaxf((xx + 0.5f) * (1.f / 28.f) - 0.5f, 0.f), 7.f);
    int y0 = (int)floorf(sy); if (y0 > 6) y0 = 6;
    int x0 = (int)floorf(sx); if (x0 > 6) x0 = 6;
    float ty = sy - y0, tx = sx - x0;
    const float* M = dct + b * 64;
    float v00 = M[y0 * 8 + x0], v01 = M[y0 * 8 + x0 + 1];
    float v10 = M[(y0 + 1) * 8 + x0], v11 = M[(y0 + 1) * 8 + x0 + 1];
    out[idx] = (1.f - ty) * ((1.f - tx) * v00 + tx * v01) + ty * ((1.f - tx) * v10 + tx * v11);
}

// ============================================================================
// Pooling
// ============================================================================
__global__ void pool7(const float* __restrict__ h, float* __restrict__ out,
                      int col_base, int n) {
    int idx = blockIdx.x * 256 + threadIdx.x;
    if (idx >= n) return;
    int b = idx / (64 * 49);
    int rem = idx % (64 * 49);
    int c = rem / 49;
    int ij = rem % 49;
    int i = ij / 7, j = ij % 7;
    const float* hp = h + ((size_t)(b * 64 + c)) * 56 * 56 + (size_t)i * 8 * 56 + j * 8;
    float s = 0.f;
#pragma unroll
    for (int r = 0; r < 8; r++)
#pragma unroll
        for (int q = 0; q < 8; q++) s += hp[r * 56 + q];
    out[(size_t)b * 6272 + col_base + c * 49 + ij] = s * (1.f / 64.f);
}

__global__ void gap2_kernel(const float* __restrict__ ha, const float* __restrict__ hb,
                            const float* __restrict__ bias, float* __restrict__ comb,
                            int nwaves) {
    int gt = blockIdx.x * blockDim.x + threadIdx.x;
    int wid = gt >> 6;
    int lane = gt & 63;
    if (wid >= nwaves) return;
    int b = wid / 512, c = wid % 512;
    const float* pa = ha + (size_t)wid * 196;
    const float* pb = hb + (size_t)wid * 196;
    float bbv = bias[c];
    float s = 0.f;
    for (int i = lane; i < 196; i += 64) {
        float v = pa[i] + pb[i] + bbv;
        s += v > 0.f ? v : 0.f;
    }
#pragma unroll
    for (int off = 32; off > 0; off >>= 1) s += __shfl_down(s, off);
    if (lane == 0) comb[(size_t)b * 1024 + c] = s * (1.f / 196.f);
}

// ============================================================================
// Fusion GEMMs (fp32, M=64, split-K atomic)
// ============================================================================
__global__ __launch_bounds__(256)
void gemm64_atomic(const float* __restrict__ A, const float* __restrict__ Bm,
                   float* __restrict__ C, int N, int K, int KC) {
    __shared__ __align__(16) float sA[16][68];
    __shared__ __align__(16) float sB[16][68];
    const int tid = threadIdx.x;
    const int n0 = blockIdx.x * 64;
    const int kbase = blockIdx.z * KC;
    const int tr = (tid >> 4) << 2;
    const int tc = (tid & 15) << 2;
    float acc[4][4];
#pragma unroll
    for (int r = 0; r < 4; r++)
#pragma unroll
        for (int c = 0; c < 4; c++) acc[r][c] = 0.f;

    for (int k0 = 0; k0 < KC; k0 += 16) {
        for (int i = tid; i < 1024; i += 256) {
            int m = i >> 4, k = i & 15;
            sA[k][m] = A[(size_t)m * K + kbase + k0 + k];
        }
        for (int i = tid; i < 1024; i += 256) {
            int k = i >> 6, n = i & 63;
            sB[k][n] = Bm[(size_t)(kbase + k0 + k) * N + n0 + n];
        }
        __syncthreads();
#pragma unroll
        for (int k = 0; k < 16; k++) {
            float4 a = *(const float4*)&sA[k][tr];
            float4 bv = *(const float4*)&sB[k][tc];
            float av[4] = {a.x, a.y, a.z, a.w};
            float bb[4] = {bv.x, bv.y, bv.z, bv.w};
#pragma unroll
            for (int r = 0; r < 4; r++)
#pragma unroll
                for (int c = 0; c < 4; c++) acc[r][c] += av[r] * bb[c];
        }
        __syncthreads();
    }
#pragma unroll
    for (int r = 0; r < 4; r++)
#pragma unroll
        for (int c = 0; c < 4; c++)
            atomicAdd(&C[(size_t)(tr + r) * N + n0 + tc + c], acc[r][c]);
}

__global__ void bias_relu_copy(const float* __restrict__ src, const float* __restrict__ bias,
                               float* __restrict__ dst, int N, int dstStride, int dstOff) {
    int idx = blockIdx.x * 256 + threadIdx.x;
    if (idx >= BATCH * N) return;
    int b = idx / N, n = idx % N;
    float v = src[idx] + bias[n];
    dst[(size_t)b * dstStride + dstOff + n] = v > 0.f ? v : 0.f;
}

__global__ void logits_kernel(const float* __restrict__ fused, const float* __restrict__ Wc,
                              const float* __restrict__ bcls, const float* __restrict__ temp,
                              float* __restrict__ out) {
    int idx = threadIdx.x;
    if (idx >= 128) return;
    int b = idx >> 1, n = idx & 1;
    float s = bcls[n];
    const float* f = fused + (size_t)b * 512;
    for (int k = 0; k < 512; k++) s += f[k] * Wc[k * 2 + n];
    out[idx] = s;
    out[128 + idx] = s / temp[0];
}

// ============================================================================
extern "C" void kernel_launch(void* const* d_in, const int* in_sizes, int n_in,
                              void* d_out, int out_size, void* d_ws, size_t ws_size,
                              hipStream_t stream) {
    const float* x      = (const float*)d_in[0];
    const float* w_stem = (const float*)d_in[1];
    const float* b_stem = (const float*)d_in[2];
    const float* w1 = (const float*)d_in[3];   const float* b1 = (const float*)d_in[4];
    const float* w2 = (const float*)d_in[5];   const float* b2 = (const float*)d_in[6];
    const float* w3 = (const float*)d_in[7];   const float* b3 = (const float*)d_in[8];
    const float* wd1 = (const float*)d_in[9];  const float* bd1 = (const float*)d_in[10];
    const float* wd2 = (const float*)d_in[11]; const float* bd2 = (const float*)d_in[12];
    const float* wf1 = (const float*)d_in[13]; const float* bf1 = (const float*)d_in[14];
    const float* wf2 = (const float*)d_in[15]; const float* bf2 = (const float*)d_in[16];
    const float* W_freq = (const float*)d_in[17]; const float* b_freq = (const float*)d_in[18];
    const float* W_fu1  = (const float*)d_in[19]; const float* b_fu1  = (const float*)d_in[20];
    const float* W_fu2  = (const float*)d_in[21]; const float* b_fu2  = (const float*)d_in[22];
    const float* W_cls  = (const float*)d_in[23]; const float* b_cls  = (const float*)d_in[24];
    const float* temp   = (const float*)d_in[25];
    float* ws = (float*)d_ws;
    float* out = (float*)d_out;

    const size_t IMG2 = 224 * 224;

    // ---- persistent region (dword offsets) ----
    size_t oWRE  = 0;                                    // packed W re (224*224)
    size_t oWIM  = oWRE + IMG2;                          // packed W im
    size_t oWSUM = oWIM + IMG2;
    size_t oDCT  = oWSUM + 288;
    size_t oDIMG = oDCT + (size_t)BATCH * 64;
    size_t oFREQIN  = oDIMG + (size_t)BATCH * IMG2;
    size_t oCOMB    = oFREQIN + (size_t)BATCH * 6272;
    size_t oFREQACC = oCOMB + (size_t)BATCH * 1024;      // zeroed region start
    size_t oFU1     = oFREQACC + (size_t)BATCH * 512;
    size_t oFUSED   = oFU1 + (size_t)BATCH * 1024;
    size_t oDCTACC  = oFUSED + (size_t)BATCH * 512;      // B*64, zeroed
    size_t oW1s     = oDCTACC + (size_t)BATCH * 64;
    size_t oW2s     = oW1s + 73728;
    size_t oW3s     = oW2s + 294912;
    size_t oWF2s    = oW3s + 1179648;
    size_t oWD2s    = oWF2s + 18432;
    size_t oWSTEMs  = oWD2s + 18432;                     // 64*224 packed stem weights
    size_t P        = oWSTEMs + 14336;

    // ---- chunk region: CB*1,605,632 dwords ----
    int CB = 16;
    while (CB > 1 && (P + (size_t)CB * 1605632) * 4 > ws_size) CB >>= 1;
    size_t base   = P;
    // XPK lives through the stem (stem reads packed x directly):
    size_t oXPK   = base;                                // CB*150528 packed x
    size_t oSTEMP = base + (size_t)CB * 150528;          // CB*802816 packed stem act
    size_t oC1P   = oSTEMP + (size_t)CB * 802816;        // CB*401408 packed
    size_t oC2P   = oC1P + (size_t)CB * 401408;          // CB*200704 packed
    // conv3 outputs alias XPK (dead after stem) + head of STEMP (dead by conv3):
    size_t oC3a   = base;                                // CB*100352 fp32
    size_t oC3b   = base + (size_t)CB * 100352;          // CB*100352 fp32
    // FFT-phase aliases inside STEMP region (dead before stem writes):
    size_t oTTRE  = oSTEMP;                              // CB*150528 packed Tt re
    size_t oTTIM  = oSTEMP + (size_t)CB * 150528;        // CB*150528 packed Tt im
    size_t oFFTIN = oSTEMP + (size_t)CB * 301056;        // CB*301056 fp32
    size_t oBIG1  = oC1P;                                // CB*401408 (packed, wf1/wd1 out)
    size_t oBIG2  = oC2P;                                // CB*200704 fp32 (mfma64 out)

    unsigned* WREp = (unsigned*)(ws + oWRE);
    unsigned* WIMp = (unsigned*)(ws + oWIM);
    unsigned* W1s = (unsigned*)(ws + oW1s);
    unsigned* W2s = (unsigned*)(ws + oW2s);
    unsigned* W3s = (unsigned*)(ws + oW3s);
    unsigned* WF2s = (unsigned*)(ws + oWF2s);
    unsigned* WD2s = (unsigned*)(ws + oWD2s);
    unsigned* WSTEMs = (unsigned*)(ws + oWSTEMs);
    unsigned* STEMP = (unsigned*)(ws + oSTEMP);
    unsigned* C1P   = (unsigned*)(ws + oC1P);
    unsigned* C2P   = (unsigned*)(ws + oC2P);
    unsigned* XPK   = (unsigned*)(ws + oXPK);
    unsigned* TTRE  = (unsigned*)(ws + oTTRE);
    unsigned* TTIM  = (unsigned*)(ws + oTTIM);
    unsigned* BIG1P = (unsigned*)(ws + oBIG1);

    // ---- batch-independent prep ----
    hipMemsetAsync(ws + oFREQACC, 0,
                   (size_t)BATCH * (512 + 1024 + 512 + 64) * sizeof(float), stream);
    make_dft<<<196, 256, 0, stream>>>(WREp, WIMp);
    make_wsum<<<1, 288, 0, stream>>>(wd1, ws + oWSUM);
    prep_w<<<(128 * 64 * 9 + 255) / 256, 256, 0, stream>>>(w1, W1s, 128, 64);
    prep_w<<<(256 * 128 * 9 + 255) / 256, 256, 0, stream>>>(w2, W2s, 256, 128);
    prep_w<<<(512 * 256 * 9 + 255) / 256, 256, 0, stream>>>(w3, W3s, 512, 256);
    prep_w<<<(64 * 32 * 9 + 255) / 256, 256, 0, stream>>>(wf2, WF2s, 64, 32);
    prep_w<<<(64 * 32 * 9 + 255) / 256, 256, 0, stream>>>(wd2, WD2s, 64, 32);
    prep_wstem<<<(64 * 224 + 255) / 256, 256, 0, stream>>>(w_stem, WSTEMs);
    dct_partial<<<dim3(BATCH, 12), 256, 0, stream>>>(x, ws + oDCTACC);
    dct_final<<<BATCH, 64, 0, stream>>>(ws + oDCTACC, ws + oDCT);
    resize_bilinear<<<12544, 256, 0, stream>>>(ws + oDCT, ws + oDIMG);

    // ---- per-image pipeline in batch chunks ----
    for (int b0 = 0; b0 < BATCH; b0 += CB) {
        const float* xc = x + (size_t)b0 * 3 * IMG2;
        // FFT branch: pack X, MFMA DFT stage1'/stage2', then convs
        pack_f32<<<(CB * 3 * (int)IMG2 + 255) / 256, 256, 0, stream>>>(
            xc, XPK, CB * 3 * (int)IMG2);
        dft_mfma_s1<<<dim3(7, 7, 3 * CB), 64, 0, stream>>>(WREp, WIMp, XPK, TTRE, TTIM);
        dft_mfma_s2<<<dim3(7, 7, 3 * CB), 64, 0, stream>>>(WREp, WIMp, TTRE, TTIM, ws + oFFTIN);
        conv3x3_s2<32, 8, 14, 6, true><<<dim3(112, 1, CB), 256, 0, stream>>>(
            ws + oFFTIN, wf1, bf1, ws + oBIG1, 6, 32, 224, 224, 112, 112);
        conv3x3s2_mfma64<<<dim3(CB * 3136 / 64, 1, 1), 256, 0, stream>>>(
            BIG1P, WF2s, bf2, ws + oBIG2, 112, 112, 56, 56, CB * 3136);
        pool7<<<(CB * 64 * 49 + 255) / 256, 256, 0, stream>>>(
            ws + oBIG2, ws + oFREQIN + (size_t)b0 * 6272, 3136, CB * 64 * 49);
        // DCT branch
        conv3x3_s2<32, 8, 14, 1, true><<<dim3(112, 1, CB), 256, 0, stream>>>(
            ws + oDIMG + (size_t)b0 * IMG2, ws + oWSUM, bd1, ws + oBIG1, 1, 32, 224, 224, 112, 112);
        conv3x3s2_mfma64<<<dim3(CB * 3136 / 64, 1, 1), 256, 0, stream>>>(
            BIG1P, WD2s, bd2, ws + oBIG2, 112, 112, 56, 56, CB * 3136);
        pool7<<<(CB * 64 * 49 + 255) / 256, 256, 0, stream>>>(
            ws + oBIG2, ws + oFREQIN + (size_t)b0 * 6272, 0, CB * 64 * 49);
        // backbone: stem MFMA (reads XPK) then conv1/2/3 MFMA
        conv7x7s2_mfma<<<dim3(CB * 196, 1, 1), 256, 0, stream>>>(
            XPK, WSTEMs, b_stem, STEMP, CB * 12544);
        conv3x3s2_mfma<<<dim3((CB * 3136 + 63) / 64, 1, 1), 256, 0, stream>>>(
            STEMP, W1s, b1, C1P, nullptr, nullptr,
            64, 128, 112, 112, 56, 56, CB * 3136, 64, 0);
        conv3x3s2_mfma<<<dim3((CB * 784 + 63) / 64, 2, 1), 256, 0, stream>>>(
            C1P, W2s, b2, C2P, nullptr, nullptr,
            128, 256, 56, 56, 28, 28, CB * 784, 128, 0);
        conv3x3s2_mfma<<<dim3((CB * 196 + 63) / 64, 4, 2), 256, 0, stream>>>(
            C2P, W3s, b3, nullptr, ws + oC3a, ws + oC3b,
            256, 512, 28, 28, 14, 14, CB * 196, 128, 1);
        gap2_kernel<<<(CB * 512 * 64 + 255) / 256, 256, 0, stream>>>(
            ws + oC3a, ws + oC3b, b3, ws + oCOMB + (size_t)b0 * 1024, CB * 512);
    }

    // ---- fusion ----
    gemm64_atomic<<<dim3(8, 1, 98), 256, 0, stream>>>(ws + oFREQIN, W_freq, ws + oFREQACC,
                                                      512, 6272, 64);
    bias_relu_copy<<<128, 256, 0, stream>>>(ws + oFREQACC, b_freq, ws + oCOMB, 512, 1024, 512);
    gemm64_atomic<<<dim3(16, 1, 16), 256, 0, stream>>>(ws + oCOMB, W_fu1, ws + oFU1,
                                                       1024, 1024, 64);
    bias_relu_copy<<<256, 256, 0, stream>>>(ws + oFU1, b_fu1, ws + oFU1, 1024, 1024, 0);
    gemm64_atomic<<<dim3(8, 1, 16), 256, 0, stream>>>(ws + oFU1, W_fu2, ws + oFUSED,
                                                      512, 1024, 64);
    bias_relu_copy<<<128, 256, 0, stream>>>(ws + oFUSED, b_fu2, ws + oFUSED, 512, 512, 0);
    logits_kernel<<<1, 128, 0, stream>>>(ws + oFUSED, W_cls, b_cls, temp, out);
}

// Round 8
// 1846.278 us; speedup vs baseline: 3.2268x; 1.1250x over previous
//
#include <hip/hip_runtime.h>

#ifndef M_PI
#define M_PI 3.14159265358979323846
#endif

// ============================================================================
// EnhancedAIDetector — round 8:
//  - REVERT round-7 tiled conv (post-timing nondeterminism + 500us regression).
//  - Round-6 kernels + XCD-aware block swizzle on the MFMA convs:
//    bx' = (bx&7)*(grid/8)+(bx>>3) gives each XCD a contiguous tile range so
//    its L2 keeps input rows + weight slices resident across the 9 taps.
//    grid.x padded to %8==0 (padded blocks fully guarded).
// ============================================================================

#define BATCH 64

typedef __bf16 bf16x8 __attribute__((ext_vector_type(8)));
typedef float f32x4 __attribute__((ext_vector_type(4)));

__device__ __forceinline__ unsigned short f2bf(float f) {
    unsigned u = __float_as_uint(f);
    u += 0x7FFF + ((u >> 16) & 1);      // RNE
    return (unsigned short)(u >> 16);
}
__device__ __forceinline__ unsigned packsplit(float v) {
    unsigned short h = f2bf(v);
    float hf = __uint_as_float(((unsigned)h) << 16);
    unsigned short l = f2bf(v - hf);
    return (((unsigned)h) << 16) | (unsigned)l;
}

union U8frag { bf16x8 v; unsigned d[4]; };

// unpack 8 packed dwords at p (LDS or global) -> hi fragment + lo fragment
__device__ __forceinline__ void unpack8(const unsigned* p, bf16x8& hi, bf16x8& lo) {
    uint4 a = *(const uint4*)p;
    uint4 b = *(const uint4*)(p + 4);
    U8frag H, L;
    H.d[0] = __builtin_amdgcn_perm(a.y, a.x, 0x07060302u);
    L.d[0] = __builtin_amdgcn_perm(a.y, a.x, 0x05040100u);
    H.d[1] = __builtin_amdgcn_perm(a.w, a.z, 0x07060302u);
    L.d[1] = __builtin_amdgcn_perm(a.w, a.z, 0x05040100u);
    H.d[2] = __builtin_amdgcn_perm(b.y, b.x, 0x07060302u);
    L.d[2] = __builtin_amdgcn_perm(b.y, b.x, 0x05040100u);
    H.d[3] = __builtin_amdgcn_perm(b.w, b.z, 0x07060302u);
    L.d[3] = __builtin_amdgcn_perm(b.w, b.z, 0x05040100u);
    hi = H.v; lo = L.v;
}

__device__ __forceinline__ bf16x8 bfneg(bf16x8 v) {
    U8frag a; a.v = v;
    a.d[0] ^= 0x80008000u; a.d[1] ^= 0x80008000u;
    a.d[2] ^= 0x80008000u; a.d[3] ^= 0x80008000u;
    return a.v;
}

// XCD-contiguity swizzle: valid bijection when gridDim.x % 8 == 0
__device__ __forceinline__ int swz_bx() {
    int bx = blockIdx.x;
    int nb = gridDim.x;
    if ((nb & 7) == 0) bx = (bx & 7) * (nb >> 3) + (bx >> 3);
    return bx;
}

// ============================================================================
// Weight prep: fp32 [Co][Ci][3][3] -> packed split [9][Co][Ci]
// ============================================================================
__global__ void prep_w(const float* __restrict__ w, unsigned* __restrict__ dst,
                       int Co, int Ci) {
    int idx = blockIdx.x * 256 + threadIdx.x;
    int tot = Co * Ci * 9;
    if (idx >= tot) return;
    int k9 = idx % 9;
    int rest = idx / 9;
    int ci = rest % Ci, co = rest / Ci;
    dst[((size_t)k9 * Co + co) * Ci + ci] = packsplit(w[idx]);
}

// stem weight prep: fp32 [64][3][7][7] -> packed [64][224], k = ky*32+kx*4+ci
__global__ void prep_wstem(const float* __restrict__ w, unsigned* __restrict__ dst) {
    int idx = blockIdx.x * 256 + threadIdx.x;
    if (idx >= 64 * 224) return;
    int co = idx / 224, k = idx % 224;
    int ci = k & 3, kx = (k >> 2) & 7, ky = k >> 5;
    float v = 0.f;
    if (ci < 3 && kx < 7)
        v = w[((co * 3 + ci) * 7 + ky) * 7 + kx];
    dst[idx] = packsplit(v);
}

__global__ void pack_f32(const float* __restrict__ src, unsigned* __restrict__ dst, int n) {
    int i = blockIdx.x * 256 + threadIdx.x;
    if (i < n) dst[i] = packsplit(src[i]);
}

// ============================================================================
// MFMA implicit-GEMM 3x3 s2 conv, 128co x 64n tile (backbone conv1/2/3).
// ============================================================================
__global__ __launch_bounds__(256)
void conv3x3s2_mfma(const unsigned* __restrict__ inP, const unsigned* __restrict__ wP,
                    const float* __restrict__ bias,
                    unsigned* __restrict__ outPk, float* __restrict__ outF0,
                    float* __restrict__ outF1,
                    int Ci, int Co, int Hin, int Win, int Hout, int Wout,
                    int NTOT, int ciPer, int mode) {
    __shared__ unsigned sA[128 * 36];
    __shared__ unsigned sB[64 * 36];
    const int tid = threadIdx.x;
    const int wv = tid >> 6, lane = tid & 63;
    const int ciBeg = blockIdx.z * ciPer;
    const int coT0 = blockIdx.y * 128;
    const int HWin = Hin * Win, HWout = Hout * Wout;
    const int bx = swz_bx();

    const int nG = bx * 64 + (tid >> 2);
    const int kqB = tid & 3;
    int bb = 0, yy = 0, xx = 0;
    bool nval = nG < NTOT;
    if (nval) {
        bb = nG / HWout;
        int rem = nG - bb * HWout;
        yy = rem / Wout;
        xx = rem - yy * Wout;
    }
    const unsigned baseImg = (unsigned)bb * Ci * HWin;
    const int coA = tid >> 1, halfA = tid & 1;

    f32x4 acc[2][4];
#pragma unroll
    for (int s = 0; s < 2; s++)
#pragma unroll
        for (int t = 0; t < 4; t++) acc[s][t] = (f32x4){0.f, 0.f, 0.f, 0.f};

    for (int k9 = 0; k9 < 9; k9++) {
        int ky = k9 / 3, kx = k9 - ky * 3;
        int iy = 2 * yy + ky, ix = 2 * xx + kx;
        bool bval = nval && iy < Hin && ix < Win;
        unsigned off0 = baseImg + (unsigned)iy * Win + (unsigned)ix;
        const unsigned* wbase = wP + ((size_t)k9 * Co + coT0 + coA) * Ci + ciBeg + halfA * 16;

        for (int c0 = 0; c0 < ciPer; c0 += 32) {
            __syncthreads();
            {
                const uint4* g = (const uint4*)(wbase + c0);
                uint4 v0 = g[0], v1 = g[1], v2 = g[2], v3 = g[3];
                uint4* d = (uint4*)(sA + coA * 36 + halfA * 16);
                d[0] = v0; d[1] = v1; d[2] = v2; d[3] = v3;
            }
            {
                unsigned u[8];
                const unsigned cbase = off0 + (unsigned)(ciBeg + c0 + kqB * 8) * HWin;
#pragma unroll
                for (int j = 0; j < 8; j++)
                    u[j] = bval ? inP[cbase + (unsigned)j * HWin] : 0u;
                uint4* d = (uint4*)(sB + (tid >> 2) * 36 + kqB * 8);
                uint4 w0; w0.x = u[0]; w0.y = u[1]; w0.z = u[2]; w0.w = u[3];
                uint4 w1; w1.x = u[4]; w1.y = u[5]; w1.z = u[6]; w1.w = u[7];
                d[0] = w0; d[1] = w1;
            }
            __syncthreads();

            bf16x8 ah[2], al[2], bh[4], bl[4];
            const int m = lane & 15, q = lane >> 4;
#pragma unroll
            for (int s = 0; s < 2; s++)
                unpack8(sA + (wv * 32 + s * 16 + m) * 36 + q * 8, ah[s], al[s]);
#pragma unroll
            for (int t = 0; t < 4; t++)
                unpack8(sB + (t * 16 + m) * 36 + q * 8, bh[t], bl[t]);

#pragma unroll
            for (int s = 0; s < 2; s++)
#pragma unroll
                for (int t = 0; t < 4; t++)
                    acc[s][t] = __builtin_amdgcn_mfma_f32_16x16x32_bf16(ah[s], bh[t], acc[s][t], 0, 0, 0);
#pragma unroll
            for (int s = 0; s < 2; s++)
#pragma unroll
                for (int t = 0; t < 4; t++)
                    acc[s][t] = __builtin_amdgcn_mfma_f32_16x16x32_bf16(ah[s], bl[t], acc[s][t], 0, 0, 0);
#pragma unroll
            for (int s = 0; s < 2; s++)
#pragma unroll
                for (int t = 0; t < 4; t++)
                    acc[s][t] = __builtin_amdgcn_mfma_f32_16x16x32_bf16(al[s], bh[t], acc[s][t], 0, 0, 0);
        }
    }

    const int m = lane & 15, q = lane >> 4;
#pragma unroll
    for (int t = 0; t < 4; t++) {
        int n_g = bx * 64 + t * 16 + m;
        if (n_g >= NTOT) continue;
        int b = n_g / HWout;
        int rem = n_g - b * HWout;
        size_t nb = (size_t)b * Co * HWout + rem;
#pragma unroll
        for (int s = 0; s < 2; s++) {
            int co_l = wv * 32 + s * 16 + q * 4;
#pragma unroll
            for (int r = 0; r < 4; r++) {
                int co_g = coT0 + co_l + r;
                float v = acc[s][t][r];
                size_t addr = nb + (size_t)co_g * HWout;
                if (mode == 0) {
                    v += bias[co_g];
                    v = v > 0.f ? v : 0.f;
                    outPk[addr] = packsplit(v);
                } else {
                    (blockIdx.z == 0 ? outF0 : outF1)[addr] = v;
                }
            }
        }
    }
}

// ============================================================================
// MFMA implicit-GEMM 3x3 s2 conv, 64co x 64n tile, Ci == 32 (wf2 / wd2).
// ============================================================================
__global__ __launch_bounds__(256)
void conv3x3s2_mfma64(const unsigned* __restrict__ inP, const unsigned* __restrict__ wP,
                      const float* __restrict__ bias, float* __restrict__ outF,
                      int Hin, int Win, int Hout, int Wout, int NTOT) {
    const int Ci = 32;
    __shared__ unsigned sA[64 * 36];
    __shared__ unsigned sB[64 * 36];
    const int tid = threadIdx.x;
    const int wv = tid >> 6, lane = tid & 63;
    const int HWin = Hin * Win, HWout = Hout * Wout;
    const int bx = swz_bx();

    const int nG = bx * 64 + (tid >> 2);
    const int kq = tid & 3;
    int bb = 0, yy = 0, xx = 0;
    bool nval = nG < NTOT;
    if (nval) {
        bb = nG / HWout;
        int rem = nG - bb * HWout;
        yy = rem / Wout;
        xx = rem - yy * Wout;
    }
    const unsigned baseImg = (unsigned)bb * Ci * HWin;
    const int ch = wv & 1, nh = wv >> 1;

    f32x4 acc[2][2];
#pragma unroll
    for (int s = 0; s < 2; s++)
#pragma unroll
        for (int t = 0; t < 2; t++) acc[s][t] = (f32x4){0.f, 0.f, 0.f, 0.f};

    for (int k9 = 0; k9 < 9; k9++) {
        int ky = k9 / 3, kx = k9 - ky * 3;
        int iy = 2 * yy + ky, ix = 2 * xx + kx;
        bool bval = nval && iy < Hin && ix < Win;
        unsigned off0 = baseImg + (unsigned)iy * Win + (unsigned)ix;
        __syncthreads();
        {
            const unsigned* g = wP + ((size_t)k9 * 64 + (tid >> 2)) * Ci + kq * 8;
            uint4 v0 = *(const uint4*)g;
            uint4 v1 = *(const uint4*)(g + 4);
            uint4* d = (uint4*)(sA + (tid >> 2) * 36 + kq * 8);
            d[0] = v0; d[1] = v1;
        }
        {
            unsigned u[8];
            const unsigned cbase = off0 + (unsigned)(kq * 8) * HWin;
#pragma unroll
            for (int j = 0; j < 8; j++)
                u[j] = bval ? inP[cbase + (unsigned)j * HWin] : 0u;
            uint4* d = (uint4*)(sB + (tid >> 2) * 36 + kq * 8);
            uint4 w0; w0.x = u[0]; w0.y = u[1]; w0.z = u[2]; w0.w = u[3];
            uint4 w1; w1.x = u[4]; w1.y = u[5]; w1.z = u[6]; w1.w = u[7];
            d[0] = w0; d[1] = w1;
        }
        __syncthreads();

        bf16x8 ah[2], al[2], bh[2], bl[2];
        const int m = lane & 15, q = lane >> 4;
#pragma unroll
        for (int s = 0; s < 2; s++)
            unpack8(sA + (ch * 32 + s * 16 + m) * 36 + q * 8, ah[s], al[s]);
#pragma unroll
        for (int t = 0; t < 2; t++)
            unpack8(sB + (nh * 32 + t * 16 + m) * 36 + q * 8, bh[t], bl[t]);

#pragma unroll
        for (int s = 0; s < 2; s++)
#pragma unroll
            for (int t = 0; t < 2; t++)
                acc[s][t] = __builtin_amdgcn_mfma_f32_16x16x32_bf16(ah[s], bh[t], acc[s][t], 0, 0, 0);
#pragma unroll
        for (int s = 0; s < 2; s++)
#pragma unroll
            for (int t = 0; t < 2; t++)
                acc[s][t] = __builtin_amdgcn_mfma_f32_16x16x32_bf16(ah[s], bl[t], acc[s][t], 0, 0, 0);
#pragma unroll
        for (int s = 0; s < 2; s++)
#pragma unroll
            for (int t = 0; t < 2; t++)
                acc[s][t] = __builtin_amdgcn_mfma_f32_16x16x32_bf16(al[s], bh[t], acc[s][t], 0, 0, 0);
    }

    const int m = lane & 15, q = lane >> 4;
#pragma unroll
    for (int t = 0; t < 2; t++) {
        int n_g = bx * 64 + nh * 32 + t * 16 + m;
        if (n_g >= NTOT) continue;
        int b = n_g / HWout;
        int rem = n_g - b * HWout;
        size_t nb = (size_t)b * 64 * HWout + rem;
#pragma unroll
        for (int s = 0; s < 2; s++) {
            int co0 = ch * 32 + s * 16 + q * 4;
#pragma unroll
            for (int r = 0; r < 4; r++) {
                int co = co0 + r;
                float v = acc[s][t][r] + bias[co];
                outF[nb + (size_t)co * HWout] = v > 0.f ? v : 0.f;
            }
        }
    }
}

// ============================================================================
// Stem 7x7 s2 conv as MFMA implicit GEMM (K = ky*32 + kx*4 + ci).
// ============================================================================
__global__ __launch_bounds__(256)
void conv7x7s2_mfma(const unsigned* __restrict__ inP, const unsigned* __restrict__ wP,
                    const float* __restrict__ bias, unsigned* __restrict__ outPk,
                    int NTOT) {
    __shared__ unsigned sA[64 * 36];
    __shared__ unsigned sB[64 * 36];
    const int tid = threadIdx.x;
    const int wv = tid >> 6, lane = tid & 63;
    const int HWout = 112 * 112;
    const int bx = swz_bx();

    const int nG = bx * 64 + (tid >> 2);
    const int kq = tid & 3;
    bool nval = nG < NTOT;
    int bb = 0, yy = 0, xx = 0;
    if (nval) {
        bb = nG / HWout;
        int rem = nG - bb * HWout;
        yy = rem / 112;
        xx = rem - yy * 112;
    }
    const int iy0 = 2 * yy - 2, ix0 = 2 * xx - 2;
    const unsigned baseImg = (unsigned)bb * 3 * 50176;
    const int ch = wv & 1, nh = wv >> 1;

    f32x4 acc[2][2];
#pragma unroll
    for (int s = 0; s < 2; s++)
#pragma unroll
        for (int t = 0; t < 2; t++) acc[s][t] = (f32x4){0.f, 0.f, 0.f, 0.f};

#pragma unroll
    for (int kyc = 0; kyc < 7; kyc++) {
        const int c0 = kyc * 32;
        const int iy = iy0 + kyc;
        const bool iyv = nval && iy >= 0 && iy < 224;
        __syncthreads();
        {
            const unsigned* g = wP + (tid >> 2) * 224 + c0 + kq * 8;
            uint4 v0 = *(const uint4*)g;
            uint4 v1 = *(const uint4*)(g + 4);
            uint4* d = (uint4*)(sA + (tid >> 2) * 36 + kq * 8);
            d[0] = v0; d[1] = v1;
        }
        {
            unsigned u[8];
            const unsigned rowbase = baseImg + (unsigned)(iy * 224);
#pragma unroll
            for (int j = 0; j < 8; j++) {
                int ci = j & 3;
                int kx = kq * 2 + (j >> 2);
                int ix = ix0 + kx;
                bool v = iyv && ci < 3 && kx < 7 && ix >= 0 && ix < 224;
                u[j] = v ? inP[rowbase + (unsigned)(ci * 50176 + ix)] : 0u;
            }
            uint4* d = (uint4*)(sB + (tid >> 2) * 36 + kq * 8);
            uint4 w0; w0.x = u[0]; w0.y = u[1]; w0.z = u[2]; w0.w = u[3];
            uint4 w1; w1.x = u[4]; w1.y = u[5]; w1.z = u[6]; w1.w = u[7];
            d[0] = w0; d[1] = w1;
        }
        __syncthreads();

        bf16x8 ah[2], al[2], bh[2], bl[2];
        const int m = lane & 15, q = lane >> 4;
#pragma unroll
        for (int s = 0; s < 2; s++)
            unpack8(sA + (ch * 32 + s * 16 + m) * 36 + q * 8, ah[s], al[s]);
#pragma unroll
        for (int t = 0; t < 2; t++)
            unpack8(sB + (nh * 32 + t * 16 + m) * 36 + q * 8, bh[t], bl[t]);

#pragma unroll
        for (int s = 0; s < 2; s++)
#pragma unroll
            for (int t = 0; t < 2; t++)
                acc[s][t] = __builtin_amdgcn_mfma_f32_16x16x32_bf16(ah[s], bh[t], acc[s][t], 0, 0, 0);
#pragma unroll
        for (int s = 0; s < 2; s++)
#pragma unroll
            for (int t = 0; t < 2; t++)
                acc[s][t] = __builtin_amdgcn_mfma_f32_16x16x32_bf16(ah[s], bl[t], acc[s][t], 0, 0, 0);
#pragma unroll
        for (int s = 0; s < 2; s++)
#pragma unroll
            for (int t = 0; t < 2; t++)
                acc[s][t] = __builtin_amdgcn_mfma_f32_16x16x32_bf16(al[s], bh[t], acc[s][t], 0, 0, 0);
    }

    const int m = lane & 15, q = lane >> 4;
#pragma unroll
    for (int t = 0; t < 2; t++) {
        int n_g = bx * 64 + nh * 32 + t * 16 + m;
        if (n_g >= NTOT) continue;
        int b = n_g / HWout;
        int rem = n_g - b * HWout;
        size_t nb = (size_t)b * 64 * HWout + rem;
#pragma unroll
        for (int s = 0; s < 2; s++) {
            int co0 = ch * 32 + s * 16 + q * 4;
#pragma unroll
            for (int r = 0; r < 4; r++) {
                int co = co0 + r;
                float v = acc[s][t][r] + bias[co];
                v = v > 0.f ? v : 0.f;
                outPk[nb + (size_t)co * HWout] = packsplit(v);
            }
        }
    }
}

// ============================================================================
// DFT matrix (packed split bf16)
// ============================================================================
__global__ void make_dft(unsigned* __restrict__ wre, unsigned* __restrict__ wim) {
    int idx = blockIdx.x * 256 + threadIdx.x;
    if (idx >= 224 * 224) return;
    int j = idx / 224, k = idx % 224;
    int m = (j * k) % 224;
    double a = -2.0 * M_PI * (double)m / 224.0;
    wre[idx] = packsplit((float)cos(a));
    wim[idx] = packsplit((float)sin(a));
}

__global__ void make_wsum(const float* __restrict__ wd1, float* __restrict__ wsum) {
    int idx = threadIdx.x;
    if (idx >= 288) return;
    int o = idx / 9, k = idx % 9;
    wsum[idx] = wd1[o * 27 + k] + wd1[o * 27 + 9 + k] + wd1[o * 27 + 18 + k];
}

// ============================================================================
// DFT stage 1 (MFMA): Tt = W @ X^T
// ============================================================================
__global__ __launch_bounds__(64)
void dft_mfma_s1(const unsigned* __restrict__ wre, const unsigned* __restrict__ wim,
                 const unsigned* __restrict__ xpk,
                 unsigned* __restrict__ ttre, unsigned* __restrict__ ttim) {
    const int z = blockIdx.z;
    const int m0 = blockIdx.x * 32, n0 = blockIdx.y * 32;
    const int lane = threadIdx.x;
    const int ml = lane & 15, q = lane >> 4;
    const unsigned* xb = xpk + (size_t)z * 50176;

    f32x4 cre[2][2], cim[2][2];
#pragma unroll
    for (int s = 0; s < 2; s++)
#pragma unroll
        for (int t = 0; t < 2; t++) { cre[s][t] = (f32x4){0,0,0,0}; cim[s][t] = (f32x4){0,0,0,0}; }

    for (int k0 = 0; k0 < 224; k0 += 32) {
        bf16x8 arh[2], arl[2], aih[2], ail[2], bh[2], bl[2];
#pragma unroll
        for (int s = 0; s < 2; s++) {
            int row = m0 + s * 16 + ml;
            unpack8(wre + row * 224 + k0 + q * 8, arh[s], arl[s]);
            unpack8(wim + row * 224 + k0 + q * 8, aih[s], ail[s]);
        }
#pragma unroll
        for (int t = 0; t < 2; t++)
            unpack8(xb + (n0 + t * 16 + ml) * 224 + k0 + q * 8, bh[t], bl[t]);

#pragma unroll
        for (int s = 0; s < 2; s++)
#pragma unroll
            for (int t = 0; t < 2; t++) {
                cre[s][t] = __builtin_amdgcn_mfma_f32_16x16x32_bf16(arh[s], bh[t], cre[s][t], 0, 0, 0);
                cre[s][t] = __builtin_amdgcn_mfma_f32_16x16x32_bf16(arh[s], bl[t], cre[s][t], 0, 0, 0);
                cre[s][t] = __builtin_amdgcn_mfma_f32_16x16x32_bf16(arl[s], bh[t], cre[s][t], 0, 0, 0);
                cim[s][t] = __builtin_amdgcn_mfma_f32_16x16x32_bf16(aih[s], bh[t], cim[s][t], 0, 0, 0);
                cim[s][t] = __builtin_amdgcn_mfma_f32_16x16x32_bf16(aih[s], bl[t], cim[s][t], 0, 0, 0);
                cim[s][t] = __builtin_amdgcn_mfma_f32_16x16x32_bf16(ail[s], bh[t], cim[s][t], 0, 0, 0);
            }
    }

    unsigned* tre = ttre + (size_t)z * 50176;
    unsigned* tim = ttim + (size_t)z * 50176;
#pragma unroll
    for (int s = 0; s < 2; s++)
#pragma unroll
        for (int t = 0; t < 2; t++)
#pragma unroll
            for (int r = 0; r < 4; r++) {
                int m = m0 + s * 16 + q * 4 + r;
                int n = n0 + t * 16 + ml;
                tre[m * 224 + n] = packsplit(cre[s][t][r]);
                tim[m * 224 + n] = packsplit(cim[s][t][r]);
            }
}

// ============================================================================
// DFT stage 2 (MFMA): Y = W @ T, complex; output fp32 fft_in
// ============================================================================
__global__ __launch_bounds__(64)
void dft_mfma_s2(const unsigned* __restrict__ wre, const unsigned* __restrict__ wim,
                 const unsigned* __restrict__ ttre, const unsigned* __restrict__ ttim,
                 float* __restrict__ fft_in) {
    const int z = blockIdx.z;
    const int m0 = blockIdx.x * 32, n0 = blockIdx.y * 32;
    const int lane = threadIdx.x;
    const int ml = lane & 15, q = lane >> 4;
    const unsigned* tre = ttre + (size_t)z * 50176;
    const unsigned* tim = ttim + (size_t)z * 50176;

    f32x4 cre[2][2], cim[2][2];
#pragma unroll
    for (int s = 0; s < 2; s++)
#pragma unroll
        for (int t = 0; t < 2; t++) { cre[s][t] = (f32x4){0,0,0,0}; cim[s][t] = (f32x4){0,0,0,0}; }

    for (int k0 = 0; k0 < 224; k0 += 32) {
        bf16x8 arh[2], arl[2], aih[2], ail[2];
        bf16x8 brh[2], brl[2], bih[2], bil[2];
#pragma unroll
        for (int s = 0; s < 2; s++) {
            int row = m0 + s * 16 + ml;
            unpack8(wre + row * 224 + k0 + q * 8, arh[s], arl[s]);
            unpack8(wim + row * 224 + k0 + q * 8, aih[s], ail[s]);
        }
#pragma unroll
        for (int t = 0; t < 2; t++) {
            int row = n0 + t * 16 + ml;
            unpack8(tre + row * 224 + k0 + q * 8, brh[t], brl[t]);
            unpack8(tim + row * 224 + k0 + q * 8, bih[t], bil[t]);
        }

#pragma unroll
        for (int t = 0; t < 2; t++) {
            bf16x8 nih = bfneg(bih[t]);
            bf16x8 nil = bfneg(bil[t]);
#pragma unroll
            for (int s = 0; s < 2; s++) {
                cre[s][t] = __builtin_amdgcn_mfma_f32_16x16x32_bf16(arh[s], brh[t], cre[s][t], 0, 0, 0);
                cre[s][t] = __builtin_amdgcn_mfma_f32_16x16x32_bf16(arh[s], brl[t], cre[s][t], 0, 0, 0);
                cre[s][t] = __builtin_amdgcn_mfma_f32_16x16x32_bf16(arl[s], brh[t], cre[s][t], 0, 0, 0);
                cre[s][t] = __builtin_amdgcn_mfma_f32_16x16x32_bf16(aih[s], nih, cre[s][t], 0, 0, 0);
                cre[s][t] = __builtin_amdgcn_mfma_f32_16x16x32_bf16(aih[s], nil, cre[s][t], 0, 0, 0);
                cre[s][t] = __builtin_amdgcn_mfma_f32_16x16x32_bf16(ail[s], nih, cre[s][t], 0, 0, 0);
                cim[s][t] = __builtin_amdgcn_mfma_f32_16x16x32_bf16(arh[s], bih[t], cim[s][t], 0, 0, 0);
                cim[s][t] = __builtin_amdgcn_mfma_f32_16x16x32_bf16(arh[s], bil[t], cim[s][t], 0, 0, 0);
                cim[s][t] = __builtin_amdgcn_mfma_f32_16x16x32_bf16(arl[s], bih[t], cim[s][t], 0, 0, 0);
                cim[s][t] = __builtin_amdgcn_mfma_f32_16x16x32_bf16(aih[s], brh[t], cim[s][t], 0, 0, 0);
                cim[s][t] = __builtin_amdgcn_mfma_f32_16x16x32_bf16(aih[s], brl[t], cim[s][t], 0, 0, 0);
                cim[s][t] = __builtin_amdgcn_mfma_f32_16x16x32_bf16(ail[s], brh[t], cim[s][t], 0, 0, 0);
            }
        }
    }

    const int b_loc = z / 3, c = z % 3;
    float* yre = fft_in + (size_t)(b_loc * 6 + 2 * c) * 50176;
    float* yim = yre + 50176;
#pragma unroll
    for (int s = 0; s < 2; s++)
#pragma unroll
        for (int t = 0; t < 2; t++)
#pragma unroll
            for (int r = 0; r < 4; r++) {
                int m = m0 + s * 16 + q * 4 + r;
                int n = n0 + t * 16 + ml;
                yre[m * 224 + n] = cre[s][t][r];
                yim[m * 224 + n] = cim[s][t][r];
            }
}

// ============================================================================
// fp32 direct 3x3 s2 conv; PACK=true writes split-bf16 packed dwords.
// ============================================================================
template <int CO_BLK, int TH, int TW, int CI_CHUNK, bool PACK>
__global__ __launch_bounds__(CO_BLK * TH)
void conv3x3_s2(const float* __restrict__ in, const float* __restrict__ w,
                const float* __restrict__ bias, float* __restrict__ out,
                int Ci, int Co, int Hin, int Win, int Hout, int Wout) {
    constexpr int IN_H = 2 * TH + 1;
    constexpr int IN_W = 2 * TW + 1;
    constexpr int IN_WP = 32;
    constexpr int WSTR = (CI_CHUNK * 9) | 1;
    __shared__ __align__(16) float s_in[CI_CHUNK][IN_H][IN_WP];
    __shared__ float s_w[CO_BLK * WSTR];

    const int tid = threadIdx.x;
    const int tiles_x = Wout / TW;
    const int tile = blockIdx.x;
    const int ty0 = (tile / tiles_x) * TH;
    const int tx0 = (tile % tiles_x) * TW;
    const int cog = blockIdx.y;
    const int b = blockIdx.z;
    const int co = tid % CO_BLK;
    const int ty = tid / CO_BLK;
    const int co_g = cog * CO_BLK + co;

    float acc[TW];
#pragma unroll
    for (int i = 0; i < TW; i++) acc[i] = 0.f;

    const float* in_b = in + (size_t)b * Ci * Hin * Win;
    const int iy0 = 2 * ty0, ix0 = 2 * tx0;

    for (int ci0 = 0; ci0 < Ci; ci0 += CI_CHUNK) {
        for (int idx = tid; idx < CI_CHUNK * IN_H * IN_W; idx += CO_BLK * TH) {
            int ci = idx / (IN_H * IN_W);
            int rem = idx % (IN_H * IN_W);
            int r = rem / IN_W, cc = rem % IN_W;
            int gy = iy0 + r, gx = ix0 + cc;
            float v = 0.f;
            if (gy < Hin && gx < Win)
                v = in_b[(size_t)(ci0 + ci) * Hin * Win + (size_t)gy * Win + gx];
            s_in[ci][r][cc] = v;
        }
        for (int idx = tid; idx < CO_BLK * CI_CHUNK * 9; idx += CO_BLK * TH) {
            int c = idx / (CI_CHUNK * 9);
            int k = idx % (CI_CHUNK * 9);
            s_w[c * WSTR + k] = w[((size_t)(cog * CO_BLK + c) * Ci + ci0) * 9 + k];
        }
        __syncthreads();

#pragma unroll
        for (int ci = 0; ci < CI_CHUNK; ci++) {
            float wr[9];
#pragma unroll
            for (int k = 0; k < 9; k++) wr[k] = s_w[co * WSTR + ci * 9 + k];
#pragma unroll
            for (int ky = 0; ky < 3; ky++) {
                float r[IN_WP];
                const float4* rowp = (const float4*)&s_in[ci][2 * ty + ky][0];
#pragma unroll
                for (int qq = 0; qq < IN_WP / 4; qq++) {
                    float4 v = rowp[qq];
                    r[4 * qq] = v.x; r[4 * qq + 1] = v.y; r[4 * qq + 2] = v.z; r[4 * qq + 3] = v.w;
                }
#pragma unroll
                for (int kx = 0; kx < 3; kx++) {
                    float wv = wr[ky * 3 + kx];
#pragma unroll
                    for (int xq = 0; xq < TW; xq++) acc[xq] += r[2 * xq + kx] * wv;
                }
            }
        }
        __syncthreads();
    }
    float bb = bias[co_g];
    size_t obase = ((size_t)b * Co + co_g) * Hout * Wout + (size_t)(ty0 + ty) * Wout + tx0;
#pragma unroll
    for (int xq = 0; xq < TW; xq++) {
        float v = acc[xq] + bb;
        v = v > 0.f ? v : 0.f;
        if (PACK)
            ((unsigned*)out)[obase + xq] = packsplit(v);
        else
            out[obase + xq] = v;
    }
}

// ============================================================================
// DCT branch: parallel block-mean (2-stage) then 8x8 DCT; bilinear resize.
// ============================================================================
__device__ __forceinline__ float dct_coef(int u, int i) {
    if (u == 0) return 0.35355339059327373f;
    return 0.5f * cosf((float)M_PI * (float)((2 * i + 1) * u) / 16.0f);
}

__global__ __launch_bounds__(256)
void dct_partial(const float* __restrict__ x, float* __restrict__ accum) {
    __shared__ float red[256];
    const int b = blockIdx.x, g = blockIdx.y;
    const int tid = threadIdx.x;
    const int ij = tid & 63;
    const int grp = tid >> 6;
    const int i = ij >> 3, j = ij & 7;
    const float* xb = x + (size_t)b * 3 * 50176;
    float s = 0.f;
    for (int blk = g * 4 + grp; blk < 784; blk += 48) {
        int m = blk / 28, n = blk % 28;
        size_t o = (size_t)(m * 8 + i) * 224 + n * 8 + j;
        s += 0.299f * xb[o] + 0.587f * xb[50176 + o] + 0.114f * xb[2 * 50176 + o];
    }
    red[tid] = s;
    __syncthreads();
    if (tid < 64)
        atomicAdd(&accum[b * 64 + tid],
                  red[tid] + red[tid + 64] + red[tid + 128] + red[tid + 192]);
}

__global__ __launch_bounds__(64)
void dct_final(const float* __restrict__ accum, float* __restrict__ dct_out) {
    __shared__ float Mb[64];
    const int b = blockIdx.x, tid = threadIdx.x;
    Mb[tid] = accum[b * 64 + tid] * (255.f / 784.f);
    __syncthreads();
    int u = tid >> 3, v = tid & 7;
    float acc = 0.f;
#pragma unroll
    for (int i2 = 0; i2 < 8; i2++) {
        float du = dct_coef(u, i2);
#pragma unroll
        for (int j2 = 0; j2 < 8; j2++) acc += du * Mb[i2 * 8 + j2] * dct_coef(v, j2);
    }
    dct_out[b * 64 + tid] = acc;
}

__global__ void resize_bilinear(const float* __restrict__ dct, float* __restrict__ out) {
    int idx = blockIdx.x * 256 + threadIdx.x;
    if (idx >= BATCH * 224 * 224) return;
    int b = idx / (224 * 224);
    int rem = idx % (224 * 224);
    int y = rem / 224, xx = rem % 224;
    float sy = fminf(fmaxf((y + 0.5f) * (1.f / 28.f) - 0.5f, 0.f), 7.f);
    float sx = fminf(fmaxf((xx + 0.5f) * (1.f / 28.f) - 0.5f, 0.f), 7.f);
    int y0 = (int)floorf(sy); if (y0 > 6) y0 = 6;
    int x0 = (int)floorf(sx); if (x0 > 6) x0 = 6;
    float ty = sy - y0, tx = sx - x0;
    const float* M = dct + b * 64;
    float v00 = M[y0 * 8 + x0], v01 = M[y0 * 8 + x0 + 1];
    float v10 = M[(y0 + 1) * 8 + x0], v11 = M[(y0 + 1) * 8 + x0 + 1];
    out[idx] = (1.f - ty) * ((1.f - tx) * v00 + tx * v01) + ty * ((1.f - tx) * v10 + tx * v11);
}

// ============================================================================
// Pooling
// ============================================================================
__global__ void pool7(const float* __restrict__ h, float* __restrict__ out,
                      int col_base, int n) {
    int idx = blockIdx.x * 256 + threadIdx.x;
    if (idx >= n) return;
    int b = idx / (64 * 49);
    int rem = idx % (64 * 49);
    int c = rem / 49;
    int ij = rem % 49;
    int i = ij / 7, j = ij % 7;
    const float* hp = h + ((size_t)(b * 64 + c)) * 56 * 56 + (size_t)i * 8 * 56 + j * 8;
    float s = 0.f;
#pragma unroll
    for (int r = 0; r < 8; r++)
#pragma unroll
        for (int q = 0; q < 8; q++) s += hp[r * 56 + q];
    out[(size_t)b * 6272 + col_base + c * 49 + ij] = s * (1.f / 64.f);
}

__global__ void gap2_kernel(const float* __restrict__ ha, const float* __restrict__ hb,
                            const float* __restrict__ bias, float* __restrict__ comb,
                            int nwaves) {
    int gt = blockIdx.x * blockDim.x + threadIdx.x;
    int wid = gt >> 6;
    int lane = gt & 63;
    if (wid >= nwaves) return;
    int b = wid / 512, c = wid % 512;
    const float* pa = ha + (size_t)wid * 196;
    const float* pb = hb + (size_t)wid * 196;
    float bbv = bias[c];
    float s = 0.f;
    for (int i = lane; i < 196; i += 64) {
        float v = pa[i] + pb[i] + bbv;
        s += v > 0.f ? v : 0.f;
    }
#pragma unroll
    for (int off = 32; off > 0; off >>= 1) s += __shfl_down(s, off);
    if (lane == 0) comb[(size_t)b * 1024 + c] = s * (1.f / 196.f);
}

// ============================================================================
// Fusion GEMMs (fp32, M=64, split-K atomic)
// ============================================================================
__global__ __launch_bounds__(256)
void gemm64_atomic(const float* __restrict__ A, const float* __restrict__ Bm,
                   float* __restrict__ C, int N, int K, int KC) {
    __shared__ __align__(16) float sA[16][68];
    __shared__ __align__(16) float sB[16][68];
    const int tid = threadIdx.x;
    const int n0 = blockIdx.x * 64;
    const int kbase = blockIdx.z * KC;
    const int tr = (tid >> 4) << 2;
    const int tc = (tid & 15) << 2;
    float acc[4][4];
#pragma unroll
    for (int r = 0; r < 4; r++)
#pragma unroll
        for (int c = 0; c < 4; c++) acc[r][c] = 0.f;

    for (int k0 = 0; k0 < KC; k0 += 16) {
        for (int i = tid; i < 1024; i += 256) {
            int m = i >> 4, k = i & 15;
            sA[k][m] = A[(size_t)m * K + kbase + k0 + k];
        }
        for (int i = tid; i < 1024; i += 256) {
            int k = i >> 6, n = i & 63;
            sB[k][n] = Bm[(size_t)(kbase + k0 + k) * N + n0 + n];
        }
        __syncthreads();
#pragma unroll
        for (int k = 0; k < 16; k++) {
            float4 a = *(const float4*)&sA[k][tr];
            float4 bv = *(const float4*)&sB[k][tc];
            float av[4] = {a.x, a.y, a.z, a.w};
            float bb[4] = {bv.x, bv.y, bv.z, bv.w};
#pragma unroll
            for (int r = 0; r < 4; r++)
#pragma unroll
                for (int c = 0; c < 4; c++) acc[r][c] += av[r] * bb[c];
        }
        __syncthreads();
    }
#pragma unroll
    for (int r = 0; r < 4; r++)
#pragma unroll
        for (int c = 0; c < 4; c++)
            atomicAdd(&C[(size_t)(tr + r) * N + n0 + tc + c], acc[r][c]);
}

__global__ void bias_relu_copy(const float* __restrict__ src, const float* __restrict__ bias,
                               float* __restrict__ dst, int N, int dstStride, int dstOff) {
    int idx = blockIdx.x * 256 + threadIdx.x;
    if (idx >= BATCH * N) return;
    int b = idx / N, n = idx % N;
    float v = src[idx] + bias[n];
    dst[(size_t)b * dstStride + dstOff + n] = v > 0.f ? v : 0.f;
}

__global__ void logits_kernel(const float* __restrict__ fused, const float* __restrict__ Wc,
                              const float* __restrict__ bcls, const float* __restrict__ temp,
                              float* __restrict__ out) {
    int idx = threadIdx.x;
    if (idx >= 128) return;
    int b = idx >> 1, n = idx & 1;
    float s = bcls[n];
    const float* f = fused + (size_t)b * 512;
    for (int k = 0; k < 512; k++) s += f[k] * Wc[k * 2 + n];
    out[idx] = s;
    out[128 + idx] = s / temp[0];
}

static inline int ceil8(int n) { return (n + 7) & ~7; }

// ============================================================================
extern "C" void kernel_launch(void* const* d_in, const int* in_sizes, int n_in,
                              void* d_out, int out_size, void* d_ws, size_t ws_size,
                              hipStream_t stream) {
    const float* x      = (const float*)d_in[0];
    const float* w_stem = (const float*)d_in[1];
    const float* b_stem = (const float*)d_in[2];
    const float* w1 = (const float*)d_in[3];   const float* b1 = (const float*)d_in[4];
    const float* w2 = (const float*)d_in[5];   const float* b2 = (const float*)d_in[6];
    const float* w3 = (const float*)d_in[7];   const float* b3 = (const float*)d_in[8];
    const float* wd1 = (const float*)d_in[9];  const float* bd1 = (const float*)d_in[10];
    const float* wd2 = (const float*)d_in[11]; const float* bd2 = (const float*)d_in[12];
    const float* wf1 = (const float*)d_in[13]; const float* bf1 = (const float*)d_in[14];
    const float* wf2 = (const float*)d_in[15]; const float* bf2 = (const float*)d_in[16];
    const float* W_freq = (const float*)d_in[17]; const float* b_freq = (const float*)d_in[18];
    const float* W_fu1  = (const float*)d_in[19]; const float* b_fu1  = (const float*)d_in[20];
    const float* W_fu2  = (const float*)d_in[21]; const float* b_fu2  = (const float*)d_in[22];
    const float* W_cls  = (const float*)d_in[23]; const float* b_cls  = (const float*)d_in[24];
    const float* temp   = (const float*)d_in[25];
    float* ws = (float*)d_ws;
    float* out = (float*)d_out;

    const size_t IMG2 = 224 * 224;

    // ---- persistent region (dword offsets) ----
    size_t oWRE  = 0;
    size_t oWIM  = oWRE + IMG2;
    size_t oWSUM = oWIM + IMG2;
    size_t oDCT  = oWSUM + 288;
    size_t oDIMG = oDCT + (size_t)BATCH * 64;
    size_t oFREQIN  = oDIMG + (size_t)BATCH * IMG2;
    size_t oCOMB    = oFREQIN + (size_t)BATCH * 6272;
    size_t oFREQACC = oCOMB + (size_t)BATCH * 1024;
    size_t oFU1     = oFREQACC + (size_t)BATCH * 512;
    size_t oFUSED   = oFU1 + (size_t)BATCH * 1024;
    size_t oDCTACC  = oFUSED + (size_t)BATCH * 512;
    size_t oW1s     = oDCTACC + (size_t)BATCH * 64;
    size_t oW2s     = oW1s + 73728;
    size_t oW3s     = oW2s + 294912;
    size_t oWF2s    = oW3s + 1179648;
    size_t oWD2s    = oWF2s + 18432;
    size_t oWSTEMs  = oWD2s + 18432;
    size_t P        = oWSTEMs + 14336;

    // ---- chunk region: CB*1,605,632 dwords ----
    int CB = 16;
    while (CB > 1 && (P + (size_t)CB * 1605632) * 4 > ws_size) CB >>= 1;
    size_t base   = P;
    size_t oXPK   = base;                                // CB*150528 packed x
    size_t oSTEMP = base + (size_t)CB * 150528;          // CB*802816 packed stem act
    size_t oC1P   = oSTEMP + (size_t)CB * 802816;        // CB*401408 packed
    size_t oC2P   = oC1P + (size_t)CB * 401408;          // CB*200704 packed
    size_t oC3a   = base;                                // CB*100352 fp32 (aliases dead XPK)
    size_t oC3b   = base + (size_t)CB * 100352;          // CB*100352 fp32
    size_t oTTRE  = oSTEMP;                              // CB*150528 packed Tt re
    size_t oTTIM  = oSTEMP + (size_t)CB * 150528;        // CB*150528 packed Tt im
    size_t oFFTIN = oSTEMP + (size_t)CB * 301056;        // CB*301056 fp32
    size_t oBIG1  = oC1P;
    size_t oBIG2  = oC2P;

    unsigned* WREp = (unsigned*)(ws + oWRE);
    unsigned* WIMp = (unsigned*)(ws + oWIM);
    unsigned* W1s = (unsigned*)(ws + oW1s);
    unsigned* W2s = (unsigned*)(ws + oW2s);
    unsigned* W3s = (unsigned*)(ws + oW3s);
    unsigned* WF2s = (unsigned*)(ws + oWF2s);
    unsigned* WD2s = (unsigned*)(ws + oWD2s);
    unsigned* WSTEMs = (unsigned*)(ws + oWSTEMs);
    unsigned* STEMP = (unsigned*)(ws + oSTEMP);
    unsigned* C1P   = (unsigned*)(ws + oC1P);
    unsigned* C2P   = (unsigned*)(ws + oC2P);
    unsigned* XPK   = (unsigned*)(ws + oXPK);
    unsigned* TTRE  = (unsigned*)(ws + oTTRE);
    unsigned* TTIM  = (unsigned*)(ws + oTTIM);
    unsigned* BIG1P = (unsigned*)(ws + oBIG1);

    // ---- batch-independent prep ----
    hipMemsetAsync(ws + oFREQACC, 0,
                   (size_t)BATCH * (512 + 1024 + 512 + 64) * sizeof(float), stream);
    make_dft<<<196, 256, 0, stream>>>(WREp, WIMp);
    make_wsum<<<1, 288, 0, stream>>>(wd1, ws + oWSUM);
    prep_w<<<(128 * 64 * 9 + 255) / 256, 256, 0, stream>>>(w1, W1s, 128, 64);
    prep_w<<<(256 * 128 * 9 + 255) / 256, 256, 0, stream>>>(w2, W2s, 256, 128);
    prep_w<<<(512 * 256 * 9 + 255) / 256, 256, 0, stream>>>(w3, W3s, 512, 256);
    prep_w<<<(64 * 32 * 9 + 255) / 256, 256, 0, stream>>>(wf2, WF2s, 64, 32);
    prep_w<<<(64 * 32 * 9 + 255) / 256, 256, 0, stream>>>(wd2, WD2s, 64, 32);
    prep_wstem<<<(64 * 224 + 255) / 256, 256, 0, stream>>>(w_stem, WSTEMs);
    dct_partial<<<dim3(BATCH, 12), 256, 0, stream>>>(x, ws + oDCTACC);
    dct_final<<<BATCH, 64, 0, stream>>>(ws + oDCTACC, ws + oDCT);
    resize_bilinear<<<12544, 256, 0, stream>>>(ws + oDCT, ws + oDIMG);

    // ---- per-image pipeline in batch chunks ----
    for (int b0 = 0; b0 < BATCH; b0 += CB) {
        const float* xc = x + (size_t)b0 * 3 * IMG2;
        // FFT branch
        pack_f32<<<(CB * 3 * (int)IMG2 + 255) / 256, 256, 0, stream>>>(
            xc, XPK, CB * 3 * (int)IMG2);
        dft_mfma_s1<<<dim3(7, 7, 3 * CB), 64, 0, stream>>>(WREp, WIMp, XPK, TTRE, TTIM);
        dft_mfma_s2<<<dim3(7, 7, 3 * CB), 64, 0, stream>>>(WREp, WIMp, TTRE, TTIM, ws + oFFTIN);
        conv3x3_s2<32, 8, 14, 6, true><<<dim3(112, 1, CB), 256, 0, stream>>>(
            ws + oFFTIN, wf1, bf1, ws + oBIG1, 6, 32, 224, 224, 112, 112);
        conv3x3s2_mfma64<<<dim3(ceil8(CB * 3136 / 64), 1, 1), 256, 0, stream>>>(
            BIG1P, WF2s, bf2, ws + oBIG2, 112, 112, 56, 56, CB * 3136);
        pool7<<<(CB * 64 * 49 + 255) / 256, 256, 0, stream>>>(
            ws + oBIG2, ws + oFREQIN + (size_t)b0 * 6272, 3136, CB * 64 * 49);
        // DCT branch
        conv3x3_s2<32, 8, 14, 1, true><<<dim3(112, 1, CB), 256, 0, stream>>>(
            ws + oDIMG + (size_t)b0 * IMG2, ws + oWSUM, bd1, ws + oBIG1, 1, 32, 224, 224, 112, 112);
        conv3x3s2_mfma64<<<dim3(ceil8(CB * 3136 / 64), 1, 1), 256, 0, stream>>>(
            BIG1P, WD2s, bd2, ws + oBIG2, 112, 112, 56, 56, CB * 3136);
        pool7<<<(CB * 64 * 49 + 255) / 256, 256, 0, stream>>>(
            ws + oBIG2, ws + oFREQIN + (size_t)b0 * 6272, 0, CB * 64 * 49);
        // backbone: stem MFMA then conv1/2/3 MFMA (all XCD-swizzled)
        conv7x7s2_mfma<<<dim3(ceil8(CB * 196), 1, 1), 256, 0, stream>>>(
            XPK, WSTEMs, b_stem, STEMP, CB * 12544);
        conv3x3s2_mfma<<<dim3(ceil8((CB * 3136 + 63) / 64), 1, 1), 256, 0, stream>>>(
            STEMP, W1s, b1, C1P, nullptr, nullptr,
            64, 128, 112, 112, 56, 56, CB * 3136, 64, 0);
        conv3x3s2_mfma<<<dim3(ceil8((CB * 784 + 63) / 64), 2, 1), 256, 0, stream>>>(
            C1P, W2s, b2, C2P, nullptr, nullptr,
            128, 256, 56, 56, 28, 28, CB * 784, 128, 0);
        conv3x3s2_mfma<<<dim3(ceil8((CB * 196 + 63) / 64), 4, 2), 256, 0, stream>>>(
            C2P, W3s, b3, nullptr, ws + oC3a, ws + oC3b,
            256, 512, 28, 28, 14, 14, CB * 196, 128, 1);
        gap2_kernel<<<(CB * 512 * 64 + 255) / 256, 256, 0, stream>>>(
            ws + oC3a, ws + oC3b, b3, ws + oCOMB + (size_t)b0 * 1024, CB * 512);
    }

    // ---- fusion ----
    gemm64_atomic<<<dim3(8, 1, 98), 256, 0, stream>>>(ws + oFREQIN, W_freq, ws + oFREQACC,
                                                      512, 6272, 64);
    bias_relu_copy<<<128, 256, 0, stream>>>(ws + oFREQACC, b_freq, ws + oCOMB, 512, 1024, 512);
    gemm64_atomic<<<dim3(16, 1, 16), 256, 0, stream>>>(ws + oCOMB, W_fu1, ws + oFU1,
                                                       1024, 1024, 64);
    bias_relu_copy<<<256, 256, 0, stream>>>(ws + oFU1, b_fu1, ws + oFU1, 1024, 1024, 0);
    gemm64_atomic<<<dim3(8, 1, 16), 256, 0, stream>>>(ws + oFU1, W_fu2, ws + oFUSED,
                                                      512, 1024, 64);
    bias_relu_copy<<<128, 256, 0, stream>>>(ws + oFUSED, b_fu2, ws + oFUSED, 512, 512, 0);
    logits_kernel<<<1, 128, 0, stream>>>(ws + oFUSED, W_cls, b_cls, temp, out);
}